// Round 2
// baseline (1520.682 us; speedup 1.0000x reference)
//
#include <hip/hip_runtime.h>
#include <hip/hip_bf16.h>
#include <math.h>

// ---------------------------------------------------------------------------
// BashTransformer forward on MI355X. Round 10: delta_scan rewritten as
// 8-token chunked delta rule — all 16 state-dots per block read block-start
// S0 (parallel chains, saturate single-wave issue); serial part is a
// 2-FMA/token scalar chain with triangular kk/kq corrections as stall
// filler. Pair dots precomputed in staging via shfl_xor within each wave's
// 8-token group. GEMM/attn/epilogues unchanged from round 8.
// ---------------------------------------------------------------------------

#define LSEQ 1024
#define BATCH 4
#define HIDDEN 512
#define NHEAD 8
#define HDIM 64
#define SHEAD 8
#define SDHD 32
#define SDIMM 256
#define FFND 1536
#define VOCN 63
#define ATTS 72   // attn LDS row stride (elems): 144B = 16B-aligned, 2-way banks

typedef __bf16 bf16;
typedef __attribute__((ext_vector_type(8))) __bf16 bf16x8;
typedef __attribute__((ext_vector_type(4))) float floatx4;

union BF4 { bf16 h[4]; short4 p; };

__device__ __forceinline__ void gload16(const void* g, const void* l) {
    __builtin_amdgcn_global_load_lds(
        (__attribute__((address_space(1))) unsigned int*)(uintptr_t)g,
        (__attribute__((address_space(3))) unsigned int*)(unsigned int)(uintptr_t)l,
        16, 0, 0);
}

// sum over aligned groups of 8 lanes, pure DPP (VALU pipe, no LDS counters)
__device__ __forceinline__ float sum8(float x) {
    x += __int_as_float(__builtin_amdgcn_mov_dpp(__float_as_int(x), 0xB1, 0xF, 0xF, true));
    x += __int_as_float(__builtin_amdgcn_mov_dpp(__float_as_int(x), 0x4E, 0xF, 0xF, true));
    x += __int_as_float(__builtin_amdgcn_mov_dpp(__float_as_int(x), 0x141, 0xF, 0xF, true));
    return x;
}

// ------------------------------- rope tables -------------------------------
__global__ void rope_tables_k(float* __restrict__ cosT, float* __restrict__ sinT) {
    int idx = blockIdx.x * 256 + threadIdx.x;   // 32768 = 1024*32
    int l = idx >> 5, d = idx & 31;
    double ang = (double)l * pow(500000.0, -(double)(2 * d) / 64.0);
    cosT[idx] = (float)cos(ang);
    sinT[idx] = (float)sin(ang);
}

// ------------------------------- embedding ---------------------------------
__global__ void embed_k(const int* __restrict__ ids, const float* __restrict__ emb,
                        float* __restrict__ h) {
    int tok = blockIdx.x;
    int id = ids[tok];
    ((float4*)(h + (size_t)tok * HIDDEN))[threadIdx.x] =
        ((const float4*)(emb + (size_t)id * HIDDEN))[threadIdx.x];
}

// ------------------------------- casts -------------------------------------
__global__ void cast_plain(const float* __restrict__ s, bf16* __restrict__ d, int n4) {
    int i = blockIdx.x * 256 + threadIdx.x;
    if (i >= n4) return;
    float4 v = ((const float4*)s)[i];
    BF4 u;
    u.h[0] = (bf16)v.x; u.h[1] = (bf16)v.y; u.h[2] = (bf16)v.z; u.h[3] = (bf16)v.w;
    ((short4*)d)[i] = u.p;
}

// six 256x512 f32 matrices -> one fused 1536x512 bf16 (order s0..s5)
__global__ void cast6(const float* s0, const float* s1, const float* s2,
                      const float* s3, const float* s4, const float* s5,
                      bf16* __restrict__ d) {
    int i = blockIdx.x * 256 + threadIdx.x;      // 196608 short4s
    if (i >= 196608) return;
    int which = i >> 15, loc = i & 32767;
    const float* s = which == 0 ? s0 : which == 1 ? s1 : which == 2 ? s2
                    : which == 3 ? s3 : which == 4 ? s4 : s5;
    float4 v = ((const float4*)s)[loc];
    BF4 u;
    u.h[0] = (bf16)v.x; u.h[1] = (bf16)v.y; u.h[2] = (bf16)v.z; u.h[3] = (bf16)v.w;
    ((short4*)d)[i] = u.p;
}

// wq/wk/wv (6,512,512) each -> fused (6,1536,512) rows [layer*1536+which*512+r]
__global__ void cast_qkv(const float* __restrict__ q, const float* __restrict__ k,
                         const float* __restrict__ v, bf16* __restrict__ d) {
    int idx = blockIdx.x * 256 + threadIdx.x;    // 3*393216
    if (idx >= 1179648) return;
    int which = idx / 393216;
    int rem = idx - which * 393216;
    const float* s = which == 0 ? q : which == 1 ? k : v;
    int layer = rem >> 16, rr = rem & 65535;     // 512*128 per layer
    int r = rr >> 7, c4 = rr & 127;
    float4 x = ((const float4*)s)[rem];
    BF4 u;
    u.h[0] = (bf16)x.x; u.h[1] = (bf16)x.y; u.h[2] = (bf16)x.z; u.h[3] = (bf16)x.w;
    ((short4*)d)[((size_t)layer * 1536 + which * 512 + r) * 128 + c4] = u.p;
}

// w_gate/w_up (6,1536,512) -> interleaved (6,3072,512) rows [layer*3072+2r+which]
__global__ void cast_gu(const float* __restrict__ g, const float* __restrict__ uu,
                        bf16* __restrict__ d) {
    int idx = blockIdx.x * 256 + threadIdx.x;    // 2*1179648
    if (idx >= 2359296) return;
    int which = idx / 1179648;
    int rem = idx - which * 1179648;
    const float* s = which == 0 ? g : uu;
    int layer = rem / 196608, rr = rem - layer * 196608;  // 1536*128
    int r = rr >> 7, c4 = rr & 127;
    float4 x = ((const float4*)s)[rem];
    BF4 u;
    u.h[0] = (bf16)x.x; u.h[1] = (bf16)x.y; u.h[2] = (bf16)x.z; u.h[3] = (bf16)x.w;
    ((short4*)d)[((size_t)layer * 3072 + r * 2 + which) * 128 + c4] = u.p;
}

__global__ void cast_embed_pad(const float* __restrict__ s, bf16* __restrict__ d) {
    int i = blockIdx.x * 256 + threadIdx.x;   // 128*128 = 16384 short4s
    int row = i >> 7, c4 = i & 127;
    BF4 u;
    if (row < VOCN) {
        float4 v = ((const float4*)s)[row * 128 + c4];
        u.h[0] = (bf16)v.x; u.h[1] = (bf16)v.y; u.h[2] = (bf16)v.z; u.h[3] = (bf16)v.w;
    } else {
        u.h[0] = (bf16)0.f; u.h[1] = (bf16)0.f; u.h[2] = (bf16)0.f; u.h[3] = (bf16)0.f;
    }
    ((short4*)d)[i] = u.p;
}

// ------------------------------- rmsnorm -> bf16 ---------------------------
__global__ void rmsnorm512(const float* __restrict__ in, const float* __restrict__ w,
                           bf16* __restrict__ out) {
    int row = blockIdx.x, t = threadIdx.x;     // 128 threads
    float4 x = ((const float4*)(in + (size_t)row * 512))[t];
    float s = x.x * x.x + x.y * x.y + x.z * x.z + x.w * x.w;
    for (int m = 1; m < 64; m <<= 1) s += __shfl_xor(s, m);
    __shared__ float red[2];
    if ((t & 63) == 0) red[t >> 6] = s;
    __syncthreads();
    float tot = red[0] + red[1];
    float r = rsqrtf(tot * (1.f / 512.f) + 1e-6f);
    float4 wv = ((const float4*)w)[t];
    BF4 u;
    u.h[0] = (bf16)(x.x * r * wv.x); u.h[1] = (bf16)(x.y * r * wv.y);
    u.h[2] = (bf16)(x.z * r * wv.z); u.h[3] = (bf16)(x.w * r * wv.w);
    ((short4*)(out + (size_t)row * 512))[t] = u.p;
}

// ------------------------------- bf16 MFMA GEMM (128x128) ------------------
// C = A(bf16, MxK rm) @ B(bf16, NxK rm)^T. 128x128 tile, Kstep 32, 4 waves.
// MODE 0: C(f32)=v
// MODE 4: gate/up interleaved cols; Cb[row*Nreal+col/2]=bf16(silu(g)*u)
// MODE 5: fused QKV epilogue: RoPE(q,k)->Qb/Kb bf16 [bh][l][64], v->Vtb
//         [bh][d][l]. Requires N=1536 layout q|k|v and M = b-major tokens.
template <int MODE>
__global__ __launch_bounds__(256) void gemm_bf16(const bf16* __restrict__ A,
                                                 const bf16* __restrict__ B,
                                                 float* __restrict__ C,
                                                 bf16* __restrict__ Cb,
                                                 const float* __restrict__ cosT,
                                                 const float* __restrict__ sinT,
                                                 bf16* __restrict__ Qb,
                                                 bf16* __restrict__ Kb,
                                                 bf16* __restrict__ Vtb,
                                                 int M, int N, int K, int Nreal) {
    __shared__ bf16 As[128 * 32];
    __shared__ bf16 Bs[128 * 32];
    const int tid = threadIdx.x;
    const int wave = tid >> 6, lane = tid & 63;
    const int row0 = blockIdx.y * 128, col0 = blockIdx.x * 128;
    floatx4 acc[4][4];
#pragma unroll
    for (int i = 0; i < 4; ++i)
#pragma unroll
        for (int j = 0; j < 4; ++j) acc[i][j] = (floatx4){0.f, 0.f, 0.f, 0.f};
    const int m0 = (wave & 1) * 64, n0 = (wave >> 1) * 64;
    const int sr = tid >> 2;
    const int ske = (tid & 3) * 8;
    const size_t arow1 = (size_t)(row0 + sr) * K + ske;
    const size_t arow2 = (size_t)(row0 + 64 + sr) * K + ske;
    const size_t brow1 = (size_t)(col0 + sr) * K + ske;
    const size_t brow2 = (size_t)(col0 + 64 + sr) * K + ske;
    char* AsB = (char*)As;
    char* BsB = (char*)Bs;
    const int lds0 = wave * 1024, lds1 = 4096 + wave * 1024;

    for (int k0 = 0; k0 < K; k0 += 32) {
        gload16(A + arow1 + k0, AsB + lds0);
        gload16(A + arow2 + k0, AsB + lds1);
        gload16(B + brow1 + k0, BsB + lds0);
        gload16(B + brow2 + k0, BsB + lds1);
        __syncthreads();
        bf16x8 af[4], bfr[4];
#pragma unroll
        for (int mi = 0; mi < 4; ++mi)
            af[mi] = *(const bf16x8*)(AsB + ((m0 + mi * 16 + (lane & 15)) * 32 + (lane >> 4) * 8) * 2);
#pragma unroll
        for (int ni = 0; ni < 4; ++ni)
            bfr[ni] = *(const bf16x8*)(BsB + ((n0 + ni * 16 + (lane & 15)) * 32 + (lane >> 4) * 8) * 2);
#pragma unroll
        for (int mi = 0; mi < 4; ++mi)
#pragma unroll
            for (int ni = 0; ni < 4; ++ni)
                acc[mi][ni] = __builtin_amdgcn_mfma_f32_16x16x32_bf16(af[mi], bfr[ni], acc[mi][ni], 0, 0, 0);
        __syncthreads();
    }
    const int cr = (lane >> 4) * 4;
    const int cc = lane & 15;
    if (MODE == 5) {
        // wave-uniform 64-col span: segment + head fixed per wave
        int segbase = col0 + n0;
        int seg = segbase >> 9;           // 0=q 1=k 2=v
        int head = (segbase >> 6) & 7;
#pragma unroll
        for (int mi = 0; mi < 4; ++mi) {
#pragma unroll
            for (int r = 0; r < 4; ++r) {
                int row = row0 + m0 + mi * 16 + cr + r;
                int b = row >> 10, l = row & 1023;
                size_t bh = (size_t)(b * 8 + head);
                float x0 = acc[mi][0][r], x1 = acc[mi][1][r];
                float x2 = acc[mi][2][r], x3 = acc[mi][3][r];
                if (seg < 2) {
                    float c0 = cosT[l * 32 + cc], c1 = cosT[l * 32 + 16 + cc];
                    float s0 = sinT[l * 32 + cc], s1 = sinT[l * 32 + 16 + cc];
                    bf16* dst = (seg == 0 ? Qb : Kb) + bh * 65536 + l * 64;
                    dst[cc]      = (bf16)(x0 * c0 - x2 * s0);
                    dst[16 + cc] = (bf16)(x1 * c1 - x3 * s1);
                    dst[32 + cc] = (bf16)(x2 * c0 + x0 * s0);
                    dst[48 + cc] = (bf16)(x3 * c1 + x1 * s1);
                } else {
                    bf16* dst = Vtb + bh * 65536 + l;
                    dst[(size_t)(cc) * 1024]      = (bf16)x0;
                    dst[(size_t)(16 + cc) * 1024] = (bf16)x1;
                    dst[(size_t)(32 + cc) * 1024] = (bf16)x2;
                    dst[(size_t)(48 + cc) * 1024] = (bf16)x3;
                }
            }
        }
        return;
    }
#pragma unroll
    for (int mi = 0; mi < 4; ++mi) {
#pragma unroll
        for (int ni = 0; ni < 4; ++ni) {
#pragma unroll
            for (int r = 0; r < 4; ++r) {
                int row = row0 + m0 + mi * 16 + cr + r;
                int col = col0 + n0 + ni * 16 + cc;
                float v = acc[mi][ni][r];
                if (MODE == 4) {
                    float o = __shfl_xor(v, 1);
                    if (!(lane & 1)) {
                        float sg = v / (1.f + __expf(-v));
                        Cb[(size_t)row * Nreal + (col >> 1)] = (bf16)(sg * o);
                    }
                } else if (col < Nreal) {
                    size_t off = (size_t)row * Nreal + col;
                    if (MODE == 0) C[off] = v;
                }
            }
        }
    }
}

// ---------------------- 64x128-tile GEMM (accumulate) ----------------------
// Tile M=64, N=128, 4 waves each 32x64. Doubles grid fill for N=512 GEMMs.
// MODE 0: C=v  MODE 1: C+=v
template <int MODE>
__global__ __launch_bounds__(256) void gemm64_bf16(const bf16* __restrict__ A,
                                                   const bf16* __restrict__ B,
                                                   float* __restrict__ C,
                                                   int M, int N, int K, int Nreal) {
    __shared__ bf16 As[64 * 32];
    __shared__ bf16 Bs[128 * 32];
    const int tid = threadIdx.x;
    const int wave = tid >> 6, lane = tid & 63;
    const int row0 = blockIdx.y * 64, col0 = blockIdx.x * 128;
    floatx4 acc[2][4];
#pragma unroll
    for (int i = 0; i < 2; ++i)
#pragma unroll
        for (int j = 0; j < 4; ++j) acc[i][j] = (floatx4){0.f, 0.f, 0.f, 0.f};
    const int m0 = (wave & 1) * 32, n0 = (wave >> 1) * 64;
    const int sr = tid >> 2;
    const int ske = (tid & 3) * 8;
    const size_t arow = (size_t)(row0 + sr) * K + ske;
    const size_t brow1 = (size_t)(col0 + sr) * K + ske;
    const size_t brow2 = (size_t)(col0 + 64 + sr) * K + ske;
    char* AsB = (char*)As;
    char* BsB = (char*)Bs;
    const int lds0 = wave * 1024, lds1 = 4096 + wave * 1024;

    for (int k0 = 0; k0 < K; k0 += 32) {
        gload16(A + arow + k0, AsB + tid * 16);
        gload16(B + brow1 + k0, BsB + lds0);
        gload16(B + brow2 + k0, BsB + lds1);
        __syncthreads();
        bf16x8 af[2], bfr[4];
#pragma unroll
        for (int mi = 0; mi < 2; ++mi)
            af[mi] = *(const bf16x8*)(AsB + ((m0 + mi * 16 + (lane & 15)) * 32 + (lane >> 4) * 8) * 2);
#pragma unroll
        for (int ni = 0; ni < 4; ++ni)
            bfr[ni] = *(const bf16x8*)(BsB + ((n0 + ni * 16 + (lane & 15)) * 32 + (lane >> 4) * 8) * 2);
#pragma unroll
        for (int mi = 0; mi < 2; ++mi)
#pragma unroll
            for (int ni = 0; ni < 4; ++ni)
                acc[mi][ni] = __builtin_amdgcn_mfma_f32_16x16x32_bf16(af[mi], bfr[ni], acc[mi][ni], 0, 0, 0);
        __syncthreads();
    }
    const int cr = (lane >> 4) * 4;
    const int cc = lane & 15;
#pragma unroll
    for (int mi = 0; mi < 2; ++mi) {
#pragma unroll
        for (int ni = 0; ni < 4; ++ni) {
#pragma unroll
            for (int r = 0; r < 4; ++r) {
                int row = row0 + m0 + mi * 16 + cr + r;
                int col = col0 + n0 + ni * 16 + cc;
                if (col < Nreal) {
                    size_t off = (size_t)row * Nreal + col;
                    float v = acc[mi][ni][r];
                    if (MODE == 0) C[off] = v;
                    else C[off] += v;
                }
            }
        }
    }
}

// ------------------------- MFMA flash attention ----------------------------
__global__ __launch_bounds__(256) void attn_mfma(const bf16* __restrict__ Qb,
                                                 const bf16* __restrict__ Kb,
                                                 const bf16* __restrict__ Vtb,
                                                 bf16* __restrict__ O) {
    int qt = blockIdx.x, hh = blockIdx.y, b = blockIdx.z;
    int bh = b * 8 + hh;
    int q0 = qt * 64;
    const bf16* Qg = Qb + ((size_t)bh * 1024 + q0) * 64;
    const bf16* Kg = Kb + (size_t)bh * 1024 * 64;
    const bf16* Vg = Vtb + (size_t)bh * 64 * 1024;   // [64 d][1024 l]
    __shared__ bf16 Qs[64 * ATTS];
    __shared__ bf16 Ks[64 * ATTS];
    __shared__ bf16 Vs[64 * ATTS];
    __shared__ bf16 Ps[64 * ATTS];
    int tid = threadIdx.x, wave = tid >> 6, lane = tid & 63;
    int lr = lane & 15, quad = lane >> 4;

#pragma unroll
    for (int it = 0; it < 2; ++it) {
        int cidx = tid + it * 256;
        int row = cidx >> 3, ch = cidx & 7;
        *(bf16x8*)(Qs + row * ATTS + ch * 8) = *(const bf16x8*)(Qg + row * 64 + ch * 8);
    }
    float mrow[4], lrow[4];
    floatx4 Oacc[4];
#pragma unroll
    for (int r = 0; r < 4; ++r) { mrow[r] = -1e30f; lrow[r] = 0.f; }
#pragma unroll
    for (int d0 = 0; d0 < 4; ++d0) Oacc[d0] = (floatx4){0.f, 0.f, 0.f, 0.f};

    int ntiles = qt + 1;
    for (int t = 0; t < ntiles; ++t) {
        int kv0 = t * 64;
        __syncthreads();
#pragma unroll
        for (int it = 0; it < 2; ++it) {
            int cidx = tid + it * 256;
            int row = cidx >> 3, ch = cidx & 7;
            *(bf16x8*)(Ks + row * ATTS + ch * 8) =
                *(const bf16x8*)(Kg + (size_t)(kv0 + row) * 64 + ch * 8);
            *(bf16x8*)(Vs + row * ATTS + ch * 8) =
                *(const bf16x8*)(Vg + (size_t)row * 1024 + kv0 + ch * 8);
        }
        __syncthreads();
        bf16x8 aq[2];
#pragma unroll
        for (int kc = 0; kc < 2; ++kc)
            aq[kc] = *(const bf16x8*)(Qs + (wave * 16 + lr) * ATTS + kc * 32 + quad * 8);
        floatx4 sacc[4];
#pragma unroll
        for (int n0 = 0; n0 < 4; ++n0) {
            bf16x8 bk0 = *(const bf16x8*)(Ks + (n0 * 16 + lr) * ATTS + quad * 8);
            bf16x8 bk1 = *(const bf16x8*)(Ks + (n0 * 16 + lr) * ATTS + 32 + quad * 8);
            floatx4 z = (floatx4){0.f, 0.f, 0.f, 0.f};
            z = __builtin_amdgcn_mfma_f32_16x16x32_bf16(aq[0], bk0, z, 0, 0, 0);
            sacc[n0] = __builtin_amdgcn_mfma_f32_16x16x32_bf16(aq[1], bk1, z, 0, 0, 0);
        }
        float sv[4][4];
#pragma unroll
        for (int n0 = 0; n0 < 4; ++n0)
#pragma unroll
            for (int r = 0; r < 4; ++r) sv[n0][r] = sacc[n0][r] * 0.125f;
        if (t == ntiles - 1) {
#pragma unroll
            for (int n0 = 0; n0 < 4; ++n0)
#pragma unroll
                for (int r = 0; r < 4; ++r)
                    if (n0 * 16 + lr > wave * 16 + quad * 4 + r) sv[n0][r] = -1e30f;
        }
        float al[4];
#pragma unroll
        for (int r = 0; r < 4; ++r) {
            float tm = fmaxf(fmaxf(sv[0][r], sv[1][r]), fmaxf(sv[2][r], sv[3][r]));
            tm = fmaxf(tm, __shfl_xor(tm, 1));
            tm = fmaxf(tm, __shfl_xor(tm, 2));
            tm = fmaxf(tm, __shfl_xor(tm, 4));
            tm = fmaxf(tm, __shfl_xor(tm, 8));
            float mn = fmaxf(mrow[r], tm);
            al[r] = __expf(mrow[r] - mn);
            mrow[r] = mn;
        }
        float rs[4];
#pragma unroll
        for (int r = 0; r < 4; ++r) rs[r] = 0.f;
#pragma unroll
        for (int n0 = 0; n0 < 4; ++n0)
#pragma unroll
            for (int r = 0; r < 4; ++r) {
                float p = __expf(sv[n0][r] - mrow[r]);
                sv[n0][r] = p;
                rs[r] += p;
            }
#pragma unroll
        for (int r = 0; r < 4; ++r) {
            float t2 = rs[r];
            t2 += __shfl_xor(t2, 1);
            t2 += __shfl_xor(t2, 2);
            t2 += __shfl_xor(t2, 4);
            t2 += __shfl_xor(t2, 8);
            lrow[r] = lrow[r] * al[r] + t2;
        }
#pragma unroll
        for (int d0 = 0; d0 < 4; ++d0)
#pragma unroll
            for (int r = 0; r < 4; ++r) Oacc[d0][r] *= al[r];
#pragma unroll
        for (int n0 = 0; n0 < 4; ++n0)
#pragma unroll
            for (int r = 0; r < 4; ++r)
                Ps[(wave * 16 + quad * 4 + r) * ATTS + n0 * 16 + lr] = (bf16)sv[n0][r];
        bf16x8 ap[2];
#pragma unroll
        for (int kc = 0; kc < 2; ++kc)
            ap[kc] = *(const bf16x8*)(Ps + (wave * 16 + lr) * ATTS + kc * 32 + quad * 8);
#pragma unroll
        for (int d0 = 0; d0 < 4; ++d0) {
            bf16x8 bv0 = *(const bf16x8*)(Vs + (d0 * 16 + lr) * ATTS + quad * 8);
            bf16x8 bv1 = *(const bf16x8*)(Vs + (d0 * 16 + lr) * ATTS + 32 + quad * 8);
            Oacc[d0] = __builtin_amdgcn_mfma_f32_16x16x32_bf16(ap[0], bv0, Oacc[d0], 0, 0, 0);
            Oacc[d0] = __builtin_amdgcn_mfma_f32_16x16x32_bf16(ap[1], bv1, Oacc[d0], 0, 0, 0);
        }
    }
    float inv[4];
#pragma unroll
    for (int r = 0; r < 4; ++r) inv[r] = 1.f / lrow[r];
#pragma unroll
    for (int d0 = 0; d0 < 4; ++d0)
#pragma unroll
        for (int r = 0; r < 4; ++r) {
            int row = b * 1024 + q0 + wave * 16 + quad * 4 + r;
            int col = hh * 64 + d0 * 16 + lr;
            O[(size_t)row * 512 + col] = (bf16)(Oacc[d0][r] * inv[r]);
        }
}

// ------------------------------- delta scan --------------------------------
// 32 blocks (one per b,h) x 4 waves. Wave w owns S rows w*8..w*8+7; lane =
// (row, col group of 4). Round 10: 8-token chunked form. Per chunk, with
// A_j = prod a, w_i = u_i/A_i:
//   acc_j = S0.k_j + sum_{i<j} w_i (k_i.k_j);  w_j = bv_j/A_j - b_j acc_j
//   out_j = A_j (S0.q_j + sum_{i<=j} w_i (k_i.q_j))
//   S'    = A_8 (S0 + sum_i w_i k_i)
// All 16 S0-dots are parallel; serial chain = 2 FMA/token. Pair dots
// (k_i.k_j, k_i.q_j) precomputed in staging via shfl_xor within each wave's
// aligned 8-token group, stored compact (28+36 floats/chunk).
__global__ __launch_bounds__(256, 1) void delta_scan(
    const float* __restrict__ P, const float* __restrict__ S_in,
    const float* __restrict__ bbias, const float* __restrict__ abias,
    float* __restrict__ S_out, float* __restrict__ ctx) {
    int bh = blockIdx.x;
    int b = bh >> 3, hh = bh & 7;
    int tid = threadIdx.x;
    int lane = tid & 63;
    int ri = (tid >> 6) * 8 + (lane >> 3);
    int c = lane & 7;
    bool cz = (c == 0);
    __shared__ __align__(16) float ks[64][36], qs[64][36], vs[64][36],
                                   bs[64][36], as_[64][36];
    __shared__ __align__(16) float cs[64][32];
    __shared__ __align__(16) float kkc[8][28];   // chunk kk upper-tri, row-major
    __shared__ __align__(16) float kqc[8][36];   // chunk kq i<=j, row-major
    float4 S = *(const float4*)(S_in + ((size_t)bh * 32 + ri) * 32 + c * 4);

    int sc4 = tid & 7, sr0 = tid >> 3;   // staging: token rows sr0, sr0+32
    float4 bB = *(const float4*)(bbias + hh * 32 + sc4 * 4);
    float4 bA = *(const float4*)(abias + hh * 32 + sc4 * 4);

    for (int c0 = 0; c0 < LSEQ; c0 += 64) {
        __syncthreads();
        const float* Pb = P + ((size_t)(b * 1024 + c0) * 1536) + hh * 32 + sc4 * 4;
#pragma unroll
        for (int it = 0; it < 2; ++it) {
            int tok = sr0 + it * 32;
            const float* pg = Pb + (size_t)tok * 1536;
            float4 kv = *(const float4*)(pg);
            float4 vv = *(const float4*)(pg + 256);
            float4 qv = *(const float4*)(pg + 512);
            float4 bv = *(const float4*)(pg + 768);
            float4 av = *(const float4*)(pg + 1024);
            float ss = kv.x * kv.x + kv.y * kv.y + kv.z * kv.z + kv.w * kv.w;
            ss = sum8(ss);
            float rn = 1.f / fmaxf(sqrtf(ss), 1e-12f);
            kv.x *= rn; kv.y *= rn; kv.z *= rn; kv.w *= rn;
            float4 bo, ao;
            bo.x = 1.f / (1.f + __expf(-(bv.x + bB.x)));
            bo.y = 1.f / (1.f + __expf(-(bv.y + bB.y)));
            bo.z = 1.f / (1.f + __expf(-(bv.z + bB.z)));
            bo.w = 1.f / (1.f + __expf(-(bv.w + bB.w)));
            ao.x = 1.f / (1.f + __expf(-(av.x + bA.x)));
            ao.y = 1.f / (1.f + __expf(-(av.y + bA.y)));
            ao.z = 1.f / (1.f + __expf(-(av.z + bA.z)));
            ao.w = 1.f / (1.f + __expf(-(av.w + bA.w)));
            float4 vo;
            vo.x = bo.x * vv.x; vo.y = bo.y * vv.y;
            vo.z = bo.z * vv.z; vo.w = bo.w * vv.w;
            *(float4*)&ks[tok][sc4 * 4] = kv;
            *(float4*)&vs[tok][sc4 * 4] = vo;
            *(float4*)&qs[tok][sc4 * 4] = qv;
            *(float4*)&bs[tok][sc4 * 4] = bo;
            *(float4*)&as_[tok][sc4 * 4] = ao;
            // ---- chunk pair dots: wave holds tokens of one aligned 8-group.
            int blk = tok >> 3, g = tok & 7;
            int offk = 7 * g - (g * (g - 1)) / 2;
            int offq = 8 * g - (g * (g - 1)) / 2;
            float kq0 = sum8(kv.x * qv.x + kv.y * qv.y + kv.z * qv.z + kv.w * qv.w);
            if (cz) kqc[blk][offq] = kq0;     // (g,g) diagonal
#pragma unroll
            for (int dlt = 1; dlt < 8; ++dlt) {
                float4 ko, qo;
                ko.x = __shfl_xor(kv.x, dlt * 8); ko.y = __shfl_xor(kv.y, dlt * 8);
                ko.z = __shfl_xor(kv.z, dlt * 8); ko.w = __shfl_xor(kv.w, dlt * 8);
                qo.x = __shfl_xor(qv.x, dlt * 8); qo.y = __shfl_xor(qv.y, dlt * 8);
                qo.z = __shfl_xor(qv.z, dlt * 8); qo.w = __shfl_xor(qv.w, dlt * 8);
                float kkv = sum8(kv.x * ko.x + kv.y * ko.y + kv.z * ko.z + kv.w * ko.w);
                float kqv = sum8(kv.x * qo.x + kv.y * qo.y + kv.z * qo.z + kv.w * qo.w);
                int j = g ^ dlt;
                if (cz && g < j) {
                    kkc[blk][offk + j - g - 1] = kkv;
                    kqc[blk][offq + j - g] = kqv;
                }
            }
        }
        __syncthreads();
        for (int blk = 0; blk < 8; ++blk) {
            int t0 = blk * 8;
            // ---- loads (all independent of S; pipeline under dot phase)
            float4 kv[8];
#pragma unroll
            for (int i = 0; i < 8; ++i) kv[i] = *(const float4*)&ks[t0 + i][c * 4];
            float a8[8], b8[8], g8[8];
#pragma unroll
            for (int i = 0; i < 8; ++i) {
                a8[i] = as_[t0 + i][ri];
                b8[i] = bs[t0 + i][ri];
                g8[i] = vs[t0 + i][ri];     // = b*v
            }
            floatx4 kr[7], qr[9];
#pragma unroll
            for (int i = 0; i < 7; ++i) kr[i] = *(const floatx4*)&kkc[blk][i * 4];
#pragma unroll
            for (int i = 0; i < 9; ++i) qr[i] = *(const floatx4*)&kqc[blk][i * 4];
            // ---- 16 parallel S0-dots
            float Dr[8], Qr[8];
#pragma unroll
            for (int i = 0; i < 8; ++i)
                Dr[i] = fmaf(S.w, kv[i].w, fmaf(S.z, kv[i].z, fmaf(S.y, kv[i].y, S.x * kv[i].x)));
#pragma unroll
            for (int i = 0; i < 8; ++i) {
                float4 q = *(const float4*)&qs[t0 + i][c * 4];
                Qr[i] = fmaf(S.w, q.w, fmaf(S.z, q.z, fmaf(S.y, q.y, S.x * q.x)));
            }
#pragma unroll
            for (int i = 0; i < 8; ++i) Dr[i] = sum8(Dr[i]);
#pragma unroll
            for (int i = 0; i < 8; ++i) Qr[i] = sum8(Qr[i]);
            // ---- decay prefixes
            float iA[8], A[8];
            iA[0] = __builtin_amdgcn_rcpf(a8[0]);
            A[0] = a8[0];
#pragma unroll
            for (int i = 1; i < 8; ++i) {
                iA[i] = iA[i - 1] * __builtin_amdgcn_rcpf(a8[i]);
                A[i] = A[i - 1] * a8[i];
            }
#pragma unroll
            for (int i = 0; i < 8; ++i) g8[i] *= iA[i];
            // ---- serial w-chain + triangular corrections (Dr->acc, Qr->out)
            float w[8];
#pragma unroll
            for (int i = 0; i < 8; ++i) {
                w[i] = fmaf(-b8[i], Dr[i], g8[i]);
#pragma unroll
                for (int j = i + 1; j < 8; ++j) {
                    int kx = 7 * i - (i * (i - 1)) / 2 + j - i - 1;
                    Dr[j] = fmaf(w[i], kr[kx >> 2][kx & 3], Dr[j]);
                }
#pragma unroll
                for (int j = i; j < 8; ++j) {
                    int qx = 8 * i - (i * (i - 1)) / 2 + j - i;
                    Qr[j] = fmaf(w[i], qr[qx >> 2][qx & 3], Qr[j]);
                }
            }
            if (cz) {
#pragma unroll
                for (int j = 0; j < 8; ++j) cs[t0 + j][ri] = A[j] * Qr[j];
            }
            // ---- state update
            float4 t4 = S;
#pragma unroll
            for (int i = 0; i < 8; ++i) {
                t4.x = fmaf(w[i], kv[i].x, t4.x);
                t4.y = fmaf(w[i], kv[i].y, t4.y);
                t4.z = fmaf(w[i], kv[i].z, t4.z);
                t4.w = fmaf(w[i], kv[i].w, t4.w);
            }
            S.x = A[7] * t4.x; S.y = A[7] * t4.y;
            S.z = A[7] * t4.z; S.w = A[7] * t4.w;
        }
        __syncthreads();
        int gbase = b * 1024 + c0;
        for (int e = tid; e < 512; e += 256) {
            int t = e >> 3, j4 = e & 7;
            float4 val = *(const float4*)&cs[t][j4 * 4];
            *(float4*)(ctx + (size_t)(gbase + t) * 256 + hh * 32 + j4 * 4) = val;
        }
    }
    *(float4*)(S_out + ((size_t)bh * 32 + ri) * 32 + c * 4) = S;
}

// ------------- ctxbf = bf16(rmsnorm(ctx,nw)*silu(gate)), gate in P@1280 ----
__global__ void ctx_post(const float* __restrict__ ctx, const float* __restrict__ P,
                         const float* __restrict__ nw, bf16* __restrict__ out) {
    int row = blockIdx.x, t = threadIdx.x;  // 64 threads
    float4 x = ((const float4*)(ctx + (size_t)row * SDIMM))[t];
    float s = x.x * x.x + x.y * x.y + x.z * x.z + x.w * x.w;
    for (int m = 1; m < 64; m <<= 1) s += __shfl_xor(s, m);
    float r = rsqrtf(s * (1.f / 256.f) + 1e-6f);
    float4 n = ((const float4*)nw)[t];
    float4 g = ((const float4*)(P + (size_t)row * 1536 + 1280))[t];
    BF4 u;
    u.h[0] = (bf16)(x.x * r * n.x * (g.x / (1.f + __expf(-g.x))));
    u.h[1] = (bf16)(x.y * r * n.y * (g.y / (1.f + __expf(-g.y))));
    u.h[2] = (bf16)(x.z * r * n.z * (g.z / (1.f + __expf(-g.z))));
    u.h[3] = (bf16)(x.w * r * n.w * (g.w / (1.f + __expf(-g.w))));
    ((short4*)(out + (size_t)row * SDIMM))[t] = u.p;
}

// ---------------------------------------------------------------------------
extern "C" void kernel_launch(void* const* d_in, const int* in_sizes, int n_in,
                              void* d_out, int out_size, void* d_ws, size_t ws_size,
                              hipStream_t stream) {
    (void)in_sizes; (void)n_in; (void)out_size; (void)ws_size;
    const int* ids = (const int*)d_in[0];
    const float* state = (const float*)d_in[1];
    const float* embedw = (const float*)d_in[2];
    auto F = [&](int i) { return (const float*)d_in[i]; };

    char* wsb = (char*)d_ws;
    const size_t MB = 1048576;
    float* H    = (float*)(wsb);                 // 0-8 MB
    bf16*  XNbf = (bf16*)(wsb + 8 * MB);         // 8-12 (alias ctxf in delta)
    float* ctxf = (float*)(wsb + 8 * MB);
    bf16*  Hbf  = (bf16*)(wsb + 12 * MB);        // 12-16 (alias ctxb)
    bf16*  ctxb = (bf16*)(wsb + 12 * MB);
    float* P    = (float*)(wsb + 16 * MB);       // 16-40 (delta proj f32)
    bf16*  Obf  = (bf16*)(wsb + 40 * MB);        // 40-44 attn out
    bf16*  Qbuf = (bf16*)(wsb + 44 * MB);        // 44-48
    bf16*  Kbuf = (bf16*)(wsb + 48 * MB);        // 48-52
    bf16*  Vtb  = (bf16*)(wsb + 52 * MB);        // 52-56
    bf16*  A1b  = (bf16*)(wsb + 44 * MB);        // alias Q/K/Vt (dead after attn)
    float* cosT = (float*)(wsb + 58 * MB);
    float* sinT = cosT + 32768;
    float* Sbuf = sinT + 32768;
    char*  wbase = wsb + 59 * MB;
    bf16* wqkv  = (bf16*)(wbase);                        // 6x1536x512
    bf16* wob   = (bf16*)(wbase + 9437184);              // 6x512x512
    bf16* wgu   = (bf16*)(wbase + 12582912);             // 6x3072x512 interleaved
    bf16* wdnb  = (bf16*)(wbase + 31457280);             // 6x512x1536
    bf16* wdR   = (bf16*)(wbase + 40894464);             // 1536x512
    bf16* woutR = (bf16*)(wbase + 42467328);             // 512x256
    bf16* wdW   = (bf16*)(wbase + 42729472);             // 1536x512
    bf16* woutW = (bf16*)(wbase + 44302336);             // 512x256
    bf16* embp  = (bf16*)(wbase + 44564480);             // 128x512 padded

    float* out = (float*)d_out;
    float* logits = out;
    float* Sout = out + 4096 * VOCN;

    // 128x128-tile launches
    auto G0 = [&](const bf16* A, const bf16* B, float* C, int M, int N, int K, int Nreal) {
        gemm_bf16<0><<<dim3(N / 128, M / 128), 256, 0, stream>>>(
            A, B, C, nullptr, nullptr, nullptr, nullptr, nullptr, nullptr, M, N, K, Nreal);
    };
    auto G4 = [&](const bf16* A, const bf16* B, bf16* Cb, int M, int N, int K, int Nreal) {
        gemm_bf16<4><<<dim3(N / 128, M / 128), 256, 0, stream>>>(
            A, B, nullptr, Cb, nullptr, nullptr, nullptr, nullptr, nullptr, M, N, K, Nreal);
    };
    auto G5 = [&](const bf16* A, const bf16* B, int M, int N, int K) {
        gemm_bf16<5><<<dim3(N / 128, M / 128), 256, 0, stream>>>(
            A, B, nullptr, nullptr, cosT, sinT, Qbuf, Kbuf, Vtb, M, N, K, N);
    };
    // 64x128-tile accumulate
    auto G1s = [&](const bf16* A, const bf16* B, float* C, int M, int N, int K) {
        gemm64_bf16<1><<<dim3(N / 128, M / 64), 256, 0, stream>>>(A, B, C, M, N, K, N);
    };
    auto G0s = [&](const bf16* A, const bf16* B, float* C, int M, int N, int K, int Nreal) {
        gemm64_bf16<0><<<dim3(N / 128, M / 64), 256, 0, stream>>>(A, B, C, M, N, K, Nreal);
    };
    auto CP = [&](const float* s, bf16* d, int n4) {
        cast_plain<<<(n4 + 255) / 256, 256, 0, stream>>>(s, d, n4);
    };

    // ---- weight casts ----
    cast_qkv<<<4608, 256, 0, stream>>>(F(24), F(25), F(26), wqkv);
    CP(F(27), wob, 393216);
    cast_gu<<<9216, 256, 0, stream>>>(F(29), F(30), wgu);
    CP(F(31), wdnb, 1179648);
    cast6<<<768, 256, 0, stream>>>(F(3), F(4), F(5), F(6), F(8), F(12), wdR);
    CP(F(10), woutR, 32768);
    cast6<<<768, 256, 0, stream>>>(F(13), F(14), F(15), F(16), F(18), F(22), wdW);
    CP(F(20), woutW, 32768);
    cast_embed_pad<<<64, 256, 0, stream>>>(embedw, embp);

    rope_tables_k<<<128, 256, 0, stream>>>(cosT, sinT);
    embed_k<<<4096, 128, 0, stream>>>(ids, embedw, H);

    // ---- delta read ----
    CP(H, Hbf, 524288);
    G0(Hbf, wdR, P, 4096, 1536, 512, 1536);
    delta_scan<<<32, 256, 0, stream>>>(P, state, F(7), F(9), Sbuf, ctxf);
    ctx_post<<<4096, 64, 0, stream>>>(ctxf, P, F(11), ctxb);
    G1s(ctxb, woutR, H, 4096, 512, 256);

    for (int i = 0; i < 6; ++i) {
        rmsnorm512<<<4096, 128, 0, stream>>>(H, F(23) + (size_t)i * 512, XNbf);
        G5(XNbf, wqkv + (size_t)i * 1536 * 512, 4096, 1536, 512);
        attn_mfma<<<dim3(16, 8, 4), 256, 0, stream>>>(Qbuf, Kbuf, Vtb, Obf);
        G1s(Obf, wob + (size_t)i * 512 * 512, H, 4096, 512, 512);
        rmsnorm512<<<4096, 128, 0, stream>>>(H, F(28) + (size_t)i * 512, XNbf);
        G4(XNbf, wgu + (size_t)i * 3072 * 512, A1b, 4096, 3072, 512, 1536);
        G1s(A1b, wdnb + (size_t)i * 512 * 1536, H, 4096, 512, 1536);
    }

    // ---- delta write ----
    CP(H, Hbf, 524288);
    G0(Hbf, wdW, P, 4096, 1536, 512, 1536);
    delta_scan<<<32, 256, 0, stream>>>(P, Sbuf, F(17), F(19), Sout, ctxf);
    ctx_post<<<4096, 64, 0, stream>>>(ctxf, P, F(21), ctxb);
    G1s(ctxb, woutW, H, 4096, 512, 256);

    rmsnorm512<<<4096, 128, 0, stream>>>(H, F(32), XNbf);
    G0s(XNbf, embp, logits, 4096, 128, 512, VOCN);
}

// Round 3
// 1496.179 us; speedup vs baseline: 1.0164x; 1.0164x over previous
//
#include <hip/hip_runtime.h>
#include <hip/hip_bf16.h>
#include <math.h>

// ---------------------------------------------------------------------------
// BashTransformer forward on MI355X. Round 11: delta_scan keeps round-10's
// verified 8-token chunk math but fixes the schedule: block-level register
// double-buffer (loadblk(blk+1) before stepblk(blk)) so LDS latency hides
// under compute, and Q-phase split (q/kq loads issued early, consumed after
// the w-chain). GEMM/attn/epilogues unchanged from round 8.
// ---------------------------------------------------------------------------

#define LSEQ 1024
#define BATCH 4
#define HIDDEN 512
#define NHEAD 8
#define HDIM 64
#define SHEAD 8
#define SDHD 32
#define SDIMM 256
#define FFND 1536
#define VOCN 63
#define ATTS 72   // attn LDS row stride (elems): 144B = 16B-aligned, 2-way banks

typedef __bf16 bf16;
typedef __attribute__((ext_vector_type(8))) __bf16 bf16x8;
typedef __attribute__((ext_vector_type(4))) float floatx4;

union BF4 { bf16 h[4]; short4 p; };

__device__ __forceinline__ void gload16(const void* g, const void* l) {
    __builtin_amdgcn_global_load_lds(
        (__attribute__((address_space(1))) unsigned int*)(uintptr_t)g,
        (__attribute__((address_space(3))) unsigned int*)(unsigned int)(uintptr_t)l,
        16, 0, 0);
}

// sum over aligned groups of 8 lanes, pure DPP (VALU pipe, no LDS counters)
__device__ __forceinline__ float sum8(float x) {
    x += __int_as_float(__builtin_amdgcn_mov_dpp(__float_as_int(x), 0xB1, 0xF, 0xF, true));
    x += __int_as_float(__builtin_amdgcn_mov_dpp(__float_as_int(x), 0x4E, 0xF, 0xF, true));
    x += __int_as_float(__builtin_amdgcn_mov_dpp(__float_as_int(x), 0x141, 0xF, 0xF, true));
    return x;
}

// ------------------------------- rope tables -------------------------------
__global__ void rope_tables_k(float* __restrict__ cosT, float* __restrict__ sinT) {
    int idx = blockIdx.x * 256 + threadIdx.x;   // 32768 = 1024*32
    int l = idx >> 5, d = idx & 31;
    double ang = (double)l * pow(500000.0, -(double)(2 * d) / 64.0);
    cosT[idx] = (float)cos(ang);
    sinT[idx] = (float)sin(ang);
}

// ------------------------------- embedding ---------------------------------
__global__ void embed_k(const int* __restrict__ ids, const float* __restrict__ emb,
                        float* __restrict__ h) {
    int tok = blockIdx.x;
    int id = ids[tok];
    ((float4*)(h + (size_t)tok * HIDDEN))[threadIdx.x] =
        ((const float4*)(emb + (size_t)id * HIDDEN))[threadIdx.x];
}

// ------------------------------- casts -------------------------------------
__global__ void cast_plain(const float* __restrict__ s, bf16* __restrict__ d, int n4) {
    int i = blockIdx.x * 256 + threadIdx.x;
    if (i >= n4) return;
    float4 v = ((const float4*)s)[i];
    BF4 u;
    u.h[0] = (bf16)v.x; u.h[1] = (bf16)v.y; u.h[2] = (bf16)v.z; u.h[3] = (bf16)v.w;
    ((short4*)d)[i] = u.p;
}

// six 256x512 f32 matrices -> one fused 1536x512 bf16 (order s0..s5)
__global__ void cast6(const float* s0, const float* s1, const float* s2,
                      const float* s3, const float* s4, const float* s5,
                      bf16* __restrict__ d) {
    int i = blockIdx.x * 256 + threadIdx.x;      // 196608 short4s
    if (i >= 196608) return;
    int which = i >> 15, loc = i & 32767;
    const float* s = which == 0 ? s0 : which == 1 ? s1 : which == 2 ? s2
                    : which == 3 ? s3 : which == 4 ? s4 : s5;
    float4 v = ((const float4*)s)[loc];
    BF4 u;
    u.h[0] = (bf16)v.x; u.h[1] = (bf16)v.y; u.h[2] = (bf16)v.z; u.h[3] = (bf16)v.w;
    ((short4*)d)[i] = u.p;
}

// wq/wk/wv (6,512,512) each -> fused (6,1536,512) rows [layer*1536+which*512+r]
__global__ void cast_qkv(const float* __restrict__ q, const float* __restrict__ k,
                         const float* __restrict__ v, bf16* __restrict__ d) {
    int idx = blockIdx.x * 256 + threadIdx.x;    // 3*393216
    if (idx >= 1179648) return;
    int which = idx / 393216;
    int rem = idx - which * 393216;
    const float* s = which == 0 ? q : which == 1 ? k : v;
    int layer = rem >> 16, rr = rem & 65535;     // 512*128 per layer
    int r = rr >> 7, c4 = rr & 127;
    float4 x = ((const float4*)s)[rem];
    BF4 u;
    u.h[0] = (bf16)x.x; u.h[1] = (bf16)x.y; u.h[2] = (bf16)x.z; u.h[3] = (bf16)x.w;
    ((short4*)d)[((size_t)layer * 1536 + which * 512 + r) * 128 + c4] = u.p;
}

// w_gate/w_up (6,1536,512) -> interleaved (6,3072,512) rows [layer*3072+2r+which]
__global__ void cast_gu(const float* __restrict__ g, const float* __restrict__ uu,
                        bf16* __restrict__ d) {
    int idx = blockIdx.x * 256 + threadIdx.x;    // 2*1179648
    if (idx >= 2359296) return;
    int which = idx / 1179648;
    int rem = idx - which * 1179648;
    const float* s = which == 0 ? g : uu;
    int layer = rem / 196608, rr = rem - layer * 196608;  // 1536*128
    int r = rr >> 7, c4 = rr & 127;
    float4 x = ((const float4*)s)[rem];
    BF4 u;
    u.h[0] = (bf16)x.x; u.h[1] = (bf16)x.y; u.h[2] = (bf16)x.z; u.h[3] = (bf16)x.w;
    ((short4*)d)[((size_t)layer * 3072 + r * 2 + which) * 128 + c4] = u.p;
}

__global__ void cast_embed_pad(const float* __restrict__ s, bf16* __restrict__ d) {
    int i = blockIdx.x * 256 + threadIdx.x;   // 128*128 = 16384 short4s
    int row = i >> 7, c4 = i & 127;
    BF4 u;
    if (row < VOCN) {
        float4 v = ((const float4*)s)[row * 128 + c4];
        u.h[0] = (bf16)v.x; u.h[1] = (bf16)v.y; u.h[2] = (bf16)v.z; u.h[3] = (bf16)v.w;
    } else {
        u.h[0] = (bf16)0.f; u.h[1] = (bf16)0.f; u.h[2] = (bf16)0.f; u.h[3] = (bf16)0.f;
    }
    ((short4*)d)[i] = u.p;
}

// ------------------------------- rmsnorm -> bf16 ---------------------------
__global__ void rmsnorm512(const float* __restrict__ in, const float* __restrict__ w,
                           bf16* __restrict__ out) {
    int row = blockIdx.x, t = threadIdx.x;     // 128 threads
    float4 x = ((const float4*)(in + (size_t)row * 512))[t];
    float s = x.x * x.x + x.y * x.y + x.z * x.z + x.w * x.w;
    for (int m = 1; m < 64; m <<= 1) s += __shfl_xor(s, m);
    __shared__ float red[2];
    if ((t & 63) == 0) red[t >> 6] = s;
    __syncthreads();
    float tot = red[0] + red[1];
    float r = rsqrtf(tot * (1.f / 512.f) + 1e-6f);
    float4 wv = ((const float4*)w)[t];
    BF4 u;
    u.h[0] = (bf16)(x.x * r * wv.x); u.h[1] = (bf16)(x.y * r * wv.y);
    u.h[2] = (bf16)(x.z * r * wv.z); u.h[3] = (bf16)(x.w * r * wv.w);
    ((short4*)(out + (size_t)row * 512))[t] = u.p;
}

// ------------------------------- bf16 MFMA GEMM (128x128) ------------------
// C = A(bf16, MxK rm) @ B(bf16, NxK rm)^T. 128x128 tile, Kstep 32, 4 waves.
// MODE 0: C(f32)=v
// MODE 4: gate/up interleaved cols; Cb[row*Nreal+col/2]=bf16(silu(g)*u)
// MODE 5: fused QKV epilogue: RoPE(q,k)->Qb/Kb bf16 [bh][l][64], v->Vtb
//         [bh][d][l]. Requires N=1536 layout q|k|v and M = b-major tokens.
template <int MODE>
__global__ __launch_bounds__(256) void gemm_bf16(const bf16* __restrict__ A,
                                                 const bf16* __restrict__ B,
                                                 float* __restrict__ C,
                                                 bf16* __restrict__ Cb,
                                                 const float* __restrict__ cosT,
                                                 const float* __restrict__ sinT,
                                                 bf16* __restrict__ Qb,
                                                 bf16* __restrict__ Kb,
                                                 bf16* __restrict__ Vtb,
                                                 int M, int N, int K, int Nreal) {
    __shared__ bf16 As[128 * 32];
    __shared__ bf16 Bs[128 * 32];
    const int tid = threadIdx.x;
    const int wave = tid >> 6, lane = tid & 63;
    const int row0 = blockIdx.y * 128, col0 = blockIdx.x * 128;
    floatx4 acc[4][4];
#pragma unroll
    for (int i = 0; i < 4; ++i)
#pragma unroll
        for (int j = 0; j < 4; ++j) acc[i][j] = (floatx4){0.f, 0.f, 0.f, 0.f};
    const int m0 = (wave & 1) * 64, n0 = (wave >> 1) * 64;
    const int sr = tid >> 2;
    const int ske = (tid & 3) * 8;
    const size_t arow1 = (size_t)(row0 + sr) * K + ske;
    const size_t arow2 = (size_t)(row0 + 64 + sr) * K + ske;
    const size_t brow1 = (size_t)(col0 + sr) * K + ske;
    const size_t brow2 = (size_t)(col0 + 64 + sr) * K + ske;
    char* AsB = (char*)As;
    char* BsB = (char*)Bs;
    const int lds0 = wave * 1024, lds1 = 4096 + wave * 1024;

    for (int k0 = 0; k0 < K; k0 += 32) {
        gload16(A + arow1 + k0, AsB + lds0);
        gload16(A + arow2 + k0, AsB + lds1);
        gload16(B + brow1 + k0, BsB + lds0);
        gload16(B + brow2 + k0, BsB + lds1);
        __syncthreads();
        bf16x8 af[4], bfr[4];
#pragma unroll
        for (int mi = 0; mi < 4; ++mi)
            af[mi] = *(const bf16x8*)(AsB + ((m0 + mi * 16 + (lane & 15)) * 32 + (lane >> 4) * 8) * 2);
#pragma unroll
        for (int ni = 0; ni < 4; ++ni)
            bfr[ni] = *(const bf16x8*)(BsB + ((n0 + ni * 16 + (lane & 15)) * 32 + (lane >> 4) * 8) * 2);
#pragma unroll
        for (int mi = 0; mi < 4; ++mi)
#pragma unroll
            for (int ni = 0; ni < 4; ++ni)
                acc[mi][ni] = __builtin_amdgcn_mfma_f32_16x16x32_bf16(af[mi], bfr[ni], acc[mi][ni], 0, 0, 0);
        __syncthreads();
    }
    const int cr = (lane >> 4) * 4;
    const int cc = lane & 15;
    if (MODE == 5) {
        // wave-uniform 64-col span: segment + head fixed per wave
        int segbase = col0 + n0;
        int seg = segbase >> 9;           // 0=q 1=k 2=v
        int head = (segbase >> 6) & 7;
#pragma unroll
        for (int mi = 0; mi < 4; ++mi) {
#pragma unroll
            for (int r = 0; r < 4; ++r) {
                int row = row0 + m0 + mi * 16 + cr + r;
                int b = row >> 10, l = row & 1023;
                size_t bh = (size_t)(b * 8 + head);
                float x0 = acc[mi][0][r], x1 = acc[mi][1][r];
                float x2 = acc[mi][2][r], x3 = acc[mi][3][r];
                if (seg < 2) {
                    float c0 = cosT[l * 32 + cc], c1 = cosT[l * 32 + 16 + cc];
                    float s0 = sinT[l * 32 + cc], s1 = sinT[l * 32 + 16 + cc];
                    bf16* dst = (seg == 0 ? Qb : Kb) + bh * 65536 + l * 64;
                    dst[cc]      = (bf16)(x0 * c0 - x2 * s0);
                    dst[16 + cc] = (bf16)(x1 * c1 - x3 * s1);
                    dst[32 + cc] = (bf16)(x2 * c0 + x0 * s0);
                    dst[48 + cc] = (bf16)(x3 * c1 + x1 * s1);
                } else {
                    bf16* dst = Vtb + bh * 65536 + l;
                    dst[(size_t)(cc) * 1024]      = (bf16)x0;
                    dst[(size_t)(16 + cc) * 1024] = (bf16)x1;
                    dst[(size_t)(32 + cc) * 1024] = (bf16)x2;
                    dst[(size_t)(48 + cc) * 1024] = (bf16)x3;
                }
            }
        }
        return;
    }
#pragma unroll
    for (int mi = 0; mi < 4; ++mi) {
#pragma unroll
        for (int ni = 0; ni < 4; ++ni) {
#pragma unroll
            for (int r = 0; r < 4; ++r) {
                int row = row0 + m0 + mi * 16 + cr + r;
                int col = col0 + n0 + ni * 16 + cc;
                float v = acc[mi][ni][r];
                if (MODE == 4) {
                    float o = __shfl_xor(v, 1);
                    if (!(lane & 1)) {
                        float sg = v / (1.f + __expf(-v));
                        Cb[(size_t)row * Nreal + (col >> 1)] = (bf16)(sg * o);
                    }
                } else if (col < Nreal) {
                    size_t off = (size_t)row * Nreal + col;
                    if (MODE == 0) C[off] = v;
                }
            }
        }
    }
}

// ---------------------- 64x128-tile GEMM (accumulate) ----------------------
// Tile M=64, N=128, 4 waves each 32x64. Doubles grid fill for N=512 GEMMs.
// MODE 0: C=v  MODE 1: C+=v
template <int MODE>
__global__ __launch_bounds__(256) void gemm64_bf16(const bf16* __restrict__ A,
                                                   const bf16* __restrict__ B,
                                                   float* __restrict__ C,
                                                   int M, int N, int K, int Nreal) {
    __shared__ bf16 As[64 * 32];
    __shared__ bf16 Bs[128 * 32];
    const int tid = threadIdx.x;
    const int wave = tid >> 6, lane = tid & 63;
    const int row0 = blockIdx.y * 64, col0 = blockIdx.x * 128;
    floatx4 acc[2][4];
#pragma unroll
    for (int i = 0; i < 2; ++i)
#pragma unroll
        for (int j = 0; j < 4; ++j) acc[i][j] = (floatx4){0.f, 0.f, 0.f, 0.f};
    const int m0 = (wave & 1) * 32, n0 = (wave >> 1) * 64;
    const int sr = tid >> 2;
    const int ske = (tid & 3) * 8;
    const size_t arow = (size_t)(row0 + sr) * K + ske;
    const size_t brow1 = (size_t)(col0 + sr) * K + ske;
    const size_t brow2 = (size_t)(col0 + 64 + sr) * K + ske;
    char* AsB = (char*)As;
    char* BsB = (char*)Bs;
    const int lds0 = wave * 1024, lds1 = 4096 + wave * 1024;

    for (int k0 = 0; k0 < K; k0 += 32) {
        gload16(A + arow + k0, AsB + tid * 16);
        gload16(B + brow1 + k0, BsB + lds0);
        gload16(B + brow2 + k0, BsB + lds1);
        __syncthreads();
        bf16x8 af[2], bfr[4];
#pragma unroll
        for (int mi = 0; mi < 2; ++mi)
            af[mi] = *(const bf16x8*)(AsB + ((m0 + mi * 16 + (lane & 15)) * 32 + (lane >> 4) * 8) * 2);
#pragma unroll
        for (int ni = 0; ni < 4; ++ni)
            bfr[ni] = *(const bf16x8*)(BsB + ((n0 + ni * 16 + (lane & 15)) * 32 + (lane >> 4) * 8) * 2);
#pragma unroll
        for (int mi = 0; mi < 2; ++mi)
#pragma unroll
            for (int ni = 0; ni < 4; ++ni)
                acc[mi][ni] = __builtin_amdgcn_mfma_f32_16x16x32_bf16(af[mi], bfr[ni], acc[mi][ni], 0, 0, 0);
        __syncthreads();
    }
    const int cr = (lane >> 4) * 4;
    const int cc = lane & 15;
#pragma unroll
    for (int mi = 0; mi < 2; ++mi) {
#pragma unroll
        for (int ni = 0; ni < 4; ++ni) {
#pragma unroll
            for (int r = 0; r < 4; ++r) {
                int row = row0 + m0 + mi * 16 + cr + r;
                int col = col0 + n0 + ni * 16 + cc;
                if (col < Nreal) {
                    size_t off = (size_t)row * Nreal + col;
                    float v = acc[mi][ni][r];
                    if (MODE == 0) C[off] = v;
                    else C[off] += v;
                }
            }
        }
    }
}

// ------------------------- MFMA flash attention ----------------------------
__global__ __launch_bounds__(256) void attn_mfma(const bf16* __restrict__ Qb,
                                                 const bf16* __restrict__ Kb,
                                                 const bf16* __restrict__ Vtb,
                                                 bf16* __restrict__ O) {
    int qt = blockIdx.x, hh = blockIdx.y, b = blockIdx.z;
    int bh = b * 8 + hh;
    int q0 = qt * 64;
    const bf16* Qg = Qb + ((size_t)bh * 1024 + q0) * 64;
    const bf16* Kg = Kb + (size_t)bh * 1024 * 64;
    const bf16* Vg = Vtb + (size_t)bh * 64 * 1024;   // [64 d][1024 l]
    __shared__ bf16 Qs[64 * ATTS];
    __shared__ bf16 Ks[64 * ATTS];
    __shared__ bf16 Vs[64 * ATTS];
    __shared__ bf16 Ps[64 * ATTS];
    int tid = threadIdx.x, wave = tid >> 6, lane = tid & 63;
    int lr = lane & 15, quad = lane >> 4;

#pragma unroll
    for (int it = 0; it < 2; ++it) {
        int cidx = tid + it * 256;
        int row = cidx >> 3, ch = cidx & 7;
        *(bf16x8*)(Qs + row * ATTS + ch * 8) = *(const bf16x8*)(Qg + row * 64 + ch * 8);
    }
    float mrow[4], lrow[4];
    floatx4 Oacc[4];
#pragma unroll
    for (int r = 0; r < 4; ++r) { mrow[r] = -1e30f; lrow[r] = 0.f; }
#pragma unroll
    for (int d0 = 0; d0 < 4; ++d0) Oacc[d0] = (floatx4){0.f, 0.f, 0.f, 0.f};

    int ntiles = qt + 1;
    for (int t = 0; t < ntiles; ++t) {
        int kv0 = t * 64;
        __syncthreads();
#pragma unroll
        for (int it = 0; it < 2; ++it) {
            int cidx = tid + it * 256;
            int row = cidx >> 3, ch = cidx & 7;
            *(bf16x8*)(Ks + row * ATTS + ch * 8) =
                *(const bf16x8*)(Kg + (size_t)(kv0 + row) * 64 + ch * 8);
            *(bf16x8*)(Vs + row * ATTS + ch * 8) =
                *(const bf16x8*)(Vg + (size_t)row * 1024 + kv0 + ch * 8);
        }
        __syncthreads();
        bf16x8 aq[2];
#pragma unroll
        for (int kc = 0; kc < 2; ++kc)
            aq[kc] = *(const bf16x8*)(Qs + (wave * 16 + lr) * ATTS + kc * 32 + quad * 8);
        floatx4 sacc[4];
#pragma unroll
        for (int n0 = 0; n0 < 4; ++n0) {
            bf16x8 bk0 = *(const bf16x8*)(Ks + (n0 * 16 + lr) * ATTS + quad * 8);
            bf16x8 bk1 = *(const bf16x8*)(Ks + (n0 * 16 + lr) * ATTS + 32 + quad * 8);
            floatx4 z = (floatx4){0.f, 0.f, 0.f, 0.f};
            z = __builtin_amdgcn_mfma_f32_16x16x32_bf16(aq[0], bk0, z, 0, 0, 0);
            sacc[n0] = __builtin_amdgcn_mfma_f32_16x16x32_bf16(aq[1], bk1, z, 0, 0, 0);
        }
        float sv[4][4];
#pragma unroll
        for (int n0 = 0; n0 < 4; ++n0)
#pragma unroll
            for (int r = 0; r < 4; ++r) sv[n0][r] = sacc[n0][r] * 0.125f;
        if (t == ntiles - 1) {
#pragma unroll
            for (int n0 = 0; n0 < 4; ++n0)
#pragma unroll
                for (int r = 0; r < 4; ++r)
                    if (n0 * 16 + lr > wave * 16 + quad * 4 + r) sv[n0][r] = -1e30f;
        }
        float al[4];
#pragma unroll
        for (int r = 0; r < 4; ++r) {
            float tm = fmaxf(fmaxf(sv[0][r], sv[1][r]), fmaxf(sv[2][r], sv[3][r]));
            tm = fmaxf(tm, __shfl_xor(tm, 1));
            tm = fmaxf(tm, __shfl_xor(tm, 2));
            tm = fmaxf(tm, __shfl_xor(tm, 4));
            tm = fmaxf(tm, __shfl_xor(tm, 8));
            float mn = fmaxf(mrow[r], tm);
            al[r] = __expf(mrow[r] - mn);
            mrow[r] = mn;
        }
        float rs[4];
#pragma unroll
        for (int r = 0; r < 4; ++r) rs[r] = 0.f;
#pragma unroll
        for (int n0 = 0; n0 < 4; ++n0)
#pragma unroll
            for (int r = 0; r < 4; ++r) {
                float p = __expf(sv[n0][r] - mrow[r]);
                sv[n0][r] = p;
                rs[r] += p;
            }
#pragma unroll
        for (int r = 0; r < 4; ++r) {
            float t2 = rs[r];
            t2 += __shfl_xor(t2, 1);
            t2 += __shfl_xor(t2, 2);
            t2 += __shfl_xor(t2, 4);
            t2 += __shfl_xor(t2, 8);
            lrow[r] = lrow[r] * al[r] + t2;
        }
#pragma unroll
        for (int d0 = 0; d0 < 4; ++d0)
#pragma unroll
            for (int r = 0; r < 4; ++r) Oacc[d0][r] *= al[r];
#pragma unroll
        for (int n0 = 0; n0 < 4; ++n0)
#pragma unroll
            for (int r = 0; r < 4; ++r)
                Ps[(wave * 16 + quad * 4 + r) * ATTS + n0 * 16 + lr] = (bf16)sv[n0][r];
        bf16x8 ap[2];
#pragma unroll
        for (int kc = 0; kc < 2; ++kc)
            ap[kc] = *(const bf16x8*)(Ps + (wave * 16 + lr) * ATTS + kc * 32 + quad * 8);
#pragma unroll
        for (int d0 = 0; d0 < 4; ++d0) {
            bf16x8 bv0 = *(const bf16x8*)(Vs + (d0 * 16 + lr) * ATTS + quad * 8);
            bf16x8 bv1 = *(const bf16x8*)(Vs + (d0 * 16 + lr) * ATTS + 32 + quad * 8);
            Oacc[d0] = __builtin_amdgcn_mfma_f32_16x16x32_bf16(ap[0], bv0, Oacc[d0], 0, 0, 0);
            Oacc[d0] = __builtin_amdgcn_mfma_f32_16x16x32_bf16(ap[1], bv1, Oacc[d0], 0, 0, 0);
        }
    }
    float inv[4];
#pragma unroll
    for (int r = 0; r < 4; ++r) inv[r] = 1.f / lrow[r];
#pragma unroll
    for (int d0 = 0; d0 < 4; ++d0)
#pragma unroll
        for (int r = 0; r < 4; ++r) {
            int row = b * 1024 + q0 + wave * 16 + quad * 4 + r;
            int col = hh * 64 + d0 * 16 + lr;
            O[(size_t)row * 512 + col] = (bf16)(Oacc[d0][r] * inv[r]);
        }
}

// ------------------------------- delta scan --------------------------------
// 32 blocks (one per b,h) x 4 waves. Wave w owns S rows w*8..w*8+7; lane =
// (row, col group of 4). Round 11: round-10's verified 8-token chunk math
// with a fixed schedule — block-level register double-buffer (RA/RB) so the
// next block's LDS loads overlap the current block's compute, and the Q
// phase split so q/kq loads issue early and are consumed after the w-chain.
//   acc_j = S0.k_j + sum_{i<j} w_i (k_i.k_j);  w_j = bv_j/A_j - b_j acc_j
//   out_j = A_j (S0.q_j + sum_{i<=j} w_i (k_i.q_j))
//   S'    = A_8 (S0 + sum_i w_i k_i)
__global__ __launch_bounds__(256, 1) void delta_scan(
    const float* __restrict__ P, const float* __restrict__ S_in,
    const float* __restrict__ bbias, const float* __restrict__ abias,
    float* __restrict__ S_out, float* __restrict__ ctx) {
    int bh = blockIdx.x;
    int b = bh >> 3, hh = bh & 7;
    int tid = threadIdx.x;
    int lane = tid & 63;
    int ri = (tid >> 6) * 8 + (lane >> 3);
    int c = lane & 7;
    bool cz = (c == 0);
    // ks/vs/bs/as_ padded to 72 rows (block-8 prefetch reads rows 64..71,
    // values unused); qs only read for blk<8 so 64 rows suffice.
    __shared__ __align__(16) float ks[72][36], vs[72][36], bs[72][36], as_[72][36];
    __shared__ __align__(16) float qs[64][36];
    __shared__ __align__(16) float cs[64][32];
    __shared__ __align__(16) float kkc[9][28];   // chunk kk upper-tri (pad row 8)
    __shared__ __align__(16) float kqc[8][36];   // chunk kq i<=j, row-major
    float4 S = *(const float4*)(S_in + ((size_t)bh * 32 + ri) * 32 + c * 4);

    int sc4 = tid & 7, sr0 = tid >> 3;   // staging: token rows sr0, sr0+32
    float4 bB = *(const float4*)(bbias + hh * 32 + sc4 * 4);
    float4 bA = *(const float4*)(abias + hh * 32 + sc4 * 4);

    struct Blk {
        float4 kv[8];
        float a[8], b[8], g[8];
        floatx4 kr[7];
    };
    Blk RA, RB;

    auto loadblk = [&](int blk, Blk& R) {
        int t0 = blk * 8;
#pragma unroll
        for (int i = 0; i < 8; ++i) R.kv[i] = *(const float4*)&ks[t0 + i][c * 4];
#pragma unroll
        for (int i = 0; i < 8; ++i) {
            R.a[i] = as_[t0 + i][ri];
            R.b[i] = bs[t0 + i][ri];
            R.g[i] = vs[t0 + i][ri];     // = b*v
        }
#pragma unroll
        for (int i = 0; i < 7; ++i) R.kr[i] = *(const floatx4*)&kkc[blk][i * 4];
    };
    auto stepblk = [&](const Blk& R, int blk) {
        int t0 = blk * 8;
        // issue q / kq-table loads first; consumed after the w-chain
        float4 qv[8];
#pragma unroll
        for (int i = 0; i < 8; ++i) qv[i] = *(const float4*)&qs[t0 + i][c * 4];
        floatx4 qr[9];
#pragma unroll
        for (int i = 0; i < 9; ++i) qr[i] = *(const floatx4*)&kqc[blk][i * 4];
        // 8 parallel k-dots against block-start S
        float Dr[8];
#pragma unroll
        for (int i = 0; i < 8; ++i)
            Dr[i] = sum8(fmaf(S.w, R.kv[i].w,
                        fmaf(S.z, R.kv[i].z, fmaf(S.y, R.kv[i].y, S.x * R.kv[i].x))));
        // decay prefixes
        float A[8];
        A[0] = R.a[0];
#pragma unroll
        for (int i = 1; i < 8; ++i) A[i] = A[i - 1] * R.a[i];
        float g8[8];
#pragma unroll
        for (int i = 0; i < 8; ++i) g8[i] = R.g[i] * __builtin_amdgcn_rcpf(A[i]);
        // serial w-chain with kk triangular corrections
        float w[8];
#pragma unroll
        for (int i = 0; i < 8; ++i) {
            w[i] = fmaf(-R.b[i], Dr[i], g8[i]);
#pragma unroll
            for (int j = i + 1; j < 8; ++j) {
                int kx = 7 * i - (i * (i - 1)) / 2 + j - i - 1;
                Dr[j] = fmaf(w[i], R.kr[kx >> 2][kx & 3], Dr[j]);
            }
        }
        // q-dots against block-start S + triangular kq corrections (w known)
        float Qr[8];
#pragma unroll
        for (int i = 0; i < 8; ++i)
            Qr[i] = sum8(fmaf(S.w, qv[i].w,
                        fmaf(S.z, qv[i].z, fmaf(S.y, qv[i].y, S.x * qv[i].x))));
#pragma unroll
        for (int j = 0; j < 8; ++j) {
#pragma unroll
            for (int i = 0; i <= j; ++i) {
                int qx = 8 * i - (i * (i - 1)) / 2 + j - i;
                Qr[j] = fmaf(w[i], qr[qx >> 2][qx & 3], Qr[j]);
            }
            if (cz) cs[t0 + j][ri] = A[j] * Qr[j];
        }
        // state update
        float4 t4 = S;
#pragma unroll
        for (int i = 0; i < 8; ++i) {
            t4.x = fmaf(w[i], R.kv[i].x, t4.x);
            t4.y = fmaf(w[i], R.kv[i].y, t4.y);
            t4.z = fmaf(w[i], R.kv[i].z, t4.z);
            t4.w = fmaf(w[i], R.kv[i].w, t4.w);
        }
        S.x = A[7] * t4.x; S.y = A[7] * t4.y;
        S.z = A[7] * t4.z; S.w = A[7] * t4.w;
    };

    for (int c0 = 0; c0 < LSEQ; c0 += 64) {
        __syncthreads();
        const float* Pb = P + ((size_t)(b * 1024 + c0) * 1536) + hh * 32 + sc4 * 4;
#pragma unroll
        for (int it = 0; it < 2; ++it) {
            int tok = sr0 + it * 32;
            const float* pg = Pb + (size_t)tok * 1536;
            float4 kv = *(const float4*)(pg);
            float4 vv = *(const float4*)(pg + 256);
            float4 qv = *(const float4*)(pg + 512);
            float4 bv = *(const float4*)(pg + 768);
            float4 av = *(const float4*)(pg + 1024);
            float ss = kv.x * kv.x + kv.y * kv.y + kv.z * kv.z + kv.w * kv.w;
            ss = sum8(ss);
            float rn = 1.f / fmaxf(sqrtf(ss), 1e-12f);
            kv.x *= rn; kv.y *= rn; kv.z *= rn; kv.w *= rn;
            float4 bo, ao;
            bo.x = 1.f / (1.f + __expf(-(bv.x + bB.x)));
            bo.y = 1.f / (1.f + __expf(-(bv.y + bB.y)));
            bo.z = 1.f / (1.f + __expf(-(bv.z + bB.z)));
            bo.w = 1.f / (1.f + __expf(-(bv.w + bB.w)));
            ao.x = 1.f / (1.f + __expf(-(av.x + bA.x)));
            ao.y = 1.f / (1.f + __expf(-(av.y + bA.y)));
            ao.z = 1.f / (1.f + __expf(-(av.z + bA.z)));
            ao.w = 1.f / (1.f + __expf(-(av.w + bA.w)));
            float4 vo;
            vo.x = bo.x * vv.x; vo.y = bo.y * vv.y;
            vo.z = bo.z * vv.z; vo.w = bo.w * vv.w;
            *(float4*)&ks[tok][sc4 * 4] = kv;
            *(float4*)&vs[tok][sc4 * 4] = vo;
            *(float4*)&qs[tok][sc4 * 4] = qv;
            *(float4*)&bs[tok][sc4 * 4] = bo;
            *(float4*)&as_[tok][sc4 * 4] = ao;
            // ---- chunk pair dots: wave holds tokens of one aligned 8-group.
            int blk = tok >> 3, g = tok & 7;
            int offk = 7 * g - (g * (g - 1)) / 2;
            int offq = 8 * g - (g * (g - 1)) / 2;
            float kq0 = sum8(kv.x * qv.x + kv.y * qv.y + kv.z * qv.z + kv.w * qv.w);
            if (cz) kqc[blk][offq] = kq0;     // (g,g) diagonal
#pragma unroll
            for (int dlt = 1; dlt < 8; ++dlt) {
                float4 ko, qo;
                ko.x = __shfl_xor(kv.x, dlt * 8); ko.y = __shfl_xor(kv.y, dlt * 8);
                ko.z = __shfl_xor(kv.z, dlt * 8); ko.w = __shfl_xor(kv.w, dlt * 8);
                qo.x = __shfl_xor(qv.x, dlt * 8); qo.y = __shfl_xor(qv.y, dlt * 8);
                qo.z = __shfl_xor(qv.z, dlt * 8); qo.w = __shfl_xor(qv.w, dlt * 8);
                float kkv = sum8(kv.x * ko.x + kv.y * ko.y + kv.z * ko.z + kv.w * ko.w);
                float kqv = sum8(kv.x * qo.x + kv.y * qo.y + kv.z * qo.z + kv.w * qo.w);
                int j = g ^ dlt;
                if (cz && g < j) {
                    kkc[blk][offk + j - g - 1] = kkv;
                    kqc[blk][offq + j - g] = kqv;
                }
            }
        }
        __syncthreads();
        // ---- software-pipelined block loop (register double-buffer)
        loadblk(0, RA);
        for (int blk = 0; blk < 8; blk += 2) {
            loadblk(blk + 1, RB);
            stepblk(RA, blk);
            loadblk(blk + 2, RA);   // blk==6 -> block 8: pad rows, unused
            stepblk(RB, blk + 1);
        }
        __syncthreads();
        int gbase = b * 1024 + c0;
        for (int e = tid; e < 512; e += 256) {
            int t = e >> 3, j4 = e & 7;
            float4 val = *(const float4*)&cs[t][j4 * 4];
            *(float4*)(ctx + (size_t)(gbase + t) * 256 + hh * 32 + j4 * 4) = val;
        }
    }
    *(float4*)(S_out + ((size_t)bh * 32 + ri) * 32 + c * 4) = S;
}

// ------------- ctxbf = bf16(rmsnorm(ctx,nw)*silu(gate)), gate in P@1280 ----
__global__ void ctx_post(const float* __restrict__ ctx, const float* __restrict__ P,
                         const float* __restrict__ nw, bf16* __restrict__ out) {
    int row = blockIdx.x, t = threadIdx.x;  // 64 threads
    float4 x = ((const float4*)(ctx + (size_t)row * SDIMM))[t];
    float s = x.x * x.x + x.y * x.y + x.z * x.z + x.w * x.w;
    for (int m = 1; m < 64; m <<= 1) s += __shfl_xor(s, m);
    float r = rsqrtf(s * (1.f / 256.f) + 1e-6f);
    float4 n = ((const float4*)nw)[t];
    float4 g = ((const float4*)(P + (size_t)row * 1536 + 1280))[t];
    BF4 u;
    u.h[0] = (bf16)(x.x * r * n.x * (g.x / (1.f + __expf(-g.x))));
    u.h[1] = (bf16)(x.y * r * n.y * (g.y / (1.f + __expf(-g.y))));
    u.h[2] = (bf16)(x.z * r * n.z * (g.z / (1.f + __expf(-g.z))));
    u.h[3] = (bf16)(x.w * r * n.w * (g.w / (1.f + __expf(-g.w))));
    ((short4*)(out + (size_t)row * SDIMM))[t] = u.p;
}

// ---------------------------------------------------------------------------
extern "C" void kernel_launch(void* const* d_in, const int* in_sizes, int n_in,
                              void* d_out, int out_size, void* d_ws, size_t ws_size,
                              hipStream_t stream) {
    (void)in_sizes; (void)n_in; (void)out_size; (void)ws_size;
    const int* ids = (const int*)d_in[0];
    const float* state = (const float*)d_in[1];
    const float* embedw = (const float*)d_in[2];
    auto F = [&](int i) { return (const float*)d_in[i]; };

    char* wsb = (char*)d_ws;
    const size_t MB = 1048576;
    float* H    = (float*)(wsb);                 // 0-8 MB
    bf16*  XNbf = (bf16*)(wsb + 8 * MB);         // 8-12 (alias ctxf in delta)
    float* ctxf = (float*)(wsb + 8 * MB);
    bf16*  Hbf  = (bf16*)(wsb + 12 * MB);        // 12-16 (alias ctxb)
    bf16*  ctxb = (bf16*)(wsb + 12 * MB);
    float* P    = (float*)(wsb + 16 * MB);       // 16-40 (delta proj f32)
    bf16*  Obf  = (bf16*)(wsb + 40 * MB);        // 40-44 attn out
    bf16*  Qbuf = (bf16*)(wsb + 44 * MB);        // 44-48
    bf16*  Kbuf = (bf16*)(wsb + 48 * MB);        // 48-52
    bf16*  Vtb  = (bf16*)(wsb + 52 * MB);        // 52-56
    bf16*  A1b  = (bf16*)(wsb + 44 * MB);        // alias Q/K/Vt (dead after attn)
    float* cosT = (float*)(wsb + 58 * MB);
    float* sinT = cosT + 32768;
    float* Sbuf = sinT + 32768;
    char*  wbase = wsb + 59 * MB;
    bf16* wqkv  = (bf16*)(wbase);                        // 6x1536x512
    bf16* wob   = (bf16*)(wbase + 9437184);              // 6x512x512
    bf16* wgu   = (bf16*)(wbase + 12582912);             // 6x3072x512 interleaved
    bf16* wdnb  = (bf16*)(wbase + 31457280);             // 6x512x1536
    bf16* wdR   = (bf16*)(wbase + 40894464);             // 1536x512
    bf16* woutR = (bf16*)(wbase + 42467328);             // 512x256
    bf16* wdW   = (bf16*)(wbase + 42729472);             // 1536x512
    bf16* woutW = (bf16*)(wbase + 44302336);             // 512x256
    bf16* embp  = (bf16*)(wbase + 44564480);             // 128x512 padded

    float* out = (float*)d_out;
    float* logits = out;
    float* Sout = out + 4096 * VOCN;

    // 128x128-tile launches
    auto G0 = [&](const bf16* A, const bf16* B, float* C, int M, int N, int K, int Nreal) {
        gemm_bf16<0><<<dim3(N / 128, M / 128), 256, 0, stream>>>(
            A, B, C, nullptr, nullptr, nullptr, nullptr, nullptr, nullptr, M, N, K, Nreal);
    };
    auto G4 = [&](const bf16* A, const bf16* B, bf16* Cb, int M, int N, int K, int Nreal) {
        gemm_bf16<4><<<dim3(N / 128, M / 128), 256, 0, stream>>>(
            A, B, nullptr, Cb, nullptr, nullptr, nullptr, nullptr, nullptr, M, N, K, Nreal);
    };
    auto G5 = [&](const bf16* A, const bf16* B, int M, int N, int K) {
        gemm_bf16<5><<<dim3(N / 128, M / 128), 256, 0, stream>>>(
            A, B, nullptr, nullptr, cosT, sinT, Qbuf, Kbuf, Vtb, M, N, K, N);
    };
    // 64x128-tile accumulate
    auto G1s = [&](const bf16* A, const bf16* B, float* C, int M, int N, int K) {
        gemm64_bf16<1><<<dim3(N / 128, M / 64), 256, 0, stream>>>(A, B, C, M, N, K, N);
    };
    auto G0s = [&](const bf16* A, const bf16* B, float* C, int M, int N, int K, int Nreal) {
        gemm64_bf16<0><<<dim3(N / 128, M / 64), 256, 0, stream>>>(A, B, C, M, N, K, Nreal);
    };
    auto CP = [&](const float* s, bf16* d, int n4) {
        cast_plain<<<(n4 + 255) / 256, 256, 0, stream>>>(s, d, n4);
    };

    // ---- weight casts ----
    cast_qkv<<<4608, 256, 0, stream>>>(F(24), F(25), F(26), wqkv);
    CP(F(27), wob, 393216);
    cast_gu<<<9216, 256, 0, stream>>>(F(29), F(30), wgu);
    CP(F(31), wdnb, 1179648);
    cast6<<<768, 256, 0, stream>>>(F(3), F(4), F(5), F(6), F(8), F(12), wdR);
    CP(F(10), woutR, 32768);
    cast6<<<768, 256, 0, stream>>>(F(13), F(14), F(15), F(16), F(18), F(22), wdW);
    CP(F(20), woutW, 32768);
    cast_embed_pad<<<64, 256, 0, stream>>>(embedw, embp);

    rope_tables_k<<<128, 256, 0, stream>>>(cosT, sinT);
    embed_k<<<4096, 128, 0, stream>>>(ids, embedw, H);

    // ---- delta read ----
    CP(H, Hbf, 524288);
    G0(Hbf, wdR, P, 4096, 1536, 512, 1536);
    delta_scan<<<32, 256, 0, stream>>>(P, state, F(7), F(9), Sbuf, ctxf);
    ctx_post<<<4096, 64, 0, stream>>>(ctxf, P, F(11), ctxb);
    G1s(ctxb, woutR, H, 4096, 512, 256);

    for (int i = 0; i < 6; ++i) {
        rmsnorm512<<<4096, 128, 0, stream>>>(H, F(23) + (size_t)i * 512, XNbf);
        G5(XNbf, wqkv + (size_t)i * 1536 * 512, 4096, 1536, 512);
        attn_mfma<<<dim3(16, 8, 4), 256, 0, stream>>>(Qbuf, Kbuf, Vtb, Obf);
        G1s(Obf, wob + (size_t)i * 512 * 512, H, 4096, 512, 512);
        rmsnorm512<<<4096, 128, 0, stream>>>(H, F(28) + (size_t)i * 512, XNbf);
        G4(XNbf, wgu + (size_t)i * 3072 * 512, A1b, 4096, 3072, 512, 1536);
        G1s(A1b, wdnb + (size_t)i * 512 * 1536, H, 4096, 512, 1536);
    }

    // ---- delta write ----
    CP(H, Hbf, 524288);
    G0(Hbf, wdW, P, 4096, 1536, 512, 1536);
    delta_scan<<<32, 256, 0, stream>>>(P, Sbuf, F(17), F(19), Sout, ctxf);
    ctx_post<<<4096, 64, 0, stream>>>(ctxf, P, F(21), ctxb);
    G1s(ctxb, woutW, H, 4096, 512, 256);

    rmsnorm512<<<4096, 128, 0, stream>>>(H, F(32), XNbf);
    G0s(XNbf, embp, logits, 4096, 128, 512, VOCN);
}

// Round 4
// 1494.104 us; speedup vs baseline: 1.0178x; 1.0014x over previous
//
#include <hip/hip_runtime.h>
#include <hip/hip_bf16.h>
#include <math.h>

// ---------------------------------------------------------------------------
// BashTransformer forward on MI355X. Round 12: delta_scan reverts to the
// round-9 verified 2-token pair math; mapping changed to 16 blocks x 512
// threads with TWO (b,h) chains per block (2 waves/SIMD co-residency) so
// independent chains fill each other's latency stalls. LDS staging
// duplicated per half (112 KB/block). GEMM/attn/epilogues unchanged.
// ---------------------------------------------------------------------------

#define LSEQ 1024
#define BATCH 4
#define HIDDEN 512
#define NHEAD 8
#define HDIM 64
#define SHEAD 8
#define SDHD 32
#define SDIMM 256
#define FFND 1536
#define VOCN 63
#define ATTS 72   // attn LDS row stride (elems): 144B = 16B-aligned, 2-way banks

typedef __bf16 bf16;
typedef __attribute__((ext_vector_type(8))) __bf16 bf16x8;
typedef __attribute__((ext_vector_type(4))) float floatx4;

union BF4 { bf16 h[4]; short4 p; };

__device__ __forceinline__ void gload16(const void* g, const void* l) {
    __builtin_amdgcn_global_load_lds(
        (__attribute__((address_space(1))) unsigned int*)(uintptr_t)g,
        (__attribute__((address_space(3))) unsigned int*)(unsigned int)(uintptr_t)l,
        16, 0, 0);
}

// sum over aligned groups of 8 lanes, pure DPP (VALU pipe, no LDS counters)
__device__ __forceinline__ float sum8(float x) {
    x += __int_as_float(__builtin_amdgcn_mov_dpp(__float_as_int(x), 0xB1, 0xF, 0xF, true));
    x += __int_as_float(__builtin_amdgcn_mov_dpp(__float_as_int(x), 0x4E, 0xF, 0xF, true));
    x += __int_as_float(__builtin_amdgcn_mov_dpp(__float_as_int(x), 0x141, 0xF, 0xF, true));
    return x;
}

// ------------------------------- rope tables -------------------------------
__global__ void rope_tables_k(float* __restrict__ cosT, float* __restrict__ sinT) {
    int idx = blockIdx.x * 256 + threadIdx.x;   // 32768 = 1024*32
    int l = idx >> 5, d = idx & 31;
    double ang = (double)l * pow(500000.0, -(double)(2 * d) / 64.0);
    cosT[idx] = (float)cos(ang);
    sinT[idx] = (float)sin(ang);
}

// ------------------------------- embedding ---------------------------------
__global__ void embed_k(const int* __restrict__ ids, const float* __restrict__ emb,
                        float* __restrict__ h) {
    int tok = blockIdx.x;
    int id = ids[tok];
    ((float4*)(h + (size_t)tok * HIDDEN))[threadIdx.x] =
        ((const float4*)(emb + (size_t)id * HIDDEN))[threadIdx.x];
}

// ------------------------------- casts -------------------------------------
__global__ void cast_plain(const float* __restrict__ s, bf16* __restrict__ d, int n4) {
    int i = blockIdx.x * 256 + threadIdx.x;
    if (i >= n4) return;
    float4 v = ((const float4*)s)[i];
    BF4 u;
    u.h[0] = (bf16)v.x; u.h[1] = (bf16)v.y; u.h[2] = (bf16)v.z; u.h[3] = (bf16)v.w;
    ((short4*)d)[i] = u.p;
}

// six 256x512 f32 matrices -> one fused 1536x512 bf16 (order s0..s5)
__global__ void cast6(const float* s0, const float* s1, const float* s2,
                      const float* s3, const float* s4, const float* s5,
                      bf16* __restrict__ d) {
    int i = blockIdx.x * 256 + threadIdx.x;      // 196608 short4s
    if (i >= 196608) return;
    int which = i >> 15, loc = i & 32767;
    const float* s = which == 0 ? s0 : which == 1 ? s1 : which == 2 ? s2
                    : which == 3 ? s3 : which == 4 ? s4 : s5;
    float4 v = ((const float4*)s)[loc];
    BF4 u;
    u.h[0] = (bf16)v.x; u.h[1] = (bf16)v.y; u.h[2] = (bf16)v.z; u.h[3] = (bf16)v.w;
    ((short4*)d)[i] = u.p;
}

// wq/wk/wv (6,512,512) each -> fused (6,1536,512) rows [layer*1536+which*512+r]
__global__ void cast_qkv(const float* __restrict__ q, const float* __restrict__ k,
                         const float* __restrict__ v, bf16* __restrict__ d) {
    int idx = blockIdx.x * 256 + threadIdx.x;    // 3*393216
    if (idx >= 1179648) return;
    int which = idx / 393216;
    int rem = idx - which * 393216;
    const float* s = which == 0 ? q : which == 1 ? k : v;
    int layer = rem >> 16, rr = rem & 65535;     // 512*128 per layer
    int r = rr >> 7, c4 = rr & 127;
    float4 x = ((const float4*)s)[rem];
    BF4 u;
    u.h[0] = (bf16)x.x; u.h[1] = (bf16)x.y; u.h[2] = (bf16)x.z; u.h[3] = (bf16)x.w;
    ((short4*)d)[((size_t)layer * 1536 + which * 512 + r) * 128 + c4] = u.p;
}

// w_gate/w_up (6,1536,512) -> interleaved (6,3072,512) rows [layer*3072+2r+which]
__global__ void cast_gu(const float* __restrict__ g, const float* __restrict__ uu,
                        bf16* __restrict__ d) {
    int idx = blockIdx.x * 256 + threadIdx.x;    // 2*1179648
    if (idx >= 2359296) return;
    int which = idx / 1179648;
    int rem = idx - which * 1179648;
    const float* s = which == 0 ? g : uu;
    int layer = rem / 196608, rr = rem - layer * 196608;  // 1536*128
    int r = rr >> 7, c4 = rr & 127;
    float4 x = ((const float4*)s)[rem];
    BF4 u;
    u.h[0] = (bf16)x.x; u.h[1] = (bf16)x.y; u.h[2] = (bf16)x.z; u.h[3] = (bf16)x.w;
    ((short4*)d)[((size_t)layer * 3072 + r * 2 + which) * 128 + c4] = u.p;
}

__global__ void cast_embed_pad(const float* __restrict__ s, bf16* __restrict__ d) {
    int i = blockIdx.x * 256 + threadIdx.x;   // 128*128 = 16384 short4s
    int row = i >> 7, c4 = i & 127;
    BF4 u;
    if (row < VOCN) {
        float4 v = ((const float4*)s)[row * 128 + c4];
        u.h[0] = (bf16)v.x; u.h[1] = (bf16)v.y; u.h[2] = (bf16)v.z; u.h[3] = (bf16)v.w;
    } else {
        u.h[0] = (bf16)0.f; u.h[1] = (bf16)0.f; u.h[2] = (bf16)0.f; u.h[3] = (bf16)0.f;
    }
    ((short4*)d)[i] = u.p;
}

// ------------------------------- rmsnorm -> bf16 ---------------------------
__global__ void rmsnorm512(const float* __restrict__ in, const float* __restrict__ w,
                           bf16* __restrict__ out) {
    int row = blockIdx.x, t = threadIdx.x;     // 128 threads
    float4 x = ((const float4*)(in + (size_t)row * 512))[t];
    float s = x.x * x.x + x.y * x.y + x.z * x.z + x.w * x.w;
    for (int m = 1; m < 64; m <<= 1) s += __shfl_xor(s, m);
    __shared__ float red[2];
    if ((t & 63) == 0) red[t >> 6] = s;
    __syncthreads();
    float tot = red[0] + red[1];
    float r = rsqrtf(tot * (1.f / 512.f) + 1e-6f);
    float4 wv = ((const float4*)w)[t];
    BF4 u;
    u.h[0] = (bf16)(x.x * r * wv.x); u.h[1] = (bf16)(x.y * r * wv.y);
    u.h[2] = (bf16)(x.z * r * wv.z); u.h[3] = (bf16)(x.w * r * wv.w);
    ((short4*)(out + (size_t)row * 512))[t] = u.p;
}

// ------------------------------- bf16 MFMA GEMM (128x128) ------------------
// C = A(bf16, MxK rm) @ B(bf16, NxK rm)^T. 128x128 tile, Kstep 32, 4 waves.
// MODE 0: C(f32)=v
// MODE 4: gate/up interleaved cols; Cb[row*Nreal+col/2]=bf16(silu(g)*u)
// MODE 5: fused QKV epilogue: RoPE(q,k)->Qb/Kb bf16 [bh][l][64], v->Vtb
//         [bh][d][l]. Requires N=1536 layout q|k|v and M = b-major tokens.
template <int MODE>
__global__ __launch_bounds__(256) void gemm_bf16(const bf16* __restrict__ A,
                                                 const bf16* __restrict__ B,
                                                 float* __restrict__ C,
                                                 bf16* __restrict__ Cb,
                                                 const float* __restrict__ cosT,
                                                 const float* __restrict__ sinT,
                                                 bf16* __restrict__ Qb,
                                                 bf16* __restrict__ Kb,
                                                 bf16* __restrict__ Vtb,
                                                 int M, int N, int K, int Nreal) {
    __shared__ bf16 As[128 * 32];
    __shared__ bf16 Bs[128 * 32];
    const int tid = threadIdx.x;
    const int wave = tid >> 6, lane = tid & 63;
    const int row0 = blockIdx.y * 128, col0 = blockIdx.x * 128;
    floatx4 acc[4][4];
#pragma unroll
    for (int i = 0; i < 4; ++i)
#pragma unroll
        for (int j = 0; j < 4; ++j) acc[i][j] = (floatx4){0.f, 0.f, 0.f, 0.f};
    const int m0 = (wave & 1) * 64, n0 = (wave >> 1) * 64;
    const int sr = tid >> 2;
    const int ske = (tid & 3) * 8;
    const size_t arow1 = (size_t)(row0 + sr) * K + ske;
    const size_t arow2 = (size_t)(row0 + 64 + sr) * K + ske;
    const size_t brow1 = (size_t)(col0 + sr) * K + ske;
    const size_t brow2 = (size_t)(col0 + 64 + sr) * K + ske;
    char* AsB = (char*)As;
    char* BsB = (char*)Bs;
    const int lds0 = wave * 1024, lds1 = 4096 + wave * 1024;

    for (int k0 = 0; k0 < K; k0 += 32) {
        gload16(A + arow1 + k0, AsB + lds0);
        gload16(A + arow2 + k0, AsB + lds1);
        gload16(B + brow1 + k0, BsB + lds0);
        gload16(B + brow2 + k0, BsB + lds1);
        __syncthreads();
        bf16x8 af[4], bfr[4];
#pragma unroll
        for (int mi = 0; mi < 4; ++mi)
            af[mi] = *(const bf16x8*)(AsB + ((m0 + mi * 16 + (lane & 15)) * 32 + (lane >> 4) * 8) * 2);
#pragma unroll
        for (int ni = 0; ni < 4; ++ni)
            bfr[ni] = *(const bf16x8*)(BsB + ((n0 + ni * 16 + (lane & 15)) * 32 + (lane >> 4) * 8) * 2);
#pragma unroll
        for (int mi = 0; mi < 4; ++mi)
#pragma unroll
            for (int ni = 0; ni < 4; ++ni)
                acc[mi][ni] = __builtin_amdgcn_mfma_f32_16x16x32_bf16(af[mi], bfr[ni], acc[mi][ni], 0, 0, 0);
        __syncthreads();
    }
    const int cr = (lane >> 4) * 4;
    const int cc = lane & 15;
    if (MODE == 5) {
        // wave-uniform 64-col span: segment + head fixed per wave
        int segbase = col0 + n0;
        int seg = segbase >> 9;           // 0=q 1=k 2=v
        int head = (segbase >> 6) & 7;
#pragma unroll
        for (int mi = 0; mi < 4; ++mi) {
#pragma unroll
            for (int r = 0; r < 4; ++r) {
                int row = row0 + m0 + mi * 16 + cr + r;
                int b = row >> 10, l = row & 1023;
                size_t bh = (size_t)(b * 8 + head);
                float x0 = acc[mi][0][r], x1 = acc[mi][1][r];
                float x2 = acc[mi][2][r], x3 = acc[mi][3][r];
                if (seg < 2) {
                    float c0 = cosT[l * 32 + cc], c1 = cosT[l * 32 + 16 + cc];
                    float s0 = sinT[l * 32 + cc], s1 = sinT[l * 32 + 16 + cc];
                    bf16* dst = (seg == 0 ? Qb : Kb) + bh * 65536 + l * 64;
                    dst[cc]      = (bf16)(x0 * c0 - x2 * s0);
                    dst[16 + cc] = (bf16)(x1 * c1 - x3 * s1);
                    dst[32 + cc] = (bf16)(x2 * c0 + x0 * s0);
                    dst[48 + cc] = (bf16)(x3 * c1 + x1 * s1);
                } else {
                    bf16* dst = Vtb + bh * 65536 + l;
                    dst[(size_t)(cc) * 1024]      = (bf16)x0;
                    dst[(size_t)(16 + cc) * 1024] = (bf16)x1;
                    dst[(size_t)(32 + cc) * 1024] = (bf16)x2;
                    dst[(size_t)(48 + cc) * 1024] = (bf16)x3;
                }
            }
        }
        return;
    }
#pragma unroll
    for (int mi = 0; mi < 4; ++mi) {
#pragma unroll
        for (int ni = 0; ni < 4; ++ni) {
#pragma unroll
            for (int r = 0; r < 4; ++r) {
                int row = row0 + m0 + mi * 16 + cr + r;
                int col = col0 + n0 + ni * 16 + cc;
                float v = acc[mi][ni][r];
                if (MODE == 4) {
                    float o = __shfl_xor(v, 1);
                    if (!(lane & 1)) {
                        float sg = v / (1.f + __expf(-v));
                        Cb[(size_t)row * Nreal + (col >> 1)] = (bf16)(sg * o);
                    }
                } else if (col < Nreal) {
                    size_t off = (size_t)row * Nreal + col;
                    if (MODE == 0) C[off] = v;
                }
            }
        }
    }
}

// ---------------------- 64x128-tile GEMM (accumulate) ----------------------
// Tile M=64, N=128, 4 waves each 32x64. Doubles grid fill for N=512 GEMMs.
// MODE 0: C=v  MODE 1: C+=v
template <int MODE>
__global__ __launch_bounds__(256) void gemm64_bf16(const bf16* __restrict__ A,
                                                   const bf16* __restrict__ B,
                                                   float* __restrict__ C,
                                                   int M, int N, int K, int Nreal) {
    __shared__ bf16 As[64 * 32];
    __shared__ bf16 Bs[128 * 32];
    const int tid = threadIdx.x;
    const int wave = tid >> 6, lane = tid & 63;
    const int row0 = blockIdx.y * 64, col0 = blockIdx.x * 128;
    floatx4 acc[2][4];
#pragma unroll
    for (int i = 0; i < 2; ++i)
#pragma unroll
        for (int j = 0; j < 4; ++j) acc[i][j] = (floatx4){0.f, 0.f, 0.f, 0.f};
    const int m0 = (wave & 1) * 32, n0 = (wave >> 1) * 64;
    const int sr = tid >> 2;
    const int ske = (tid & 3) * 8;
    const size_t arow = (size_t)(row0 + sr) * K + ske;
    const size_t brow1 = (size_t)(col0 + sr) * K + ske;
    const size_t brow2 = (size_t)(col0 + 64 + sr) * K + ske;
    char* AsB = (char*)As;
    char* BsB = (char*)Bs;
    const int lds0 = wave * 1024, lds1 = 4096 + wave * 1024;

    for (int k0 = 0; k0 < K; k0 += 32) {
        gload16(A + arow + k0, AsB + tid * 16);
        gload16(B + brow1 + k0, BsB + lds0);
        gload16(B + brow2 + k0, BsB + lds1);
        __syncthreads();
        bf16x8 af[2], bfr[4];
#pragma unroll
        for (int mi = 0; mi < 2; ++mi)
            af[mi] = *(const bf16x8*)(AsB + ((m0 + mi * 16 + (lane & 15)) * 32 + (lane >> 4) * 8) * 2);
#pragma unroll
        for (int ni = 0; ni < 4; ++ni)
            bfr[ni] = *(const bf16x8*)(BsB + ((n0 + ni * 16 + (lane & 15)) * 32 + (lane >> 4) * 8) * 2);
#pragma unroll
        for (int mi = 0; mi < 2; ++mi)
#pragma unroll
            for (int ni = 0; ni < 4; ++ni)
                acc[mi][ni] = __builtin_amdgcn_mfma_f32_16x16x32_bf16(af[mi], bfr[ni], acc[mi][ni], 0, 0, 0);
        __syncthreads();
    }
    const int cr = (lane >> 4) * 4;
    const int cc = lane & 15;
#pragma unroll
    for (int mi = 0; mi < 2; ++mi) {
#pragma unroll
        for (int ni = 0; ni < 4; ++ni) {
#pragma unroll
            for (int r = 0; r < 4; ++r) {
                int row = row0 + m0 + mi * 16 + cr + r;
                int col = col0 + n0 + ni * 16 + cc;
                if (col < Nreal) {
                    size_t off = (size_t)row * Nreal + col;
                    float v = acc[mi][ni][r];
                    if (MODE == 0) C[off] = v;
                    else C[off] += v;
                }
            }
        }
    }
}

// ------------------------- MFMA flash attention ----------------------------
__global__ __launch_bounds__(256) void attn_mfma(const bf16* __restrict__ Qb,
                                                 const bf16* __restrict__ Kb,
                                                 const bf16* __restrict__ Vtb,
                                                 bf16* __restrict__ O) {
    int qt = blockIdx.x, hh = blockIdx.y, b = blockIdx.z;
    int bh = b * 8 + hh;
    int q0 = qt * 64;
    const bf16* Qg = Qb + ((size_t)bh * 1024 + q0) * 64;
    const bf16* Kg = Kb + (size_t)bh * 1024 * 64;
    const bf16* Vg = Vtb + (size_t)bh * 64 * 1024;   // [64 d][1024 l]
    __shared__ bf16 Qs[64 * ATTS];
    __shared__ bf16 Ks[64 * ATTS];
    __shared__ bf16 Vs[64 * ATTS];
    __shared__ bf16 Ps[64 * ATTS];
    int tid = threadIdx.x, wave = tid >> 6, lane = tid & 63;
    int lr = lane & 15, quad = lane >> 4;

#pragma unroll
    for (int it = 0; it < 2; ++it) {
        int cidx = tid + it * 256;
        int row = cidx >> 3, ch = cidx & 7;
        *(bf16x8*)(Qs + row * ATTS + ch * 8) = *(const bf16x8*)(Qg + row * 64 + ch * 8);
    }
    float mrow[4], lrow[4];
    floatx4 Oacc[4];
#pragma unroll
    for (int r = 0; r < 4; ++r) { mrow[r] = -1e30f; lrow[r] = 0.f; }
#pragma unroll
    for (int d0 = 0; d0 < 4; ++d0) Oacc[d0] = (floatx4){0.f, 0.f, 0.f, 0.f};

    int ntiles = qt + 1;
    for (int t = 0; t < ntiles; ++t) {
        int kv0 = t * 64;
        __syncthreads();
#pragma unroll
        for (int it = 0; it < 2; ++it) {
            int cidx = tid + it * 256;
            int row = cidx >> 3, ch = cidx & 7;
            *(bf16x8*)(Ks + row * ATTS + ch * 8) =
                *(const bf16x8*)(Kg + (size_t)(kv0 + row) * 64 + ch * 8);
            *(bf16x8*)(Vs + row * ATTS + ch * 8) =
                *(const bf16x8*)(Vg + (size_t)row * 1024 + kv0 + ch * 8);
        }
        __syncthreads();
        bf16x8 aq[2];
#pragma unroll
        for (int kc = 0; kc < 2; ++kc)
            aq[kc] = *(const bf16x8*)(Qs + (wave * 16 + lr) * ATTS + kc * 32 + quad * 8);
        floatx4 sacc[4];
#pragma unroll
        for (int n0 = 0; n0 < 4; ++n0) {
            bf16x8 bk0 = *(const bf16x8*)(Ks + (n0 * 16 + lr) * ATTS + quad * 8);
            bf16x8 bk1 = *(const bf16x8*)(Ks + (n0 * 16 + lr) * ATTS + 32 + quad * 8);
            floatx4 z = (floatx4){0.f, 0.f, 0.f, 0.f};
            z = __builtin_amdgcn_mfma_f32_16x16x32_bf16(aq[0], bk0, z, 0, 0, 0);
            sacc[n0] = __builtin_amdgcn_mfma_f32_16x16x32_bf16(aq[1], bk1, z, 0, 0, 0);
        }
        float sv[4][4];
#pragma unroll
        for (int n0 = 0; n0 < 4; ++n0)
#pragma unroll
            for (int r = 0; r < 4; ++r) sv[n0][r] = sacc[n0][r] * 0.125f;
        if (t == ntiles - 1) {
#pragma unroll
            for (int n0 = 0; n0 < 4; ++n0)
#pragma unroll
                for (int r = 0; r < 4; ++r)
                    if (n0 * 16 + lr > wave * 16 + quad * 4 + r) sv[n0][r] = -1e30f;
        }
        float al[4];
#pragma unroll
        for (int r = 0; r < 4; ++r) {
            float tm = fmaxf(fmaxf(sv[0][r], sv[1][r]), fmaxf(sv[2][r], sv[3][r]));
            tm = fmaxf(tm, __shfl_xor(tm, 1));
            tm = fmaxf(tm, __shfl_xor(tm, 2));
            tm = fmaxf(tm, __shfl_xor(tm, 4));
            tm = fmaxf(tm, __shfl_xor(tm, 8));
            float mn = fmaxf(mrow[r], tm);
            al[r] = __expf(mrow[r] - mn);
            mrow[r] = mn;
        }
        float rs[4];
#pragma unroll
        for (int r = 0; r < 4; ++r) rs[r] = 0.f;
#pragma unroll
        for (int n0 = 0; n0 < 4; ++n0)
#pragma unroll
            for (int r = 0; r < 4; ++r) {
                float p = __expf(sv[n0][r] - mrow[r]);
                sv[n0][r] = p;
                rs[r] += p;
            }
#pragma unroll
        for (int r = 0; r < 4; ++r) {
            float t2 = rs[r];
            t2 += __shfl_xor(t2, 1);
            t2 += __shfl_xor(t2, 2);
            t2 += __shfl_xor(t2, 4);
            t2 += __shfl_xor(t2, 8);
            lrow[r] = lrow[r] * al[r] + t2;
        }
#pragma unroll
        for (int d0 = 0; d0 < 4; ++d0)
#pragma unroll
            for (int r = 0; r < 4; ++r) Oacc[d0][r] *= al[r];
#pragma unroll
        for (int n0 = 0; n0 < 4; ++n0)
#pragma unroll
            for (int r = 0; r < 4; ++r)
                Ps[(wave * 16 + quad * 4 + r) * ATTS + n0 * 16 + lr] = (bf16)sv[n0][r];
        bf16x8 ap[2];
#pragma unroll
        for (int kc = 0; kc < 2; ++kc)
            ap[kc] = *(const bf16x8*)(Ps + (wave * 16 + lr) * ATTS + kc * 32 + quad * 8);
#pragma unroll
        for (int d0 = 0; d0 < 4; ++d0) {
            bf16x8 bv0 = *(const bf16x8*)(Vs + (d0 * 16 + lr) * ATTS + quad * 8);
            bf16x8 bv1 = *(const bf16x8*)(Vs + (d0 * 16 + lr) * ATTS + 32 + quad * 8);
            Oacc[d0] = __builtin_amdgcn_mfma_f32_16x16x32_bf16(ap[0], bv0, Oacc[d0], 0, 0, 0);
            Oacc[d0] = __builtin_amdgcn_mfma_f32_16x16x32_bf16(ap[1], bv1, Oacc[d0], 0, 0, 0);
        }
    }
    float inv[4];
#pragma unroll
    for (int r = 0; r < 4; ++r) inv[r] = 1.f / lrow[r];
#pragma unroll
    for (int d0 = 0; d0 < 4; ++d0)
#pragma unroll
        for (int r = 0; r < 4; ++r) {
            int row = b * 1024 + q0 + wave * 16 + quad * 4 + r;
            int col = hh * 64 + d0 * 16 + lr;
            O[(size_t)row * 512 + col] = (bf16)(Oacc[d0][r] * inv[r]);
        }
}

// ------------------------------- delta scan --------------------------------
// Round 12: round-9 verified 2-token pair math, remapped to 16 blocks x 512
// threads = TWO independent (b,h) chains per block (half = tid>>8). 8 waves
// per block -> 2 waves/SIMD from different chains, so dependency stalls of
// one chain fill with the other's issue. LDS staging duplicated per half.
// Per pair:
//   u1 = bv1 - b1*a1*d1; au1 = a2*u1; A = a1*a2
//   pred2 = A*d2 + au1*c12;           u2 = bv2 - b2*pred2
//   s'' = A*s + au1*k1 + u2*k2
//   out1 = a1*dq1 + u1*(k1.q1);       out2 = A*dq2 + au1*(k1.q2) + u2*(k2.q2)
__global__ __launch_bounds__(512, 2) void delta_scan(
    const float* __restrict__ P, const float* __restrict__ S_in,
    const float* __restrict__ bbias, const float* __restrict__ abias,
    float* __restrict__ S_out, float* __restrict__ ctx) {
    int tid = threadIdx.x;
    int half = tid >> 8;            // which chain of the two in this block
    int htid = tid & 255;           // tid within the chain's 4 waves
    int bh = blockIdx.x * 2 + half;
    int b = bh >> 3, hh = bh & 7;
    int lane = htid & 63;
    int ri = (htid >> 6) * 8 + (lane >> 3);
    int c = lane & 7;
    bool cz = (c == 0);
    __shared__ __align__(16) float ks[2][66][36], qs[2][66][36], vs[2][66][36],
                                   bs[2][66][36], as_[2][66][36];
    __shared__ __align__(16) float cs[2][64][32];
    __shared__ __align__(16) float cpair[2][33][4]; // [pair][c12,k1q1,k1q2,k2q2]
    float (*ksH)[36] = ks[half];
    float (*qsH)[36] = qs[half];
    float (*vsH)[36] = vs[half];
    float (*bsH)[36] = bs[half];
    float (*asH)[36] = as_[half];
    float (*csH)[32] = cs[half];
    float (*cpH)[4]  = cpair[half];
    float4 S = *(const float4*)(S_in + ((size_t)bh * 32 + ri) * 32 + c * 4);

    int sc4 = htid & 7, sr0 = htid >> 3;   // staging: token rows sr0, sr0+32
    float4 bB = *(const float4*)(bbias + hh * 32 + sc4 * 4);
    float4 bA = *(const float4*)(abias + hh * 32 + sc4 * 4);

    struct Pair {
        float4 k1, k2, q1, q2;
        float a1, a2, b1, b2, bv1, bv2;
        float c12, cq11, cq12, cq22;
    };
    Pair PA, PB;

    auto dot4 = [](float4 s, float4 k) {
        return fmaf(s.w, k.w, fmaf(s.z, k.z, fmaf(s.y, k.y, s.x * k.x)));
    };
    auto loadp = [&](int t, Pair& Pr) {
        Pr.k1 = *(const float4*)&ksH[2 * t][c * 4];
        Pr.k2 = *(const float4*)&ksH[2 * t + 1][c * 4];
        Pr.q1 = *(const float4*)&qsH[2 * t][c * 4];
        Pr.q2 = *(const float4*)&qsH[2 * t + 1][c * 4];
        Pr.a1 = asH[2 * t][ri];  Pr.a2 = asH[2 * t + 1][ri];
        Pr.b1 = bsH[2 * t][ri];  Pr.b2 = bsH[2 * t + 1][ri];
        Pr.bv1 = vsH[2 * t][ri]; Pr.bv2 = vsH[2 * t + 1][ri];
        float4 cp = *(const float4*)&cpH[t][0];
        Pr.c12 = cp.x; Pr.cq11 = cp.y; Pr.cq12 = cp.z; Pr.cq22 = cp.w;
    };
    auto stepp = [&](const Pair& Pr, int t) {
        float d1  = sum8(dot4(S, Pr.k1));
        float d2  = sum8(dot4(S, Pr.k2));
        float dq1 = sum8(dot4(S, Pr.q1));
        float dq2 = sum8(dot4(S, Pr.q2));
        float u1 = fmaf(-(Pr.b1 * Pr.a1), d1, Pr.bv1);
        float au1 = Pr.a2 * u1;
        float A = Pr.a1 * Pr.a2;
        float pred2 = fmaf(au1, Pr.c12, A * d2);
        float u2 = fmaf(-Pr.b2, pred2, Pr.bv2);
        S.x = fmaf(u2, Pr.k2.x, fmaf(au1, Pr.k1.x, A * S.x));
        S.y = fmaf(u2, Pr.k2.y, fmaf(au1, Pr.k1.y, A * S.y));
        S.z = fmaf(u2, Pr.k2.z, fmaf(au1, Pr.k1.z, A * S.z));
        S.w = fmaf(u2, Pr.k2.w, fmaf(au1, Pr.k1.w, A * S.w));
        if (cz) {
            csH[2 * t][ri]     = fmaf(u1, Pr.cq11, Pr.a1 * dq1);
            csH[2 * t + 1][ri] = fmaf(u2, Pr.cq22, fmaf(au1, Pr.cq12, A * dq2));
        }
    };

    for (int c0 = 0; c0 < LSEQ; c0 += 64) {
        __syncthreads();
        const float* Pb = P + ((size_t)(b * 1024 + c0) * 1536) + hh * 32 + sc4 * 4;
#pragma unroll
        for (int it = 0; it < 2; ++it) {
            int tok = sr0 + it * 32;
            const float* pg = Pb + (size_t)tok * 1536;
            float4 kv = *(const float4*)(pg);
            float4 vv = *(const float4*)(pg + 256);
            float4 qv = *(const float4*)(pg + 512);
            float4 bv = *(const float4*)(pg + 768);
            float4 av = *(const float4*)(pg + 1024);
            float ss = kv.x * kv.x + kv.y * kv.y + kv.z * kv.z + kv.w * kv.w;
            ss = sum8(ss);
            float rn = 1.f / fmaxf(sqrtf(ss), 1e-12f);
            kv.x *= rn; kv.y *= rn; kv.z *= rn; kv.w *= rn;
            float4 bo, ao;
            bo.x = 1.f / (1.f + __expf(-(bv.x + bB.x)));
            bo.y = 1.f / (1.f + __expf(-(bv.y + bB.y)));
            bo.z = 1.f / (1.f + __expf(-(bv.z + bB.z)));
            bo.w = 1.f / (1.f + __expf(-(bv.w + bB.w)));
            ao.x = 1.f / (1.f + __expf(-(av.x + bA.x)));
            ao.y = 1.f / (1.f + __expf(-(av.y + bA.y)));
            ao.z = 1.f / (1.f + __expf(-(av.z + bA.z)));
            ao.w = 1.f / (1.f + __expf(-(av.w + bA.w)));
            float4 vo;
            vo.x = bo.x * vv.x; vo.y = bo.y * vv.y;
            vo.z = bo.z * vv.z; vo.w = bo.w * vv.w;
            // pair-shared dot products (tokens 2j / 2j+1 sit in adjacent
            // 8-lane groups -> shfl_xor(8) swaps partners, stays in-wave)
            float kq = sum8(kv.x * qv.x + kv.y * qv.y + kv.z * qv.z + kv.w * qv.w);
            float4 ko, qo;
            ko.x = __shfl_xor(kv.x, 8); ko.y = __shfl_xor(kv.y, 8);
            ko.z = __shfl_xor(kv.z, 8); ko.w = __shfl_xor(kv.w, 8);
            qo.x = __shfl_xor(qv.x, 8); qo.y = __shfl_xor(qv.y, 8);
            qo.z = __shfl_xor(qv.z, 8); qo.w = __shfl_xor(qv.w, 8);
            float ckk = sum8(kv.x * ko.x + kv.y * ko.y + kv.z * ko.z + kv.w * ko.w);
            float ckq = sum8(kv.x * qo.x + kv.y * qo.y + kv.z * qo.z + kv.w * qo.w);
            *(float4*)&ksH[tok][sc4 * 4] = kv;
            *(float4*)&vsH[tok][sc4 * 4] = vo;
            *(float4*)&qsH[tok][sc4 * 4] = qv;
            *(float4*)&bsH[tok][sc4 * 4] = bo;
            *(float4*)&asH[tok][sc4 * 4] = ao;
            if ((htid & 7) == 0) {
                int pairi = tok >> 1;
                if (!(tok & 1)) {
                    cpH[pairi][0] = ckk;   // k1·k2
                    cpH[pairi][1] = kq;    // k1·q1
                    cpH[pairi][2] = ckq;   // k1·q2
                } else {
                    cpH[pairi][3] = kq;    // k2·q2
                }
            }
        }
        __syncthreads();
        loadp(0, PA);
        for (int t = 0; t < 32; t += 2) {
            loadp(t + 1, PB);
            stepp(PA, t);
            loadp(t + 2, PA);   // t==30 -> pair 32: pad rows 64/65, cpair[32]
            stepp(PB, t + 1);
        }
        __syncthreads();
        int gbase = b * 1024 + c0;
        for (int e = htid; e < 512; e += 256) {
            int t = e >> 3, j4 = e & 7;
            float4 val = *(const float4*)&csH[t][j4 * 4];
            *(float4*)(ctx + (size_t)(gbase + t) * 256 + hh * 32 + j4 * 4) = val;
        }
    }
    *(float4*)(S_out + ((size_t)bh * 32 + ri) * 32 + c * 4) = S;
}

// ------------- ctxbf = bf16(rmsnorm(ctx,nw)*silu(gate)), gate in P@1280 ----
__global__ void ctx_post(const float* __restrict__ ctx, const float* __restrict__ P,
                         const float* __restrict__ nw, bf16* __restrict__ out) {
    int row = blockIdx.x, t = threadIdx.x;  // 64 threads
    float4 x = ((const float4*)(ctx + (size_t)row * SDIMM))[t];
    float s = x.x * x.x + x.y * x.y + x.z * x.z + x.w * x.w;
    for (int m = 1; m < 64; m <<= 1) s += __shfl_xor(s, m);
    float r = rsqrtf(s * (1.f / 256.f) + 1e-6f);
    float4 n = ((const float4*)nw)[t];
    float4 g = ((const float4*)(P + (size_t)row * 1536 + 1280))[t];
    BF4 u;
    u.h[0] = (bf16)(x.x * r * n.x * (g.x / (1.f + __expf(-g.x))));
    u.h[1] = (bf16)(x.y * r * n.y * (g.y / (1.f + __expf(-g.y))));
    u.h[2] = (bf16)(x.z * r * n.z * (g.z / (1.f + __expf(-g.z))));
    u.h[3] = (bf16)(x.w * r * n.w * (g.w / (1.f + __expf(-g.w))));
    ((short4*)(out + (size_t)row * SDIMM))[t] = u.p;
}

// ---------------------------------------------------------------------------
extern "C" void kernel_launch(void* const* d_in, const int* in_sizes, int n_in,
                              void* d_out, int out_size, void* d_ws, size_t ws_size,
                              hipStream_t stream) {
    (void)in_sizes; (void)n_in; (void)out_size; (void)ws_size;
    const int* ids = (const int*)d_in[0];
    const float* state = (const float*)d_in[1];
    const float* embedw = (const float*)d_in[2];
    auto F = [&](int i) { return (const float*)d_in[i]; };

    char* wsb = (char*)d_ws;
    const size_t MB = 1048576;
    float* H    = (float*)(wsb);                 // 0-8 MB
    bf16*  XNbf = (bf16*)(wsb + 8 * MB);         // 8-12 (alias ctxf in delta)
    float* ctxf = (float*)(wsb + 8 * MB);
    bf16*  Hbf  = (bf16*)(wsb + 12 * MB);        // 12-16 (alias ctxb)
    bf16*  ctxb = (bf16*)(wsb + 12 * MB);
    float* P    = (float*)(wsb + 16 * MB);       // 16-40 (delta proj f32)
    bf16*  Obf  = (bf16*)(wsb + 40 * MB);        // 40-44 attn out
    bf16*  Qbuf = (bf16*)(wsb + 44 * MB);        // 44-48
    bf16*  Kbuf = (bf16*)(wsb + 48 * MB);        // 48-52
    bf16*  Vtb  = (bf16*)(wsb + 52 * MB);        // 52-56
    bf16*  A1b  = (bf16*)(wsb + 44 * MB);        // alias Q/K/Vt (dead after attn)
    float* cosT = (float*)(wsb + 58 * MB);
    float* sinT = cosT + 32768;
    float* Sbuf = sinT + 32768;
    char*  wbase = wsb + 59 * MB;
    bf16* wqkv  = (bf16*)(wbase);                        // 6x1536x512
    bf16* wob   = (bf16*)(wbase + 9437184);              // 6x512x512
    bf16* wgu   = (bf16*)(wbase + 12582912);             // 6x3072x512 interleaved
    bf16* wdnb  = (bf16*)(wbase + 31457280);             // 6x512x1536
    bf16* wdR   = (bf16*)(wbase + 40894464);             // 1536x512
    bf16* woutR = (bf16*)(wbase + 42467328);             // 512x256
    bf16* wdW   = (bf16*)(wbase + 42729472);             // 1536x512
    bf16* woutW = (bf16*)(wbase + 44302336);             // 512x256
    bf16* embp  = (bf16*)(wbase + 44564480);             // 128x512 padded

    float* out = (float*)d_out;
    float* logits = out;
    float* Sout = out + 4096 * VOCN;

    // 128x128-tile launches
    auto G0 = [&](const bf16* A, const bf16* B, float* C, int M, int N, int K, int Nreal) {
        gemm_bf16<0><<<dim3(N / 128, M / 128), 256, 0, stream>>>(
            A, B, C, nullptr, nullptr, nullptr, nullptr, nullptr, nullptr, M, N, K, Nreal);
    };
    auto G4 = [&](const bf16* A, const bf16* B, bf16* Cb, int M, int N, int K, int Nreal) {
        gemm_bf16<4><<<dim3(N / 128, M / 128), 256, 0, stream>>>(
            A, B, nullptr, Cb, nullptr, nullptr, nullptr, nullptr, nullptr, M, N, K, Nreal);
    };
    auto G5 = [&](const bf16* A, const bf16* B, int M, int N, int K) {
        gemm_bf16<5><<<dim3(N / 128, M / 128), 256, 0, stream>>>(
            A, B, nullptr, nullptr, cosT, sinT, Qbuf, Kbuf, Vtb, M, N, K, N);
    };
    // 64x128-tile accumulate
    auto G1s = [&](const bf16* A, const bf16* B, float* C, int M, int N, int K) {
        gemm64_bf16<1><<<dim3(N / 128, M / 64), 256, 0, stream>>>(A, B, C, M, N, K, N);
    };
    auto G0s = [&](const bf16* A, const bf16* B, float* C, int M, int N, int K, int Nreal) {
        gemm64_bf16<0><<<dim3(N / 128, M / 64), 256, 0, stream>>>(A, B, C, M, N, K, Nreal);
    };
    auto CP = [&](const float* s, bf16* d, int n4) {
        cast_plain<<<(n4 + 255) / 256, 256, 0, stream>>>(s, d, n4);
    };

    // ---- weight casts ----
    cast_qkv<<<4608, 256, 0, stream>>>(F(24), F(25), F(26), wqkv);
    CP(F(27), wob, 393216);
    cast_gu<<<9216, 256, 0, stream>>>(F(29), F(30), wgu);
    CP(F(31), wdnb, 1179648);
    cast6<<<768, 256, 0, stream>>>(F(3), F(4), F(5), F(6), F(8), F(12), wdR);
    CP(F(10), woutR, 32768);
    cast6<<<768, 256, 0, stream>>>(F(13), F(14), F(15), F(16), F(18), F(22), wdW);
    CP(F(20), woutW, 32768);
    cast_embed_pad<<<64, 256, 0, stream>>>(embedw, embp);

    rope_tables_k<<<128, 256, 0, stream>>>(cosT, sinT);
    embed_k<<<4096, 128, 0, stream>>>(ids, embedw, H);

    // ---- delta read ----
    CP(H, Hbf, 524288);
    G0(Hbf, wdR, P, 4096, 1536, 512, 1536);
    delta_scan<<<16, 512, 0, stream>>>(P, state, F(7), F(9), Sbuf, ctxf);
    ctx_post<<<4096, 64, 0, stream>>>(ctxf, P, F(11), ctxb);
    G1s(ctxb, woutR, H, 4096, 512, 256);

    for (int i = 0; i < 6; ++i) {
        rmsnorm512<<<4096, 128, 0, stream>>>(H, F(23) + (size_t)i * 512, XNbf);
        G5(XNbf, wqkv + (size_t)i * 1536 * 512, 4096, 1536, 512);
        attn_mfma<<<dim3(16, 8, 4), 256, 0, stream>>>(Qbuf, Kbuf, Vtb, Obf);
        G1s(Obf, wob + (size_t)i * 512 * 512, H, 4096, 512, 512);
        rmsnorm512<<<4096, 128, 0, stream>>>(H, F(28) + (size_t)i * 512, XNbf);
        G4(XNbf, wgu + (size_t)i * 3072 * 512, A1b, 4096, 3072, 512, 1536);
        G1s(A1b, wdnb + (size_t)i * 512 * 1536, H, 4096, 512, 1536);
    }

    // ---- delta write ----
    CP(H, Hbf, 524288);
    G0(Hbf, wdW, P, 4096, 1536, 512, 1536);
    delta_scan<<<16, 512, 0, stream>>>(P, Sbuf, F(17), F(19), Sout, ctxf);
    ctx_post<<<4096, 64, 0, stream>>>(ctxf, P, F(21), ctxb);
    G1s(ctxb, woutW, H, 4096, 512, 256);

    rmsnorm512<<<4096, 128, 0, stream>>>(H, F(32), XNbf);
    G0s(XNbf, embp, logits, 4096, 128, 512, VOCN);
}

// Round 5
// 1362.407 us; speedup vs baseline: 1.1162x; 1.0967x over previous
//
#include <hip/hip_runtime.h>
#include <hip/hip_bf16.h>
#include <math.h>

// ---------------------------------------------------------------------------
// BashTransformer forward on MI355X. Round 13: delta_scan = round-9 verified
// 2-token pair scan with producer/consumer wave split: 32 blocks x 512
// threads; waves 0-3 scan chunk c while waves 4-7 stage chunk c+1 into a
// double-buffered LDS set (one barrier per chunk). Keeps all 32 chains on
// 32 CUs AND gains 2-wave/SIMD co-residency (round-12 lesson: co-residency
// helps 1.4x but must not halve active CUs). GEMM/attn/epilogues unchanged.
// ---------------------------------------------------------------------------

#define LSEQ 1024
#define BATCH 4
#define HIDDEN 512
#define NHEAD 8
#define HDIM 64
#define SHEAD 8
#define SDHD 32
#define SDIMM 256
#define FFND 1536
#define VOCN 63
#define ATTS 72   // attn LDS row stride (elems): 144B = 16B-aligned, 2-way banks

typedef __bf16 bf16;
typedef __attribute__((ext_vector_type(8))) __bf16 bf16x8;
typedef __attribute__((ext_vector_type(4))) float floatx4;

union BF4 { bf16 h[4]; short4 p; };

__device__ __forceinline__ void gload16(const void* g, const void* l) {
    __builtin_amdgcn_global_load_lds(
        (__attribute__((address_space(1))) unsigned int*)(uintptr_t)g,
        (__attribute__((address_space(3))) unsigned int*)(unsigned int)(uintptr_t)l,
        16, 0, 0);
}

// sum over aligned groups of 8 lanes, pure DPP (VALU pipe, no LDS counters)
__device__ __forceinline__ float sum8(float x) {
    x += __int_as_float(__builtin_amdgcn_mov_dpp(__float_as_int(x), 0xB1, 0xF, 0xF, true));
    x += __int_as_float(__builtin_amdgcn_mov_dpp(__float_as_int(x), 0x4E, 0xF, 0xF, true));
    x += __int_as_float(__builtin_amdgcn_mov_dpp(__float_as_int(x), 0x141, 0xF, 0xF, true));
    return x;
}

// ------------------------------- rope tables -------------------------------
__global__ void rope_tables_k(float* __restrict__ cosT, float* __restrict__ sinT) {
    int idx = blockIdx.x * 256 + threadIdx.x;   // 32768 = 1024*32
    int l = idx >> 5, d = idx & 31;
    double ang = (double)l * pow(500000.0, -(double)(2 * d) / 64.0);
    cosT[idx] = (float)cos(ang);
    sinT[idx] = (float)sin(ang);
}

// ------------------------------- embedding ---------------------------------
__global__ void embed_k(const int* __restrict__ ids, const float* __restrict__ emb,
                        float* __restrict__ h) {
    int tok = blockIdx.x;
    int id = ids[tok];
    ((float4*)(h + (size_t)tok * HIDDEN))[threadIdx.x] =
        ((const float4*)(emb + (size_t)id * HIDDEN))[threadIdx.x];
}

// ------------------------------- casts -------------------------------------
__global__ void cast_plain(const float* __restrict__ s, bf16* __restrict__ d, int n4) {
    int i = blockIdx.x * 256 + threadIdx.x;
    if (i >= n4) return;
    float4 v = ((const float4*)s)[i];
    BF4 u;
    u.h[0] = (bf16)v.x; u.h[1] = (bf16)v.y; u.h[2] = (bf16)v.z; u.h[3] = (bf16)v.w;
    ((short4*)d)[i] = u.p;
}

// six 256x512 f32 matrices -> one fused 1536x512 bf16 (order s0..s5)
__global__ void cast6(const float* s0, const float* s1, const float* s2,
                      const float* s3, const float* s4, const float* s5,
                      bf16* __restrict__ d) {
    int i = blockIdx.x * 256 + threadIdx.x;      // 196608 short4s
    if (i >= 196608) return;
    int which = i >> 15, loc = i & 32767;
    const float* s = which == 0 ? s0 : which == 1 ? s1 : which == 2 ? s2
                    : which == 3 ? s3 : which == 4 ? s4 : s5;
    float4 v = ((const float4*)s)[loc];
    BF4 u;
    u.h[0] = (bf16)v.x; u.h[1] = (bf16)v.y; u.h[2] = (bf16)v.z; u.h[3] = (bf16)v.w;
    ((short4*)d)[i] = u.p;
}

// wq/wk/wv (6,512,512) each -> fused (6,1536,512) rows [layer*1536+which*512+r]
__global__ void cast_qkv(const float* __restrict__ q, const float* __restrict__ k,
                         const float* __restrict__ v, bf16* __restrict__ d) {
    int idx = blockIdx.x * 256 + threadIdx.x;    // 3*393216
    if (idx >= 1179648) return;
    int which = idx / 393216;
    int rem = idx - which * 393216;
    const float* s = which == 0 ? q : which == 1 ? k : v;
    int layer = rem >> 16, rr = rem & 65535;     // 512*128 per layer
    int r = rr >> 7, c4 = rr & 127;
    float4 x = ((const float4*)s)[rem];
    BF4 u;
    u.h[0] = (bf16)x.x; u.h[1] = (bf16)x.y; u.h[2] = (bf16)x.z; u.h[3] = (bf16)x.w;
    ((short4*)d)[((size_t)layer * 1536 + which * 512 + r) * 128 + c4] = u.p;
}

// w_gate/w_up (6,1536,512) -> interleaved (6,3072,512) rows [layer*3072+2r+which]
__global__ void cast_gu(const float* __restrict__ g, const float* __restrict__ uu,
                        bf16* __restrict__ d) {
    int idx = blockIdx.x * 256 + threadIdx.x;    // 2*1179648
    if (idx >= 2359296) return;
    int which = idx / 1179648;
    int rem = idx - which * 1179648;
    const float* s = which == 0 ? g : uu;
    int layer = rem / 196608, rr = rem - layer * 196608;  // 1536*128
    int r = rr >> 7, c4 = rr & 127;
    float4 x = ((const float4*)s)[rem];
    BF4 u;
    u.h[0] = (bf16)x.x; u.h[1] = (bf16)x.y; u.h[2] = (bf16)x.z; u.h[3] = (bf16)x.w;
    ((short4*)d)[((size_t)layer * 3072 + r * 2 + which) * 128 + c4] = u.p;
}

__global__ void cast_embed_pad(const float* __restrict__ s, bf16* __restrict__ d) {
    int i = blockIdx.x * 256 + threadIdx.x;   // 128*128 = 16384 short4s
    int row = i >> 7, c4 = i & 127;
    BF4 u;
    if (row < VOCN) {
        float4 v = ((const float4*)s)[row * 128 + c4];
        u.h[0] = (bf16)v.x; u.h[1] = (bf16)v.y; u.h[2] = (bf16)v.z; u.h[3] = (bf16)v.w;
    } else {
        u.h[0] = (bf16)0.f; u.h[1] = (bf16)0.f; u.h[2] = (bf16)0.f; u.h[3] = (bf16)0.f;
    }
    ((short4*)d)[i] = u.p;
}

// ------------------------------- rmsnorm -> bf16 ---------------------------
__global__ void rmsnorm512(const float* __restrict__ in, const float* __restrict__ w,
                           bf16* __restrict__ out) {
    int row = blockIdx.x, t = threadIdx.x;     // 128 threads
    float4 x = ((const float4*)(in + (size_t)row * 512))[t];
    float s = x.x * x.x + x.y * x.y + x.z * x.z + x.w * x.w;
    for (int m = 1; m < 64; m <<= 1) s += __shfl_xor(s, m);
    __shared__ float red[2];
    if ((t & 63) == 0) red[t >> 6] = s;
    __syncthreads();
    float tot = red[0] + red[1];
    float r = rsqrtf(tot * (1.f / 512.f) + 1e-6f);
    float4 wv = ((const float4*)w)[t];
    BF4 u;
    u.h[0] = (bf16)(x.x * r * wv.x); u.h[1] = (bf16)(x.y * r * wv.y);
    u.h[2] = (bf16)(x.z * r * wv.z); u.h[3] = (bf16)(x.w * r * wv.w);
    ((short4*)(out + (size_t)row * 512))[t] = u.p;
}

// ------------------------------- bf16 MFMA GEMM (128x128) ------------------
// C = A(bf16, MxK rm) @ B(bf16, NxK rm)^T. 128x128 tile, Kstep 32, 4 waves.
// MODE 0: C(f32)=v
// MODE 4: gate/up interleaved cols; Cb[row*Nreal+col/2]=bf16(silu(g)*u)
// MODE 5: fused QKV epilogue: RoPE(q,k)->Qb/Kb bf16 [bh][l][64], v->Vtb
//         [bh][d][l]. Requires N=1536 layout q|k|v and M = b-major tokens.
template <int MODE>
__global__ __launch_bounds__(256) void gemm_bf16(const bf16* __restrict__ A,
                                                 const bf16* __restrict__ B,
                                                 float* __restrict__ C,
                                                 bf16* __restrict__ Cb,
                                                 const float* __restrict__ cosT,
                                                 const float* __restrict__ sinT,
                                                 bf16* __restrict__ Qb,
                                                 bf16* __restrict__ Kb,
                                                 bf16* __restrict__ Vtb,
                                                 int M, int N, int K, int Nreal) {
    __shared__ bf16 As[128 * 32];
    __shared__ bf16 Bs[128 * 32];
    const int tid = threadIdx.x;
    const int wave = tid >> 6, lane = tid & 63;
    const int row0 = blockIdx.y * 128, col0 = blockIdx.x * 128;
    floatx4 acc[4][4];
#pragma unroll
    for (int i = 0; i < 4; ++i)
#pragma unroll
        for (int j = 0; j < 4; ++j) acc[i][j] = (floatx4){0.f, 0.f, 0.f, 0.f};
    const int m0 = (wave & 1) * 64, n0 = (wave >> 1) * 64;
    const int sr = tid >> 2;
    const int ske = (tid & 3) * 8;
    const size_t arow1 = (size_t)(row0 + sr) * K + ske;
    const size_t arow2 = (size_t)(row0 + 64 + sr) * K + ske;
    const size_t brow1 = (size_t)(col0 + sr) * K + ske;
    const size_t brow2 = (size_t)(col0 + 64 + sr) * K + ske;
    char* AsB = (char*)As;
    char* BsB = (char*)Bs;
    const int lds0 = wave * 1024, lds1 = 4096 + wave * 1024;

    for (int k0 = 0; k0 < K; k0 += 32) {
        gload16(A + arow1 + k0, AsB + lds0);
        gload16(A + arow2 + k0, AsB + lds1);
        gload16(B + brow1 + k0, BsB + lds0);
        gload16(B + brow2 + k0, BsB + lds1);
        __syncthreads();
        bf16x8 af[4], bfr[4];
#pragma unroll
        for (int mi = 0; mi < 4; ++mi)
            af[mi] = *(const bf16x8*)(AsB + ((m0 + mi * 16 + (lane & 15)) * 32 + (lane >> 4) * 8) * 2);
#pragma unroll
        for (int ni = 0; ni < 4; ++ni)
            bfr[ni] = *(const bf16x8*)(BsB + ((n0 + ni * 16 + (lane & 15)) * 32 + (lane >> 4) * 8) * 2);
#pragma unroll
        for (int mi = 0; mi < 4; ++mi)
#pragma unroll
            for (int ni = 0; ni < 4; ++ni)
                acc[mi][ni] = __builtin_amdgcn_mfma_f32_16x16x32_bf16(af[mi], bfr[ni], acc[mi][ni], 0, 0, 0);
        __syncthreads();
    }
    const int cr = (lane >> 4) * 4;
    const int cc = lane & 15;
    if (MODE == 5) {
        // wave-uniform 64-col span: segment + head fixed per wave
        int segbase = col0 + n0;
        int seg = segbase >> 9;           // 0=q 1=k 2=v
        int head = (segbase >> 6) & 7;
#pragma unroll
        for (int mi = 0; mi < 4; ++mi) {
#pragma unroll
            for (int r = 0; r < 4; ++r) {
                int row = row0 + m0 + mi * 16 + cr + r;
                int b = row >> 10, l = row & 1023;
                size_t bh = (size_t)(b * 8 + head);
                float x0 = acc[mi][0][r], x1 = acc[mi][1][r];
                float x2 = acc[mi][2][r], x3 = acc[mi][3][r];
                if (seg < 2) {
                    float c0 = cosT[l * 32 + cc], c1 = cosT[l * 32 + 16 + cc];
                    float s0 = sinT[l * 32 + cc], s1 = sinT[l * 32 + 16 + cc];
                    bf16* dst = (seg == 0 ? Qb : Kb) + bh * 65536 + l * 64;
                    dst[cc]      = (bf16)(x0 * c0 - x2 * s0);
                    dst[16 + cc] = (bf16)(x1 * c1 - x3 * s1);
                    dst[32 + cc] = (bf16)(x2 * c0 + x0 * s0);
                    dst[48 + cc] = (bf16)(x3 * c1 + x1 * s1);
                } else {
                    bf16* dst = Vtb + bh * 65536 + l;
                    dst[(size_t)(cc) * 1024]      = (bf16)x0;
                    dst[(size_t)(16 + cc) * 1024] = (bf16)x1;
                    dst[(size_t)(32 + cc) * 1024] = (bf16)x2;
                    dst[(size_t)(48 + cc) * 1024] = (bf16)x3;
                }
            }
        }
        return;
    }
#pragma unroll
    for (int mi = 0; mi < 4; ++mi) {
#pragma unroll
        for (int ni = 0; ni < 4; ++ni) {
#pragma unroll
            for (int r = 0; r < 4; ++r) {
                int row = row0 + m0 + mi * 16 + cr + r;
                int col = col0 + n0 + ni * 16 + cc;
                float v = acc[mi][ni][r];
                if (MODE == 4) {
                    float o = __shfl_xor(v, 1);
                    if (!(lane & 1)) {
                        float sg = v / (1.f + __expf(-v));
                        Cb[(size_t)row * Nreal + (col >> 1)] = (bf16)(sg * o);
                    }
                } else if (col < Nreal) {
                    size_t off = (size_t)row * Nreal + col;
                    if (MODE == 0) C[off] = v;
                }
            }
        }
    }
}

// ---------------------- 64x128-tile GEMM (accumulate) ----------------------
// Tile M=64, N=128, 4 waves each 32x64. Doubles grid fill for N=512 GEMMs.
// MODE 0: C=v  MODE 1: C+=v
template <int MODE>
__global__ __launch_bounds__(256) void gemm64_bf16(const bf16* __restrict__ A,
                                                   const bf16* __restrict__ B,
                                                   float* __restrict__ C,
                                                   int M, int N, int K, int Nreal) {
    __shared__ bf16 As[64 * 32];
    __shared__ bf16 Bs[128 * 32];
    const int tid = threadIdx.x;
    const int wave = tid >> 6, lane = tid & 63;
    const int row0 = blockIdx.y * 64, col0 = blockIdx.x * 128;
    floatx4 acc[2][4];
#pragma unroll
    for (int i = 0; i < 2; ++i)
#pragma unroll
        for (int j = 0; j < 4; ++j) acc[i][j] = (floatx4){0.f, 0.f, 0.f, 0.f};
    const int m0 = (wave & 1) * 32, n0 = (wave >> 1) * 64;
    const int sr = tid >> 2;
    const int ske = (tid & 3) * 8;
    const size_t arow = (size_t)(row0 + sr) * K + ske;
    const size_t brow1 = (size_t)(col0 + sr) * K + ske;
    const size_t brow2 = (size_t)(col0 + 64 + sr) * K + ske;
    char* AsB = (char*)As;
    char* BsB = (char*)Bs;
    const int lds0 = wave * 1024, lds1 = 4096 + wave * 1024;

    for (int k0 = 0; k0 < K; k0 += 32) {
        gload16(A + arow + k0, AsB + tid * 16);
        gload16(B + brow1 + k0, BsB + lds0);
        gload16(B + brow2 + k0, BsB + lds1);
        __syncthreads();
        bf16x8 af[2], bfr[4];
#pragma unroll
        for (int mi = 0; mi < 2; ++mi)
            af[mi] = *(const bf16x8*)(AsB + ((m0 + mi * 16 + (lane & 15)) * 32 + (lane >> 4) * 8) * 2);
#pragma unroll
        for (int ni = 0; ni < 4; ++ni)
            bfr[ni] = *(const bf16x8*)(BsB + ((n0 + ni * 16 + (lane & 15)) * 32 + (lane >> 4) * 8) * 2);
#pragma unroll
        for (int mi = 0; mi < 2; ++mi)
#pragma unroll
            for (int ni = 0; ni < 4; ++ni)
                acc[mi][ni] = __builtin_amdgcn_mfma_f32_16x16x32_bf16(af[mi], bfr[ni], acc[mi][ni], 0, 0, 0);
        __syncthreads();
    }
    const int cr = (lane >> 4) * 4;
    const int cc = lane & 15;
#pragma unroll
    for (int mi = 0; mi < 2; ++mi) {
#pragma unroll
        for (int ni = 0; ni < 4; ++ni) {
#pragma unroll
            for (int r = 0; r < 4; ++r) {
                int row = row0 + m0 + mi * 16 + cr + r;
                int col = col0 + n0 + ni * 16 + cc;
                if (col < Nreal) {
                    size_t off = (size_t)row * Nreal + col;
                    float v = acc[mi][ni][r];
                    if (MODE == 0) C[off] = v;
                    else C[off] += v;
                }
            }
        }
    }
}

// ------------------------- MFMA flash attention ----------------------------
__global__ __launch_bounds__(256) void attn_mfma(const bf16* __restrict__ Qb,
                                                 const bf16* __restrict__ Kb,
                                                 const bf16* __restrict__ Vtb,
                                                 bf16* __restrict__ O) {
    int qt = blockIdx.x, hh = blockIdx.y, b = blockIdx.z;
    int bh = b * 8 + hh;
    int q0 = qt * 64;
    const bf16* Qg = Qb + ((size_t)bh * 1024 + q0) * 64;
    const bf16* Kg = Kb + (size_t)bh * 1024 * 64;
    const bf16* Vg = Vtb + (size_t)bh * 64 * 1024;   // [64 d][1024 l]
    __shared__ bf16 Qs[64 * ATTS];
    __shared__ bf16 Ks[64 * ATTS];
    __shared__ bf16 Vs[64 * ATTS];
    __shared__ bf16 Ps[64 * ATTS];
    int tid = threadIdx.x, wave = tid >> 6, lane = tid & 63;
    int lr = lane & 15, quad = lane >> 4;

#pragma unroll
    for (int it = 0; it < 2; ++it) {
        int cidx = tid + it * 256;
        int row = cidx >> 3, ch = cidx & 7;
        *(bf16x8*)(Qs + row * ATTS + ch * 8) = *(const bf16x8*)(Qg + row * 64 + ch * 8);
    }
    float mrow[4], lrow[4];
    floatx4 Oacc[4];
#pragma unroll
    for (int r = 0; r < 4; ++r) { mrow[r] = -1e30f; lrow[r] = 0.f; }
#pragma unroll
    for (int d0 = 0; d0 < 4; ++d0) Oacc[d0] = (floatx4){0.f, 0.f, 0.f, 0.f};

    int ntiles = qt + 1;
    for (int t = 0; t < ntiles; ++t) {
        int kv0 = t * 64;
        __syncthreads();
#pragma unroll
        for (int it = 0; it < 2; ++it) {
            int cidx = tid + it * 256;
            int row = cidx >> 3, ch = cidx & 7;
            *(bf16x8*)(Ks + row * ATTS + ch * 8) =
                *(const bf16x8*)(Kg + (size_t)(kv0 + row) * 64 + ch * 8);
            *(bf16x8*)(Vs + row * ATTS + ch * 8) =
                *(const bf16x8*)(Vg + (size_t)row * 1024 + kv0 + ch * 8);
        }
        __syncthreads();
        bf16x8 aq[2];
#pragma unroll
        for (int kc = 0; kc < 2; ++kc)
            aq[kc] = *(const bf16x8*)(Qs + (wave * 16 + lr) * ATTS + kc * 32 + quad * 8);
        floatx4 sacc[4];
#pragma unroll
        for (int n0 = 0; n0 < 4; ++n0) {
            bf16x8 bk0 = *(const bf16x8*)(Ks + (n0 * 16 + lr) * ATTS + quad * 8);
            bf16x8 bk1 = *(const bf16x8*)(Ks + (n0 * 16 + lr) * ATTS + 32 + quad * 8);
            floatx4 z = (floatx4){0.f, 0.f, 0.f, 0.f};
            z = __builtin_amdgcn_mfma_f32_16x16x32_bf16(aq[0], bk0, z, 0, 0, 0);
            sacc[n0] = __builtin_amdgcn_mfma_f32_16x16x32_bf16(aq[1], bk1, z, 0, 0, 0);
        }
        float sv[4][4];
#pragma unroll
        for (int n0 = 0; n0 < 4; ++n0)
#pragma unroll
            for (int r = 0; r < 4; ++r) sv[n0][r] = sacc[n0][r] * 0.125f;
        if (t == ntiles - 1) {
#pragma unroll
            for (int n0 = 0; n0 < 4; ++n0)
#pragma unroll
                for (int r = 0; r < 4; ++r)
                    if (n0 * 16 + lr > wave * 16 + quad * 4 + r) sv[n0][r] = -1e30f;
        }
        float al[4];
#pragma unroll
        for (int r = 0; r < 4; ++r) {
            float tm = fmaxf(fmaxf(sv[0][r], sv[1][r]), fmaxf(sv[2][r], sv[3][r]));
            tm = fmaxf(tm, __shfl_xor(tm, 1));
            tm = fmaxf(tm, __shfl_xor(tm, 2));
            tm = fmaxf(tm, __shfl_xor(tm, 4));
            tm = fmaxf(tm, __shfl_xor(tm, 8));
            float mn = fmaxf(mrow[r], tm);
            al[r] = __expf(mrow[r] - mn);
            mrow[r] = mn;
        }
        float rs[4];
#pragma unroll
        for (int r = 0; r < 4; ++r) rs[r] = 0.f;
#pragma unroll
        for (int n0 = 0; n0 < 4; ++n0)
#pragma unroll
            for (int r = 0; r < 4; ++r) {
                float p = __expf(sv[n0][r] - mrow[r]);
                sv[n0][r] = p;
                rs[r] += p;
            }
#pragma unroll
        for (int r = 0; r < 4; ++r) {
            float t2 = rs[r];
            t2 += __shfl_xor(t2, 1);
            t2 += __shfl_xor(t2, 2);
            t2 += __shfl_xor(t2, 4);
            t2 += __shfl_xor(t2, 8);
            lrow[r] = lrow[r] * al[r] + t2;
        }
#pragma unroll
        for (int d0 = 0; d0 < 4; ++d0)
#pragma unroll
            for (int r = 0; r < 4; ++r) Oacc[d0][r] *= al[r];
#pragma unroll
        for (int n0 = 0; n0 < 4; ++n0)
#pragma unroll
            for (int r = 0; r < 4; ++r)
                Ps[(wave * 16 + quad * 4 + r) * ATTS + n0 * 16 + lr] = (bf16)sv[n0][r];
        bf16x8 ap[2];
#pragma unroll
        for (int kc = 0; kc < 2; ++kc)
            ap[kc] = *(const bf16x8*)(Ps + (wave * 16 + lr) * ATTS + kc * 32 + quad * 8);
#pragma unroll
        for (int d0 = 0; d0 < 4; ++d0) {
            bf16x8 bv0 = *(const bf16x8*)(Vs + (d0 * 16 + lr) * ATTS + quad * 8);
            bf16x8 bv1 = *(const bf16x8*)(Vs + (d0 * 16 + lr) * ATTS + 32 + quad * 8);
            Oacc[d0] = __builtin_amdgcn_mfma_f32_16x16x32_bf16(ap[0], bv0, Oacc[d0], 0, 0, 0);
            Oacc[d0] = __builtin_amdgcn_mfma_f32_16x16x32_bf16(ap[1], bv1, Oacc[d0], 0, 0, 0);
        }
    }
    float inv[4];
#pragma unroll
    for (int r = 0; r < 4; ++r) inv[r] = 1.f / lrow[r];
#pragma unroll
    for (int d0 = 0; d0 < 4; ++d0)
#pragma unroll
        for (int r = 0; r < 4; ++r) {
            int row = b * 1024 + q0 + wave * 16 + quad * 4 + r;
            int col = hh * 64 + d0 * 16 + lr;
            O[(size_t)row * 512 + col] = (bf16)(Oacc[d0][r] * inv[r]);
        }
}

// ------------------------------- delta scan --------------------------------
// Round 13: 32 blocks x 512 threads. Waves 0-3 (role 0) run the round-9
// verified 2-token pair scan on chunk c; waves 4-7 (role 1) stage chunk c+1
// into the other LDS buffer. One barrier per chunk swaps buffers. ctx store
// is per-wave-own-rows (wave w stores S-rows 8w..8w+7 that it wrote), so no
// extra barrier between scan and store. Pair math identical to round 9:
//   u1 = bv1 - b1*a1*d1; au1 = a2*u1; A = a1*a2
//   pred2 = A*d2 + au1*c12;           u2 = bv2 - b2*pred2
//   s'' = A*s + au1*k1 + u2*k2
//   out1 = a1*dq1 + u1*(k1.q1);       out2 = A*dq2 + au1*(k1.q2) + u2*(k2.q2)
__global__ __launch_bounds__(512, 2) void delta_scan(
    const float* __restrict__ P, const float* __restrict__ S_in,
    const float* __restrict__ bbias, const float* __restrict__ abias,
    float* __restrict__ S_out, float* __restrict__ ctx) {
    int bh = blockIdx.x;
    int b = bh >> 3, hh = bh & 7;
    int tid = threadIdx.x;
    int role = tid >> 8;            // 0 = compute (waves 0-3), 1 = stage (4-7)
    int htid = tid & 255;
    int lane = htid & 63;
    int wv = htid >> 6;             // wave within role group
    int ri = wv * 8 + (lane >> 3);
    int c = lane & 7;
    bool cz = (c == 0);
    // double-buffered staging arrays (ks rows 64/65 = loadp pad)
    __shared__ __align__(16) float ks[2][66][36], qs[2][66][36], vs[2][66][36],
                                   bs[2][66][36], as_[2][66][36];
    __shared__ __align__(16) float cpair[2][33][4]; // [pair][c12,k1q1,k1q2,k2q2]
    __shared__ __align__(16) float cs[64][32];      // compute-only, single
    float4 S = *(const float4*)(S_in + ((size_t)bh * 32 + ri) * 32 + c * 4);

    int sc4 = htid & 7, sr0 = htid >> 3;   // staging map: token rows sr0, sr0+32
    float4 bB = *(const float4*)(bbias + hh * 32 + sc4 * 4);
    float4 bA = *(const float4*)(abias + hh * 32 + sc4 * 4);

    struct Pair {
        float4 k1, k2, q1, q2;
        float a1, a2, b1, b2, bv1, bv2;
        float c12, cq11, cq12, cq22;
    };

    auto dot4 = [](float4 s, float4 k) {
        return fmaf(s.w, k.w, fmaf(s.z, k.z, fmaf(s.y, k.y, s.x * k.x)));
    };

    // ---- stage one 64-token chunk into buffer `buf` (role-1 waves) ----
    auto stage_chunk = [&](int c0, int buf) {
        float (*ksH)[36] = ks[buf];
        float (*qsH)[36] = qs[buf];
        float (*vsH)[36] = vs[buf];
        float (*bsH)[36] = bs[buf];
        float (*asH)[36] = as_[buf];
        float (*cpH)[4]  = cpair[buf];
        const float* Pb = P + ((size_t)(b * 1024 + c0) * 1536) + hh * 32 + sc4 * 4;
#pragma unroll
        for (int it = 0; it < 2; ++it) {
            int tok = sr0 + it * 32;
            const float* pg = Pb + (size_t)tok * 1536;
            float4 kv = *(const float4*)(pg);
            float4 vv = *(const float4*)(pg + 256);
            float4 qv = *(const float4*)(pg + 512);
            float4 bv = *(const float4*)(pg + 768);
            float4 av = *(const float4*)(pg + 1024);
            float ss = kv.x * kv.x + kv.y * kv.y + kv.z * kv.z + kv.w * kv.w;
            ss = sum8(ss);
            float rn = 1.f / fmaxf(sqrtf(ss), 1e-12f);
            kv.x *= rn; kv.y *= rn; kv.z *= rn; kv.w *= rn;
            float4 bo, ao;
            bo.x = 1.f / (1.f + __expf(-(bv.x + bB.x)));
            bo.y = 1.f / (1.f + __expf(-(bv.y + bB.y)));
            bo.z = 1.f / (1.f + __expf(-(bv.z + bB.z)));
            bo.w = 1.f / (1.f + __expf(-(bv.w + bB.w)));
            ao.x = 1.f / (1.f + __expf(-(av.x + bA.x)));
            ao.y = 1.f / (1.f + __expf(-(av.y + bA.y)));
            ao.z = 1.f / (1.f + __expf(-(av.z + bA.z)));
            ao.w = 1.f / (1.f + __expf(-(av.w + bA.w)));
            float4 vo;
            vo.x = bo.x * vv.x; vo.y = bo.y * vv.y;
            vo.z = bo.z * vv.z; vo.w = bo.w * vv.w;
            // pair-shared dots: tokens 2j/2j+1 in adjacent 8-lane groups
            float kq = sum8(kv.x * qv.x + kv.y * qv.y + kv.z * qv.z + kv.w * qv.w);
            float4 ko, qo;
            ko.x = __shfl_xor(kv.x, 8); ko.y = __shfl_xor(kv.y, 8);
            ko.z = __shfl_xor(kv.z, 8); ko.w = __shfl_xor(kv.w, 8);
            qo.x = __shfl_xor(qv.x, 8); qo.y = __shfl_xor(qv.y, 8);
            qo.z = __shfl_xor(qv.z, 8); qo.w = __shfl_xor(qv.w, 8);
            float ckk = sum8(kv.x * ko.x + kv.y * ko.y + kv.z * ko.z + kv.w * ko.w);
            float ckq = sum8(kv.x * qo.x + kv.y * qo.y + kv.z * qo.z + kv.w * qo.w);
            *(float4*)&ksH[tok][sc4 * 4] = kv;
            *(float4*)&vsH[tok][sc4 * 4] = vo;
            *(float4*)&qsH[tok][sc4 * 4] = qv;
            *(float4*)&bsH[tok][sc4 * 4] = bo;
            *(float4*)&asH[tok][sc4 * 4] = ao;
            if ((htid & 7) == 0) {
                int pairi = tok >> 1;
                if (!(tok & 1)) {
                    cpH[pairi][0] = ckk;   // k1.k2
                    cpH[pairi][1] = kq;    // k1.q1
                    cpH[pairi][2] = ckq;   // k1.q2
                } else {
                    cpH[pairi][3] = kq;    // k2.q2
                }
            }
        }
    };

    // ---- scan one staged chunk from buffer `buf` (role-0 waves) ----
    auto scan_chunk = [&](int c0, int buf) {
        float (*ksH)[36] = ks[buf];
        float (*qsH)[36] = qs[buf];
        float (*vsH)[36] = vs[buf];
        float (*bsH)[36] = bs[buf];
        float (*asH)[36] = as_[buf];
        float (*cpH)[4]  = cpair[buf];
        auto loadp = [&](int t, Pair& Pr) {
            Pr.k1 = *(const float4*)&ksH[2 * t][c * 4];
            Pr.k2 = *(const float4*)&ksH[2 * t + 1][c * 4];
            Pr.q1 = *(const float4*)&qsH[2 * t][c * 4];
            Pr.q2 = *(const float4*)&qsH[2 * t + 1][c * 4];
            Pr.a1 = asH[2 * t][ri];  Pr.a2 = asH[2 * t + 1][ri];
            Pr.b1 = bsH[2 * t][ri];  Pr.b2 = bsH[2 * t + 1][ri];
            Pr.bv1 = vsH[2 * t][ri]; Pr.bv2 = vsH[2 * t + 1][ri];
            float4 cp = *(const float4*)&cpH[t][0];
            Pr.c12 = cp.x; Pr.cq11 = cp.y; Pr.cq12 = cp.z; Pr.cq22 = cp.w;
        };
        auto stepp = [&](const Pair& Pr, int t) {
            float d1  = sum8(dot4(S, Pr.k1));
            float d2  = sum8(dot4(S, Pr.k2));
            float dq1 = sum8(dot4(S, Pr.q1));
            float dq2 = sum8(dot4(S, Pr.q2));
            float u1 = fmaf(-(Pr.b1 * Pr.a1), d1, Pr.bv1);
            float au1 = Pr.a2 * u1;
            float A = Pr.a1 * Pr.a2;
            float pred2 = fmaf(au1, Pr.c12, A * d2);
            float u2 = fmaf(-Pr.b2, pred2, Pr.bv2);
            S.x = fmaf(u2, Pr.k2.x, fmaf(au1, Pr.k1.x, A * S.x));
            S.y = fmaf(u2, Pr.k2.y, fmaf(au1, Pr.k1.y, A * S.y));
            S.z = fmaf(u2, Pr.k2.z, fmaf(au1, Pr.k1.z, A * S.z));
            S.w = fmaf(u2, Pr.k2.w, fmaf(au1, Pr.k1.w, A * S.w));
            if (cz) {
                cs[2 * t][ri]     = fmaf(u1, Pr.cq11, Pr.a1 * dq1);
                cs[2 * t + 1][ri] = fmaf(u2, Pr.cq22, fmaf(au1, Pr.cq12, A * dq2));
            }
        };
        Pair PA, PB;
        loadp(0, PA);
        for (int t = 0; t < 32; t += 2) {
            loadp(t + 1, PB);
            stepp(PA, t);
            loadp(t + 2, PA);   // t==30 -> pair 32: pad rows 64/65, cpair[32]
            stepp(PB, t + 1);
        }
        // per-wave-own-rows ctx store: wave wv wrote cs[t][8wv..8wv+7]
        int gbase = b * 1024 + c0;
#pragma unroll
        for (int it = 0; it < 2; ++it) {
            int e = lane + it * 64;
            int t = e >> 1, j4 = wv * 2 + (e & 1);
            float4 val = *(const float4*)&cs[t][j4 * 4];
            *(float4*)(ctx + (size_t)(gbase + t) * 256 + hh * 32 + j4 * 4) = val;
        }
    };

    // ---- producer/consumer chunk pipeline ----
    if (role == 1) stage_chunk(0, 0);
    __syncthreads();
    for (int ch = 0; ch < 16; ++ch) {
        if (role == 1) {
            if (ch + 1 < 16) stage_chunk((ch + 1) * 64, (ch + 1) & 1);
        } else {
            scan_chunk(ch * 64, ch & 1);
        }
        __syncthreads();
    }
    if (role == 0)
        *(float4*)(S_out + ((size_t)bh * 32 + ri) * 32 + c * 4) = S;
}

// ------------- ctxbf = bf16(rmsnorm(ctx,nw)*silu(gate)), gate in P@1280 ----
__global__ void ctx_post(const float* __restrict__ ctx, const float* __restrict__ P,
                         const float* __restrict__ nw, bf16* __restrict__ out) {
    int row = blockIdx.x, t = threadIdx.x;  // 64 threads
    float4 x = ((const float4*)(ctx + (size_t)row * SDIMM))[t];
    float s = x.x * x.x + x.y * x.y + x.z * x.z + x.w * x.w;
    for (int m = 1; m < 64; m <<= 1) s += __shfl_xor(s, m);
    float r = rsqrtf(s * (1.f / 256.f) + 1e-6f);
    float4 n = ((const float4*)nw)[t];
    float4 g = ((const float4*)(P + (size_t)row * 1536 + 1280))[t];
    BF4 u;
    u.h[0] = (bf16)(x.x * r * n.x * (g.x / (1.f + __expf(-g.x))));
    u.h[1] = (bf16)(x.y * r * n.y * (g.y / (1.f + __expf(-g.y))));
    u.h[2] = (bf16)(x.z * r * n.z * (g.z / (1.f + __expf(-g.z))));
    u.h[3] = (bf16)(x.w * r * n.w * (g.w / (1.f + __expf(-g.w))));
    ((short4*)(out + (size_t)row * SDIMM))[t] = u.p;
}

// ---------------------------------------------------------------------------
extern "C" void kernel_launch(void* const* d_in, const int* in_sizes, int n_in,
                              void* d_out, int out_size, void* d_ws, size_t ws_size,
                              hipStream_t stream) {
    (void)in_sizes; (void)n_in; (void)out_size; (void)ws_size;
    const int* ids = (const int*)d_in[0];
    const float* state = (const float*)d_in[1];
    const float* embedw = (const float*)d_in[2];
    auto F = [&](int i) { return (const float*)d_in[i]; };

    char* wsb = (char*)d_ws;
    const size_t MB = 1048576;
    float* H    = (float*)(wsb);                 // 0-8 MB
    bf16*  XNbf = (bf16*)(wsb + 8 * MB);         // 8-12 (alias ctxf in delta)
    float* ctxf = (float*)(wsb + 8 * MB);
    bf16*  Hbf  = (bf16*)(wsb + 12 * MB);        // 12-16 (alias ctxb)
    bf16*  ctxb = (bf16*)(wsb + 12 * MB);
    float* P    = (float*)(wsb + 16 * MB);       // 16-40 (delta proj f32)
    bf16*  Obf  = (bf16*)(wsb + 40 * MB);        // 40-44 attn out
    bf16*  Qbuf = (bf16*)(wsb + 44 * MB);        // 44-48
    bf16*  Kbuf = (bf16*)(wsb + 48 * MB);        // 48-52
    bf16*  Vtb  = (bf16*)(wsb + 52 * MB);        // 52-56
    bf16*  A1b  = (bf16*)(wsb + 44 * MB);        // alias Q/K/Vt (dead after attn)
    float* cosT = (float*)(wsb + 58 * MB);
    float* sinT = cosT + 32768;
    float* Sbuf = sinT + 32768;
    char*  wbase = wsb + 59 * MB;
    bf16* wqkv  = (bf16*)(wbase);                        // 6x1536x512
    bf16* wob   = (bf16*)(wbase + 9437184);              // 6x512x512
    bf16* wgu   = (bf16*)(wbase + 12582912);             // 6x3072x512 interleaved
    bf16* wdnb  = (bf16*)(wbase + 31457280);             // 6x512x1536
    bf16* wdR   = (bf16*)(wbase + 40894464);             // 1536x512
    bf16* woutR = (bf16*)(wbase + 42467328);             // 512x256
    bf16* wdW   = (bf16*)(wbase + 42729472);             // 1536x512
    bf16* woutW = (bf16*)(wbase + 44302336);             // 512x256
    bf16* embp  = (bf16*)(wbase + 44564480);             // 128x512 padded

    float* out = (float*)d_out;
    float* logits = out;
    float* Sout = out + 4096 * VOCN;

    // 128x128-tile launches
    auto G0 = [&](const bf16* A, const bf16* B, float* C, int M, int N, int K, int Nreal) {
        gemm_bf16<0><<<dim3(N / 128, M / 128), 256, 0, stream>>>(
            A, B, C, nullptr, nullptr, nullptr, nullptr, nullptr, nullptr, M, N, K, Nreal);
    };
    auto G4 = [&](const bf16* A, const bf16* B, bf16* Cb, int M, int N, int K, int Nreal) {
        gemm_bf16<4><<<dim3(N / 128, M / 128), 256, 0, stream>>>(
            A, B, nullptr, Cb, nullptr, nullptr, nullptr, nullptr, nullptr, M, N, K, Nreal);
    };
    auto G5 = [&](const bf16* A, const bf16* B, int M, int N, int K) {
        gemm_bf16<5><<<dim3(N / 128, M / 128), 256, 0, stream>>>(
            A, B, nullptr, nullptr, cosT, sinT, Qbuf, Kbuf, Vtb, M, N, K, N);
    };
    // 64x128-tile accumulate
    auto G1s = [&](const bf16* A, const bf16* B, float* C, int M, int N, int K) {
        gemm64_bf16<1><<<dim3(N / 128, M / 64), 256, 0, stream>>>(A, B, C, M, N, K, N);
    };
    auto G0s = [&](const bf16* A, const bf16* B, float* C, int M, int N, int K, int Nreal) {
        gemm64_bf16<0><<<dim3(N / 128, M / 64), 256, 0, stream>>>(A, B, C, M, N, K, Nreal);
    };
    auto CP = [&](const float* s, bf16* d, int n4) {
        cast_plain<<<(n4 + 255) / 256, 256, 0, stream>>>(s, d, n4);
    };

    // ---- weight casts ----
    cast_qkv<<<4608, 256, 0, stream>>>(F(24), F(25), F(26), wqkv);
    CP(F(27), wob, 393216);
    cast_gu<<<9216, 256, 0, stream>>>(F(29), F(30), wgu);
    CP(F(31), wdnb, 1179648);
    cast6<<<768, 256, 0, stream>>>(F(3), F(4), F(5), F(6), F(8), F(12), wdR);
    CP(F(10), woutR, 32768);
    cast6<<<768, 256, 0, stream>>>(F(13), F(14), F(15), F(16), F(18), F(22), wdW);
    CP(F(20), woutW, 32768);
    cast_embed_pad<<<64, 256, 0, stream>>>(embedw, embp);

    rope_tables_k<<<128, 256, 0, stream>>>(cosT, sinT);
    embed_k<<<4096, 128, 0, stream>>>(ids, embedw, H);

    // ---- delta read ----
    CP(H, Hbf, 524288);
    G0(Hbf, wdR, P, 4096, 1536, 512, 1536);
    delta_scan<<<32, 512, 0, stream>>>(P, state, F(7), F(9), Sbuf, ctxf);
    ctx_post<<<4096, 64, 0, stream>>>(ctxf, P, F(11), ctxb);
    G1s(ctxb, woutR, H, 4096, 512, 256);

    for (int i = 0; i < 6; ++i) {
        rmsnorm512<<<4096, 128, 0, stream>>>(H, F(23) + (size_t)i * 512, XNbf);
        G5(XNbf, wqkv + (size_t)i * 1536 * 512, 4096, 1536, 512);
        attn_mfma<<<dim3(16, 8, 4), 256, 0, stream>>>(Qbuf, Kbuf, Vtb, Obf);
        G1s(Obf, wob + (size_t)i * 512 * 512, H, 4096, 512, 512);
        rmsnorm512<<<4096, 128, 0, stream>>>(H, F(28) + (size_t)i * 512, XNbf);
        G4(XNbf, wgu + (size_t)i * 3072 * 512, A1b, 4096, 3072, 512, 1536);
        G1s(A1b, wdnb + (size_t)i * 512 * 1536, H, 4096, 512, 1536);
    }

    // ---- delta write ----
    CP(H, Hbf, 524288);
    G0(Hbf, wdW, P, 4096, 1536, 512, 1536);
    delta_scan<<<32, 512, 0, stream>>>(P, Sbuf, F(17), F(19), Sout, ctxf);
    ctx_post<<<4096, 64, 0, stream>>>(ctxf, P, F(21), ctxb);
    G1s(ctxb, woutW, H, 4096, 512, 256);

    rmsnorm512<<<4096, 128, 0, stream>>>(H, F(32), XNbf);
    G0s(XNbf, embp, logits, 4096, 128, 512, VOCN);
}

// Round 6
// 1303.531 us; speedup vs baseline: 1.1666x; 1.0452x over previous
//
#include <hip/hip_runtime.h>
#include <hip/hip_bf16.h>
#include <math.h>

// ---------------------------------------------------------------------------
// BashTransformer forward on MI355X. Round 14: both GEMM kernels move to
// BK=64 (half the per-K barrier drains) with free XOR-swizzled LDS layout
// (pre-swizzled global source + constant swizzled read units; row&7==lane&7
// so the read XOR folds into a per-lane constant). delta_scan keeps the
// round-13 producer/consumer structure (95 us, verified).
// ---------------------------------------------------------------------------

#define LSEQ 1024
#define BATCH 4
#define HIDDEN 512
#define NHEAD 8
#define HDIM 64
#define SHEAD 8
#define SDHD 32
#define SDIMM 256
#define FFND 1536
#define VOCN 63
#define ATTS 72   // attn LDS row stride (elems): 144B = 16B-aligned, 2-way banks

typedef __bf16 bf16;
typedef __attribute__((ext_vector_type(8))) __bf16 bf16x8;
typedef __attribute__((ext_vector_type(4))) float floatx4;

union BF4 { bf16 h[4]; short4 p; };

__device__ __forceinline__ void gload16(const void* g, const void* l) {
    __builtin_amdgcn_global_load_lds(
        (__attribute__((address_space(1))) unsigned int*)(uintptr_t)g,
        (__attribute__((address_space(3))) unsigned int*)(unsigned int)(uintptr_t)l,
        16, 0, 0);
}

// sum over aligned groups of 8 lanes, pure DPP (VALU pipe, no LDS counters)
__device__ __forceinline__ float sum8(float x) {
    x += __int_as_float(__builtin_amdgcn_mov_dpp(__float_as_int(x), 0xB1, 0xF, 0xF, true));
    x += __int_as_float(__builtin_amdgcn_mov_dpp(__float_as_int(x), 0x4E, 0xF, 0xF, true));
    x += __int_as_float(__builtin_amdgcn_mov_dpp(__float_as_int(x), 0x141, 0xF, 0xF, true));
    return x;
}

// ------------------------------- rope tables -------------------------------
__global__ void rope_tables_k(float* __restrict__ cosT, float* __restrict__ sinT) {
    int idx = blockIdx.x * 256 + threadIdx.x;   // 32768 = 1024*32
    int l = idx >> 5, d = idx & 31;
    double ang = (double)l * pow(500000.0, -(double)(2 * d) / 64.0);
    cosT[idx] = (float)cos(ang);
    sinT[idx] = (float)sin(ang);
}

// ------------------------------- embedding ---------------------------------
__global__ void embed_k(const int* __restrict__ ids, const float* __restrict__ emb,
                        float* __restrict__ h) {
    int tok = blockIdx.x;
    int id = ids[tok];
    ((float4*)(h + (size_t)tok * HIDDEN))[threadIdx.x] =
        ((const float4*)(emb + (size_t)id * HIDDEN))[threadIdx.x];
}

// ------------------------------- casts -------------------------------------
__global__ void cast_plain(const float* __restrict__ s, bf16* __restrict__ d, int n4) {
    int i = blockIdx.x * 256 + threadIdx.x;
    if (i >= n4) return;
    float4 v = ((const float4*)s)[i];
    BF4 u;
    u.h[0] = (bf16)v.x; u.h[1] = (bf16)v.y; u.h[2] = (bf16)v.z; u.h[3] = (bf16)v.w;
    ((short4*)d)[i] = u.p;
}

// six 256x512 f32 matrices -> one fused 1536x512 bf16 (order s0..s5)
__global__ void cast6(const float* s0, const float* s1, const float* s2,
                      const float* s3, const float* s4, const float* s5,
                      bf16* __restrict__ d) {
    int i = blockIdx.x * 256 + threadIdx.x;      // 196608 short4s
    if (i >= 196608) return;
    int which = i >> 15, loc = i & 32767;
    const float* s = which == 0 ? s0 : which == 1 ? s1 : which == 2 ? s2
                    : which == 3 ? s3 : which == 4 ? s4 : s5;
    float4 v = ((const float4*)s)[loc];
    BF4 u;
    u.h[0] = (bf16)v.x; u.h[1] = (bf16)v.y; u.h[2] = (bf16)v.z; u.h[3] = (bf16)v.w;
    ((short4*)d)[i] = u.p;
}

// wq/wk/wv (6,512,512) each -> fused (6,1536,512) rows [layer*1536+which*512+r]
__global__ void cast_qkv(const float* __restrict__ q, const float* __restrict__ k,
                         const float* __restrict__ v, bf16* __restrict__ d) {
    int idx = blockIdx.x * 256 + threadIdx.x;    // 3*393216
    if (idx >= 1179648) return;
    int which = idx / 393216;
    int rem = idx - which * 393216;
    const float* s = which == 0 ? q : which == 1 ? k : v;
    int layer = rem >> 16, rr = rem & 65535;     // 512*128 per layer
    int r = rr >> 7, c4 = rr & 127;
    float4 x = ((const float4*)s)[rem];
    BF4 u;
    u.h[0] = (bf16)x.x; u.h[1] = (bf16)x.y; u.h[2] = (bf16)x.z; u.h[3] = (bf16)x.w;
    ((short4*)d)[((size_t)layer * 1536 + which * 512 + r) * 128 + c4] = u.p;
}

// w_gate/w_up (6,1536,512) -> interleaved (6,3072,512) rows [layer*3072+2r+which]
__global__ void cast_gu(const float* __restrict__ g, const float* __restrict__ uu,
                        bf16* __restrict__ d) {
    int idx = blockIdx.x * 256 + threadIdx.x;    // 2*1179648
    if (idx >= 2359296) return;
    int which = idx / 1179648;
    int rem = idx - which * 1179648;
    const float* s = which == 0 ? g : uu;
    int layer = rem / 196608, rr = rem - layer * 196608;  // 1536*128
    int r = rr >> 7, c4 = rr & 127;
    float4 x = ((const float4*)s)[rem];
    BF4 u;
    u.h[0] = (bf16)x.x; u.h[1] = (bf16)x.y; u.h[2] = (bf16)x.z; u.h[3] = (bf16)x.w;
    ((short4*)d)[((size_t)layer * 3072 + r * 2 + which) * 128 + c4] = u.p;
}

__global__ void cast_embed_pad(const float* __restrict__ s, bf16* __restrict__ d) {
    int i = blockIdx.x * 256 + threadIdx.x;   // 128*128 = 16384 short4s
    int row = i >> 7, c4 = i & 127;
    BF4 u;
    if (row < VOCN) {
        float4 v = ((const float4*)s)[row * 128 + c4];
        u.h[0] = (bf16)v.x; u.h[1] = (bf16)v.y; u.h[2] = (bf16)v.z; u.h[3] = (bf16)v.w;
    } else {
        u.h[0] = (bf16)0.f; u.h[1] = (bf16)0.f; u.h[2] = (bf16)0.f; u.h[3] = (bf16)0.f;
    }
    ((short4*)d)[i] = u.p;
}

// ------------------------------- rmsnorm -> bf16 ---------------------------
__global__ void rmsnorm512(const float* __restrict__ in, const float* __restrict__ w,
                           bf16* __restrict__ out) {
    int row = blockIdx.x, t = threadIdx.x;     // 128 threads
    float4 x = ((const float4*)(in + (size_t)row * 512))[t];
    float s = x.x * x.x + x.y * x.y + x.z * x.z + x.w * x.w;
    for (int m = 1; m < 64; m <<= 1) s += __shfl_xor(s, m);
    __shared__ float red[2];
    if ((t & 63) == 0) red[t >> 6] = s;
    __syncthreads();
    float tot = red[0] + red[1];
    float r = rsqrtf(tot * (1.f / 512.f) + 1e-6f);
    float4 wv = ((const float4*)w)[t];
    BF4 u;
    u.h[0] = (bf16)(x.x * r * wv.x); u.h[1] = (bf16)(x.y * r * wv.y);
    u.h[2] = (bf16)(x.z * r * wv.z); u.h[3] = (bf16)(x.w * r * wv.w);
    ((short4*)(out + (size_t)row * 512))[t] = u.p;
}

// ------------------------------- bf16 MFMA GEMM (128x128) ------------------
// C = A(bf16, MxK rm) @ B(bf16, NxK rm)^T. 128x128 tile, BK=64, 4 waves.
// LDS layout XOR-swizzled by 16B unit: LDS[r][u] = global[r][u ^ (r&7)],
// achieved via pre-swizzled global source (gload_lds dest stays linear).
// Fragment reads use unit (kk*4 + lane>>4) ^ (lane&7) — row&7 == lane&7 for
// all fragment rows since m0/n0 are multiples of 8. Conflict-free ds_read.
// MODE 0: C(f32)=v
// MODE 4: gate/up interleaved cols; Cb[row*Nreal+col/2]=bf16(silu(g)*u)
// MODE 5: fused QKV epilogue: RoPE(q,k)->Qb/Kb bf16 [bh][l][64], v->Vtb
//         [bh][d][l]. Requires N=1536 layout q|k|v and M = b-major tokens.
template <int MODE>
__global__ __launch_bounds__(256) void gemm_bf16(const bf16* __restrict__ A,
                                                 const bf16* __restrict__ B,
                                                 float* __restrict__ C,
                                                 bf16* __restrict__ Cb,
                                                 const float* __restrict__ cosT,
                                                 const float* __restrict__ sinT,
                                                 bf16* __restrict__ Qb,
                                                 bf16* __restrict__ Kb,
                                                 bf16* __restrict__ Vtb,
                                                 int M, int N, int K, int Nreal) {
    __shared__ bf16 As[128 * 64];
    __shared__ bf16 Bs[128 * 64];
    const int tid = threadIdx.x;
    const int wave = tid >> 6, lane = tid & 63;
    const int row0 = blockIdx.y * 128, col0 = blockIdx.x * 128;
    floatx4 acc[4][4];
#pragma unroll
    for (int i = 0; i < 4; ++i)
#pragma unroll
        for (int j = 0; j < 4; ++j) acc[i][j] = (floatx4){0.f, 0.f, 0.f, 0.f};
    const int m0 = (wave & 1) * 64, n0 = (wave >> 1) * 64;
    const int sr = tid >> 3;                       // 32 rows per staging call
    const int ske = ((tid & 7) ^ (sr & 7)) * 8;    // pre-swizzled k offset (elems)
    char* AsB = (char*)As;
    char* BsB = (char*)Bs;
    const int ldst = wave * 1024;
    const int ua0 = (((lane >> 4) + 0) ^ (lane & 7)) * 16;   // kk=0 unit byte
    const int ua1 = (((lane >> 4) + 4) ^ (lane & 7)) * 16;   // kk=1 unit byte

    for (int k0 = 0; k0 < K; k0 += 64) {
#pragma unroll
        for (int j = 0; j < 4; ++j) {
            gload16(A + (size_t)(row0 + j * 32 + sr) * K + ske + k0,
                    AsB + j * 4096 + ldst);
            gload16(B + (size_t)(col0 + j * 32 + sr) * K + ske + k0,
                    BsB + j * 4096 + ldst);
        }
        __syncthreads();
#pragma unroll
        for (int kk = 0; kk < 2; ++kk) {
            const int uu = kk ? ua1 : ua0;
            bf16x8 af[4], bfr[4];
#pragma unroll
            for (int mi = 0; mi < 4; ++mi)
                af[mi] = *(const bf16x8*)(AsB + (m0 + mi * 16 + (lane & 15)) * 128 + uu);
#pragma unroll
            for (int ni = 0; ni < 4; ++ni)
                bfr[ni] = *(const bf16x8*)(BsB + (n0 + ni * 16 + (lane & 15)) * 128 + uu);
#pragma unroll
            for (int mi = 0; mi < 4; ++mi)
#pragma unroll
                for (int ni = 0; ni < 4; ++ni)
                    acc[mi][ni] = __builtin_amdgcn_mfma_f32_16x16x32_bf16(af[mi], bfr[ni], acc[mi][ni], 0, 0, 0);
        }
        __syncthreads();
    }
    const int cr = (lane >> 4) * 4;
    const int cc = lane & 15;
    if (MODE == 5) {
        // wave-uniform 64-col span: segment + head fixed per wave
        int segbase = col0 + n0;
        int seg = segbase >> 9;           // 0=q 1=k 2=v
        int head = (segbase >> 6) & 7;
#pragma unroll
        for (int mi = 0; mi < 4; ++mi) {
#pragma unroll
            for (int r = 0; r < 4; ++r) {
                int row = row0 + m0 + mi * 16 + cr + r;
                int b = row >> 10, l = row & 1023;
                size_t bh = (size_t)(b * 8 + head);
                float x0 = acc[mi][0][r], x1 = acc[mi][1][r];
                float x2 = acc[mi][2][r], x3 = acc[mi][3][r];
                if (seg < 2) {
                    float c0 = cosT[l * 32 + cc], c1 = cosT[l * 32 + 16 + cc];
                    float s0 = sinT[l * 32 + cc], s1 = sinT[l * 32 + 16 + cc];
                    bf16* dst = (seg == 0 ? Qb : Kb) + bh * 65536 + l * 64;
                    dst[cc]      = (bf16)(x0 * c0 - x2 * s0);
                    dst[16 + cc] = (bf16)(x1 * c1 - x3 * s1);
                    dst[32 + cc] = (bf16)(x2 * c0 + x0 * s0);
                    dst[48 + cc] = (bf16)(x3 * c1 + x1 * s1);
                } else {
                    bf16* dst = Vtb + bh * 65536 + l;
                    dst[(size_t)(cc) * 1024]      = (bf16)x0;
                    dst[(size_t)(16 + cc) * 1024] = (bf16)x1;
                    dst[(size_t)(32 + cc) * 1024] = (bf16)x2;
                    dst[(size_t)(48 + cc) * 1024] = (bf16)x3;
                }
            }
        }
        return;
    }
#pragma unroll
    for (int mi = 0; mi < 4; ++mi) {
#pragma unroll
        for (int ni = 0; ni < 4; ++ni) {
#pragma unroll
            for (int r = 0; r < 4; ++r) {
                int row = row0 + m0 + mi * 16 + cr + r;
                int col = col0 + n0 + ni * 16 + cc;
                float v = acc[mi][ni][r];
                if (MODE == 4) {
                    float o = __shfl_xor(v, 1);
                    if (!(lane & 1)) {
                        float sg = v / (1.f + __expf(-v));
                        Cb[(size_t)row * Nreal + (col >> 1)] = (bf16)(sg * o);
                    }
                } else if (col < Nreal) {
                    size_t off = (size_t)row * Nreal + col;
                    if (MODE == 0) C[off] = v;
                }
            }
        }
    }
}

// ---------------------- 64x128-tile GEMM (accumulate) ----------------------
// Tile M=64, N=128, 4 waves each 32x64, BK=64, swizzled LDS (see gemm_bf16).
// MODE 0: C=v  MODE 1: C+=v
template <int MODE>
__global__ __launch_bounds__(256) void gemm64_bf16(const bf16* __restrict__ A,
                                                   const bf16* __restrict__ B,
                                                   float* __restrict__ C,
                                                   int M, int N, int K, int Nreal) {
    __shared__ bf16 As[64 * 64];
    __shared__ bf16 Bs[128 * 64];
    const int tid = threadIdx.x;
    const int wave = tid >> 6, lane = tid & 63;
    const int row0 = blockIdx.y * 64, col0 = blockIdx.x * 128;
    floatx4 acc[2][4];
#pragma unroll
    for (int i = 0; i < 2; ++i)
#pragma unroll
        for (int j = 0; j < 4; ++j) acc[i][j] = (floatx4){0.f, 0.f, 0.f, 0.f};
    const int m0 = (wave & 1) * 32, n0 = (wave >> 1) * 64;
    const int sr = tid >> 3;
    const int ske = ((tid & 7) ^ (sr & 7)) * 8;
    char* AsB = (char*)As;
    char* BsB = (char*)Bs;
    const int ldst = wave * 1024;
    const int ua0 = (((lane >> 4) + 0) ^ (lane & 7)) * 16;
    const int ua1 = (((lane >> 4) + 4) ^ (lane & 7)) * 16;

    for (int k0 = 0; k0 < K; k0 += 64) {
#pragma unroll
        for (int j = 0; j < 2; ++j)
            gload16(A + (size_t)(row0 + j * 32 + sr) * K + ske + k0,
                    AsB + j * 4096 + ldst);
#pragma unroll
        for (int j = 0; j < 4; ++j)
            gload16(B + (size_t)(col0 + j * 32 + sr) * K + ske + k0,
                    BsB + j * 4096 + ldst);
        __syncthreads();
#pragma unroll
        for (int kk = 0; kk < 2; ++kk) {
            const int uu = kk ? ua1 : ua0;
            bf16x8 af[2], bfr[4];
#pragma unroll
            for (int mi = 0; mi < 2; ++mi)
                af[mi] = *(const bf16x8*)(AsB + (m0 + mi * 16 + (lane & 15)) * 128 + uu);
#pragma unroll
            for (int ni = 0; ni < 4; ++ni)
                bfr[ni] = *(const bf16x8*)(BsB + (n0 + ni * 16 + (lane & 15)) * 128 + uu);
#pragma unroll
            for (int mi = 0; mi < 2; ++mi)
#pragma unroll
                for (int ni = 0; ni < 4; ++ni)
                    acc[mi][ni] = __builtin_amdgcn_mfma_f32_16x16x32_bf16(af[mi], bfr[ni], acc[mi][ni], 0, 0, 0);
        }
        __syncthreads();
    }
    const int cr = (lane >> 4) * 4;
    const int cc = lane & 15;
#pragma unroll
    for (int mi = 0; mi < 2; ++mi) {
#pragma unroll
        for (int ni = 0; ni < 4; ++ni) {
#pragma unroll
            for (int r = 0; r < 4; ++r) {
                int row = row0 + m0 + mi * 16 + cr + r;
                int col = col0 + n0 + ni * 16 + cc;
                if (col < Nreal) {
                    size_t off = (size_t)row * Nreal + col;
                    float v = acc[mi][ni][r];
                    if (MODE == 0) C[off] = v;
                    else C[off] += v;
                }
            }
        }
    }
}

// ------------------------- MFMA flash attention ----------------------------
__global__ __launch_bounds__(256) void attn_mfma(const bf16* __restrict__ Qb,
                                                 const bf16* __restrict__ Kb,
                                                 const bf16* __restrict__ Vtb,
                                                 bf16* __restrict__ O) {
    int qt = blockIdx.x, hh = blockIdx.y, b = blockIdx.z;
    int bh = b * 8 + hh;
    int q0 = qt * 64;
    const bf16* Qg = Qb + ((size_t)bh * 1024 + q0) * 64;
    const bf16* Kg = Kb + (size_t)bh * 1024 * 64;
    const bf16* Vg = Vtb + (size_t)bh * 64 * 1024;   // [64 d][1024 l]
    __shared__ bf16 Qs[64 * ATTS];
    __shared__ bf16 Ks[64 * ATTS];
    __shared__ bf16 Vs[64 * ATTS];
    __shared__ bf16 Ps[64 * ATTS];
    int tid = threadIdx.x, wave = tid >> 6, lane = tid & 63;
    int lr = lane & 15, quad = lane >> 4;

#pragma unroll
    for (int it = 0; it < 2; ++it) {
        int cidx = tid + it * 256;
        int row = cidx >> 3, ch = cidx & 7;
        *(bf16x8*)(Qs + row * ATTS + ch * 8) = *(const bf16x8*)(Qg + row * 64 + ch * 8);
    }
    float mrow[4], lrow[4];
    floatx4 Oacc[4];
#pragma unroll
    for (int r = 0; r < 4; ++r) { mrow[r] = -1e30f; lrow[r] = 0.f; }
#pragma unroll
    for (int d0 = 0; d0 < 4; ++d0) Oacc[d0] = (floatx4){0.f, 0.f, 0.f, 0.f};

    int ntiles = qt + 1;
    for (int t = 0; t < ntiles; ++t) {
        int kv0 = t * 64;
        __syncthreads();
#pragma unroll
        for (int it = 0; it < 2; ++it) {
            int cidx = tid + it * 256;
            int row = cidx >> 3, ch = cidx & 7;
            *(bf16x8*)(Ks + row * ATTS + ch * 8) =
                *(const bf16x8*)(Kg + (size_t)(kv0 + row) * 64 + ch * 8);
            *(bf16x8*)(Vs + row * ATTS + ch * 8) =
                *(const bf16x8*)(Vg + (size_t)row * 1024 + kv0 + ch * 8);
        }
        __syncthreads();
        bf16x8 aq[2];
#pragma unroll
        for (int kc = 0; kc < 2; ++kc)
            aq[kc] = *(const bf16x8*)(Qs + (wave * 16 + lr) * ATTS + kc * 32 + quad * 8);
        floatx4 sacc[4];
#pragma unroll
        for (int n0 = 0; n0 < 4; ++n0) {
            bf16x8 bk0 = *(const bf16x8*)(Ks + (n0 * 16 + lr) * ATTS + quad * 8);
            bf16x8 bk1 = *(const bf16x8*)(Ks + (n0 * 16 + lr) * ATTS + 32 + quad * 8);
            floatx4 z = (floatx4){0.f, 0.f, 0.f, 0.f};
            z = __builtin_amdgcn_mfma_f32_16x16x32_bf16(aq[0], bk0, z, 0, 0, 0);
            sacc[n0] = __builtin_amdgcn_mfma_f32_16x16x32_bf16(aq[1], bk1, z, 0, 0, 0);
        }
        float sv[4][4];
#pragma unroll
        for (int n0 = 0; n0 < 4; ++n0)
#pragma unroll
            for (int r = 0; r < 4; ++r) sv[n0][r] = sacc[n0][r] * 0.125f;
        if (t == ntiles - 1) {
#pragma unroll
            for (int n0 = 0; n0 < 4; ++n0)
#pragma unroll
                for (int r = 0; r < 4; ++r)
                    if (n0 * 16 + lr > wave * 16 + quad * 4 + r) sv[n0][r] = -1e30f;
        }
        float al[4];
#pragma unroll
        for (int r = 0; r < 4; ++r) {
            float tm = fmaxf(fmaxf(sv[0][r], sv[1][r]), fmaxf(sv[2][r], sv[3][r]));
            tm = fmaxf(tm, __shfl_xor(tm, 1));
            tm = fmaxf(tm, __shfl_xor(tm, 2));
            tm = fmaxf(tm, __shfl_xor(tm, 4));
            tm = fmaxf(tm, __shfl_xor(tm, 8));
            float mn = fmaxf(mrow[r], tm);
            al[r] = __expf(mrow[r] - mn);
            mrow[r] = mn;
        }
        float rs[4];
#pragma unroll
        for (int r = 0; r < 4; ++r) rs[r] = 0.f;
#pragma unroll
        for (int n0 = 0; n0 < 4; ++n0)
#pragma unroll
            for (int r = 0; r < 4; ++r) {
                float p = __expf(sv[n0][r] - mrow[r]);
                sv[n0][r] = p;
                rs[r] += p;
            }
#pragma unroll
        for (int r = 0; r < 4; ++r) {
            float t2 = rs[r];
            t2 += __shfl_xor(t2, 1);
            t2 += __shfl_xor(t2, 2);
            t2 += __shfl_xor(t2, 4);
            t2 += __shfl_xor(t2, 8);
            lrow[r] = lrow[r] * al[r] + t2;
        }
#pragma unroll
        for (int d0 = 0; d0 < 4; ++d0)
#pragma unroll
            for (int r = 0; r < 4; ++r) Oacc[d0][r] *= al[r];
#pragma unroll
        for (int n0 = 0; n0 < 4; ++n0)
#pragma unroll
            for (int r = 0; r < 4; ++r)
                Ps[(wave * 16 + quad * 4 + r) * ATTS + n0 * 16 + lr] = (bf16)sv[n0][r];
        bf16x8 ap[2];
#pragma unroll
        for (int kc = 0; kc < 2; ++kc)
            ap[kc] = *(const bf16x8*)(Ps + (wave * 16 + lr) * ATTS + kc * 32 + quad * 8);
#pragma unroll
        for (int d0 = 0; d0 < 4; ++d0) {
            bf16x8 bv0 = *(const bf16x8*)(Vs + (d0 * 16 + lr) * ATTS + quad * 8);
            bf16x8 bv1 = *(const bf16x8*)(Vs + (d0 * 16 + lr) * ATTS + 32 + quad * 8);
            Oacc[d0] = __builtin_amdgcn_mfma_f32_16x16x32_bf16(ap[0], bv0, Oacc[d0], 0, 0, 0);
            Oacc[d0] = __builtin_amdgcn_mfma_f32_16x16x32_bf16(ap[1], bv1, Oacc[d0], 0, 0, 0);
        }
    }
    float inv[4];
#pragma unroll
    for (int r = 0; r < 4; ++r) inv[r] = 1.f / lrow[r];
#pragma unroll
    for (int d0 = 0; d0 < 4; ++d0)
#pragma unroll
        for (int r = 0; r < 4; ++r) {
            int row = b * 1024 + q0 + wave * 16 + quad * 4 + r;
            int col = hh * 64 + d0 * 16 + lr;
            O[(size_t)row * 512 + col] = (bf16)(Oacc[d0][r] * inv[r]);
        }
}

// ------------------------------- delta scan --------------------------------
// Round 13 structure (verified, 95 us): 32 blocks x 512 threads. Waves 0-3
// (role 0) run the round-9 verified 2-token pair scan on chunk c; waves 4-7
// (role 1) stage chunk c+1 into the other LDS buffer. One barrier per chunk.
// Pair math identical to round 9.
__global__ __launch_bounds__(512, 2) void delta_scan(
    const float* __restrict__ P, const float* __restrict__ S_in,
    const float* __restrict__ bbias, const float* __restrict__ abias,
    float* __restrict__ S_out, float* __restrict__ ctx) {
    int bh = blockIdx.x;
    int b = bh >> 3, hh = bh & 7;
    int tid = threadIdx.x;
    int role = tid >> 8;            // 0 = compute (waves 0-3), 1 = stage (4-7)
    int htid = tid & 255;
    int lane = htid & 63;
    int wv = htid >> 6;             // wave within role group
    int ri = wv * 8 + (lane >> 3);
    int c = lane & 7;
    bool cz = (c == 0);
    // double-buffered staging arrays (ks rows 64/65 = loadp pad)
    __shared__ __align__(16) float ks[2][66][36], qs[2][66][36], vs[2][66][36],
                                   bs[2][66][36], as_[2][66][36];
    __shared__ __align__(16) float cpair[2][33][4]; // [pair][c12,k1q1,k1q2,k2q2]
    __shared__ __align__(16) float cs[64][32];      // compute-only, single
    float4 S = *(const float4*)(S_in + ((size_t)bh * 32 + ri) * 32 + c * 4);

    int sc4 = htid & 7, sr0 = htid >> 3;   // staging map: token rows sr0, sr0+32
    float4 bB = *(const float4*)(bbias + hh * 32 + sc4 * 4);
    float4 bA = *(const float4*)(abias + hh * 32 + sc4 * 4);

    struct Pair {
        float4 k1, k2, q1, q2;
        float a1, a2, b1, b2, bv1, bv2;
        float c12, cq11, cq12, cq22;
    };

    auto dot4 = [](float4 s, float4 k) {
        return fmaf(s.w, k.w, fmaf(s.z, k.z, fmaf(s.y, k.y, s.x * k.x)));
    };

    // ---- stage one 64-token chunk into buffer `buf` (role-1 waves) ----
    auto stage_chunk = [&](int c0, int buf) {
        float (*ksH)[36] = ks[buf];
        float (*qsH)[36] = qs[buf];
        float (*vsH)[36] = vs[buf];
        float (*bsH)[36] = bs[buf];
        float (*asH)[36] = as_[buf];
        float (*cpH)[4]  = cpair[buf];
        const float* Pb = P + ((size_t)(b * 1024 + c0) * 1536) + hh * 32 + sc4 * 4;
#pragma unroll
        for (int it = 0; it < 2; ++it) {
            int tok = sr0 + it * 32;
            const float* pg = Pb + (size_t)tok * 1536;
            float4 kv = *(const float4*)(pg);
            float4 vv = *(const float4*)(pg + 256);
            float4 qv = *(const float4*)(pg + 512);
            float4 bv = *(const float4*)(pg + 768);
            float4 av = *(const float4*)(pg + 1024);
            float ss = kv.x * kv.x + kv.y * kv.y + kv.z * kv.z + kv.w * kv.w;
            ss = sum8(ss);
            float rn = 1.f / fmaxf(sqrtf(ss), 1e-12f);
            kv.x *= rn; kv.y *= rn; kv.z *= rn; kv.w *= rn;
            float4 bo, ao;
            bo.x = 1.f / (1.f + __expf(-(bv.x + bB.x)));
            bo.y = 1.f / (1.f + __expf(-(bv.y + bB.y)));
            bo.z = 1.f / (1.f + __expf(-(bv.z + bB.z)));
            bo.w = 1.f / (1.f + __expf(-(bv.w + bB.w)));
            ao.x = 1.f / (1.f + __expf(-(av.x + bA.x)));
            ao.y = 1.f / (1.f + __expf(-(av.y + bA.y)));
            ao.z = 1.f / (1.f + __expf(-(av.z + bA.z)));
            ao.w = 1.f / (1.f + __expf(-(av.w + bA.w)));
            float4 vo;
            vo.x = bo.x * vv.x; vo.y = bo.y * vv.y;
            vo.z = bo.z * vv.z; vo.w = bo.w * vv.w;
            // pair-shared dots: tokens 2j/2j+1 in adjacent 8-lane groups
            float kq = sum8(kv.x * qv.x + kv.y * qv.y + kv.z * qv.z + kv.w * qv.w);
            float4 ko, qo;
            ko.x = __shfl_xor(kv.x, 8); ko.y = __shfl_xor(kv.y, 8);
            ko.z = __shfl_xor(kv.z, 8); ko.w = __shfl_xor(kv.w, 8);
            qo.x = __shfl_xor(qv.x, 8); qo.y = __shfl_xor(qv.y, 8);
            qo.z = __shfl_xor(qv.z, 8); qo.w = __shfl_xor(qv.w, 8);
            float ckk = sum8(kv.x * ko.x + kv.y * ko.y + kv.z * ko.z + kv.w * ko.w);
            float ckq = sum8(kv.x * qo.x + kv.y * qo.y + kv.z * qo.z + kv.w * qo.w);
            *(float4*)&ksH[tok][sc4 * 4] = kv;
            *(float4*)&vsH[tok][sc4 * 4] = vo;
            *(float4*)&qsH[tok][sc4 * 4] = qv;
            *(float4*)&bsH[tok][sc4 * 4] = bo;
            *(float4*)&asH[tok][sc4 * 4] = ao;
            if ((htid & 7) == 0) {
                int pairi = tok >> 1;
                if (!(tok & 1)) {
                    cpH[pairi][0] = ckk;   // k1.k2
                    cpH[pairi][1] = kq;    // k1.q1
                    cpH[pairi][2] = ckq;   // k1.q2
                } else {
                    cpH[pairi][3] = kq;    // k2.q2
                }
            }
        }
    };

    // ---- scan one staged chunk from buffer `buf` (role-0 waves) ----
    auto scan_chunk = [&](int c0, int buf) {
        float (*ksH)[36] = ks[buf];
        float (*qsH)[36] = qs[buf];
        float (*vsH)[36] = vs[buf];
        float (*bsH)[36] = bs[buf];
        float (*asH)[36] = as_[buf];
        float (*cpH)[4]  = cpair[buf];
        auto loadp = [&](int t, Pair& Pr) {
            Pr.k1 = *(const float4*)&ksH[2 * t][c * 4];
            Pr.k2 = *(const float4*)&ksH[2 * t + 1][c * 4];
            Pr.q1 = *(const float4*)&qsH[2 * t][c * 4];
            Pr.q2 = *(const float4*)&qsH[2 * t + 1][c * 4];
            Pr.a1 = asH[2 * t][ri];  Pr.a2 = asH[2 * t + 1][ri];
            Pr.b1 = bsH[2 * t][ri];  Pr.b2 = bsH[2 * t + 1][ri];
            Pr.bv1 = vsH[2 * t][ri]; Pr.bv2 = vsH[2 * t + 1][ri];
            float4 cp = *(const float4*)&cpH[t][0];
            Pr.c12 = cp.x; Pr.cq11 = cp.y; Pr.cq12 = cp.z; Pr.cq22 = cp.w;
        };
        auto stepp = [&](const Pair& Pr, int t) {
            float d1  = sum8(dot4(S, Pr.k1));
            float d2  = sum8(dot4(S, Pr.k2));
            float dq1 = sum8(dot4(S, Pr.q1));
            float dq2 = sum8(dot4(S, Pr.q2));
            float u1 = fmaf(-(Pr.b1 * Pr.a1), d1, Pr.bv1);
            float au1 = Pr.a2 * u1;
            float A = Pr.a1 * Pr.a2;
            float pred2 = fmaf(au1, Pr.c12, A * d2);
            float u2 = fmaf(-Pr.b2, pred2, Pr.bv2);
            S.x = fmaf(u2, Pr.k2.x, fmaf(au1, Pr.k1.x, A * S.x));
            S.y = fmaf(u2, Pr.k2.y, fmaf(au1, Pr.k1.y, A * S.y));
            S.z = fmaf(u2, Pr.k2.z, fmaf(au1, Pr.k1.z, A * S.z));
            S.w = fmaf(u2, Pr.k2.w, fmaf(au1, Pr.k1.w, A * S.w));
            if (cz) {
                cs[2 * t][ri]     = fmaf(u1, Pr.cq11, Pr.a1 * dq1);
                cs[2 * t + 1][ri] = fmaf(u2, Pr.cq22, fmaf(au1, Pr.cq12, A * dq2));
            }
        };
        Pair PA, PB;
        loadp(0, PA);
        for (int t = 0; t < 32; t += 2) {
            loadp(t + 1, PB);
            stepp(PA, t);
            loadp(t + 2, PA);   // t==30 -> pair 32: pad rows 64/65, cpair[32]
            stepp(PB, t + 1);
        }
        // per-wave-own-rows ctx store: wave wv wrote cs[t][8wv..8wv+7]
        int gbase = b * 1024 + c0;
#pragma unroll
        for (int it = 0; it < 2; ++it) {
            int e = lane + it * 64;
            int t = e >> 1, j4 = wv * 2 + (e & 1);
            float4 val = *(const float4*)&cs[t][j4 * 4];
            *(float4*)(ctx + (size_t)(gbase + t) * 256 + hh * 32 + j4 * 4) = val;
        }
    };

    // ---- producer/consumer chunk pipeline ----
    if (role == 1) stage_chunk(0, 0);
    __syncthreads();
    for (int ch = 0; ch < 16; ++ch) {
        if (role == 1) {
            if (ch + 1 < 16) stage_chunk((ch + 1) * 64, (ch + 1) & 1);
        } else {
            scan_chunk(ch * 64, ch & 1);
        }
        __syncthreads();
    }
    if (role == 0)
        *(float4*)(S_out + ((size_t)bh * 32 + ri) * 32 + c * 4) = S;
}

// ------------- ctxbf = bf16(rmsnorm(ctx,nw)*silu(gate)), gate in P@1280 ----
__global__ void ctx_post(const float* __restrict__ ctx, const float* __restrict__ P,
                         const float* __restrict__ nw, bf16* __restrict__ out) {
    int row = blockIdx.x, t = threadIdx.x;  // 64 threads
    float4 x = ((const float4*)(ctx + (size_t)row * SDIMM))[t];
    float s = x.x * x.x + x.y * x.y + x.z * x.z + x.w * x.w;
    for (int m = 1; m < 64; m <<= 1) s += __shfl_xor(s, m);
    float r = rsqrtf(s * (1.f / 256.f) + 1e-6f);
    float4 n = ((const float4*)nw)[t];
    float4 g = ((const float4*)(P + (size_t)row * 1536 + 1280))[t];
    BF4 u;
    u.h[0] = (bf16)(x.x * r * n.x * (g.x / (1.f + __expf(-g.x))));
    u.h[1] = (bf16)(x.y * r * n.y * (g.y / (1.f + __expf(-g.y))));
    u.h[2] = (bf16)(x.z * r * n.z * (g.z / (1.f + __expf(-g.z))));
    u.h[3] = (bf16)(x.w * r * n.w * (g.w / (1.f + __expf(-g.w))));
    ((short4*)(out + (size_t)row * SDIMM))[t] = u.p;
}

// ---------------------------------------------------------------------------
extern "C" void kernel_launch(void* const* d_in, const int* in_sizes, int n_in,
                              void* d_out, int out_size, void* d_ws, size_t ws_size,
                              hipStream_t stream) {
    (void)in_sizes; (void)n_in; (void)out_size; (void)ws_size;
    const int* ids = (const int*)d_in[0];
    const float* state = (const float*)d_in[1];
    const float* embedw = (const float*)d_in[2];
    auto F = [&](int i) { return (const float*)d_in[i]; };

    char* wsb = (char*)d_ws;
    const size_t MB = 1048576;
    float* H    = (float*)(wsb);                 // 0-8 MB
    bf16*  XNbf = (bf16*)(wsb + 8 * MB);         // 8-12 (alias ctxf in delta)
    float* ctxf = (float*)(wsb + 8 * MB);
    bf16*  Hbf  = (bf16*)(wsb + 12 * MB);        // 12-16 (alias ctxb)
    bf16*  ctxb = (bf16*)(wsb + 12 * MB);
    float* P    = (float*)(wsb + 16 * MB);       // 16-40 (delta proj f32)
    bf16*  Obf  = (bf16*)(wsb + 40 * MB);        // 40-44 attn out
    bf16*  Qbuf = (bf16*)(wsb + 44 * MB);        // 44-48
    bf16*  Kbuf = (bf16*)(wsb + 48 * MB);        // 48-52
    bf16*  Vtb  = (bf16*)(wsb + 52 * MB);        // 52-56
    bf16*  A1b  = (bf16*)(wsb + 44 * MB);        // alias Q/K/Vt (dead after attn)
    float* cosT = (float*)(wsb + 58 * MB);
    float* sinT = cosT + 32768;
    float* Sbuf = sinT + 32768;
    char*  wbase = wsb + 59 * MB;
    bf16* wqkv  = (bf16*)(wbase);                        // 6x1536x512
    bf16* wob   = (bf16*)(wbase + 9437184);              // 6x512x512
    bf16* wgu   = (bf16*)(wbase + 12582912);             // 6x3072x512 interleaved
    bf16* wdnb  = (bf16*)(wbase + 31457280);             // 6x512x1536
    bf16* wdR   = (bf16*)(wbase + 40894464);             // 1536x512
    bf16* woutR = (bf16*)(wbase + 42467328);             // 512x256
    bf16* wdW   = (bf16*)(wbase + 42729472);             // 1536x512
    bf16* woutW = (bf16*)(wbase + 44302336);             // 512x256
    bf16* embp  = (bf16*)(wbase + 44564480);             // 128x512 padded

    float* out = (float*)d_out;
    float* logits = out;
    float* Sout = out + 4096 * VOCN;

    // 128x128-tile launches
    auto G0 = [&](const bf16* A, const bf16* B, float* C, int M, int N, int K, int Nreal) {
        gemm_bf16<0><<<dim3(N / 128, M / 128), 256, 0, stream>>>(
            A, B, C, nullptr, nullptr, nullptr, nullptr, nullptr, nullptr, M, N, K, Nreal);
    };
    auto G4 = [&](const bf16* A, const bf16* B, bf16* Cb, int M, int N, int K, int Nreal) {
        gemm_bf16<4><<<dim3(N / 128, M / 128), 256, 0, stream>>>(
            A, B, nullptr, Cb, nullptr, nullptr, nullptr, nullptr, nullptr, M, N, K, Nreal);
    };
    auto G5 = [&](const bf16* A, const bf16* B, int M, int N, int K) {
        gemm_bf16<5><<<dim3(N / 128, M / 128), 256, 0, stream>>>(
            A, B, nullptr, nullptr, cosT, sinT, Qbuf, Kbuf, Vtb, M, N, K, N);
    };
    // 64x128-tile accumulate
    auto G1s = [&](const bf16* A, const bf16* B, float* C, int M, int N, int K) {
        gemm64_bf16<1><<<dim3(N / 128, M / 64), 256, 0, stream>>>(A, B, C, M, N, K, N);
    };
    auto G0s = [&](const bf16* A, const bf16* B, float* C, int M, int N, int K, int Nreal) {
        gemm64_bf16<0><<<dim3(N / 128, M / 64), 256, 0, stream>>>(A, B, C, M, N, K, Nreal);
    };
    auto CP = [&](const float* s, bf16* d, int n4) {
        cast_plain<<<(n4 + 255) / 256, 256, 0, stream>>>(s, d, n4);
    };

    // ---- weight casts ----
    cast_qkv<<<4608, 256, 0, stream>>>(F(24), F(25), F(26), wqkv);
    CP(F(27), wob, 393216);
    cast_gu<<<9216, 256, 0, stream>>>(F(29), F(30), wgu);
    CP(F(31), wdnb, 1179648);
    cast6<<<768, 256, 0, stream>>>(F(3), F(4), F(5), F(6), F(8), F(12), wdR);
    CP(F(10), woutR, 32768);
    cast6<<<768, 256, 0, stream>>>(F(13), F(14), F(15), F(16), F(18), F(22), wdW);
    CP(F(20), woutW, 32768);
    cast_embed_pad<<<64, 256, 0, stream>>>(embedw, embp);

    rope_tables_k<<<128, 256, 0, stream>>>(cosT, sinT);
    embed_k<<<4096, 128, 0, stream>>>(ids, embedw, H);

    // ---- delta read ----
    CP(H, Hbf, 524288);
    G0(Hbf, wdR, P, 4096, 1536, 512, 1536);
    delta_scan<<<32, 512, 0, stream>>>(P, state, F(7), F(9), Sbuf, ctxf);
    ctx_post<<<4096, 64, 0, stream>>>(ctxf, P, F(11), ctxb);
    G1s(ctxb, woutR, H, 4096, 512, 256);

    for (int i = 0; i < 6; ++i) {
        rmsnorm512<<<4096, 128, 0, stream>>>(H, F(23) + (size_t)i * 512, XNbf);
        G5(XNbf, wqkv + (size_t)i * 1536 * 512, 4096, 1536, 512);
        attn_mfma<<<dim3(16, 8, 4), 256, 0, stream>>>(Qbuf, Kbuf, Vtb, Obf);
        G1s(Obf, wob + (size_t)i * 512 * 512, H, 4096, 512, 512);
        rmsnorm512<<<4096, 128, 0, stream>>>(H, F(28) + (size_t)i * 512, XNbf);
        G4(XNbf, wgu + (size_t)i * 3072 * 512, A1b, 4096, 3072, 512, 1536);
        G1s(A1b, wdnb + (size_t)i * 512 * 1536, H, 4096, 512, 1536);
    }

    // ---- delta write ----
    CP(H, Hbf, 524288);
    G0(Hbf, wdW, P, 4096, 1536, 512, 1536);
    delta_scan<<<32, 512, 0, stream>>>(P, Sbuf, F(17), F(19), Sout, ctxf);
    ctx_post<<<4096, 64, 0, stream>>>(ctxf, P, F(21), ctxb);
    G1s(ctxb, woutW, H, 4096, 512, 256);

    rmsnorm512<<<4096, 128, 0, stream>>>(H, F(32), XNbf);
    G0s(XNbf, embp, logits, 4096, 128, 512, VOCN);
}